// Round 1
// baseline (2514.978 us; speedup 1.0000x reference)
//
#include <hip/hip_runtime.h>

#define H_DIM 128
#define NT 20000
#define NC 100000
#define DT 512
#define DC 256
#define E_TC 100000
#define E_SIM 800000
#define E_TS 640000

static __host__ int cdiv_h(int a, int b) { return (a + b - 1) / b; }

// ---------------- small elementwise kernels ----------------

__global__ void add4_kernel(const float* __restrict__ a, const float* __restrict__ b,
                            const float* __restrict__ c, const float* __restrict__ d,
                            float* __restrict__ o, int n) {
    int i = blockIdx.x * blockDim.x + threadIdx.x;
    if (i < n) {
        float v = a[i] + b[i];
        if (c) v += c[i];
        if (d) v += d[i];
        o[i] = v;
    }
}

__global__ void relu_kernel(float* __restrict__ x, int n4) {
    int i = blockIdx.x * blockDim.x + threadIdx.x;
    if (i < n4) {
        float4 v = reinterpret_cast<float4*>(x)[i];
        v.x = fmaxf(v.x, 0.f); v.y = fmaxf(v.y, 0.f);
        v.z = fmaxf(v.z, 0.f); v.w = fmaxf(v.w, 0.f);
        reinterpret_cast<float4*>(x)[i] = v;
    }
}

__global__ void fill_f32(float* __restrict__ p, float v, int n) {
    int i = blockIdx.x * blockDim.x + threadIdx.x;
    if (i < n) p[i] = v;
}

// ---------------- GEMM: Y[M,128] = X[M,K] @ W[K,128] (+bias) ----------------
// 64x128 tile per 256-thread block, K staged in chunks of 16.

__launch_bounds__(256)
__global__ void gemm_n128(const float* __restrict__ X, const float* __restrict__ W,
                          const float* __restrict__ bias, float* __restrict__ Y,
                          int M, int K) {
    __shared__ float As[16][68];   // k-major, padded (stride 272B: 16B-aligned, conflict-light)
    __shared__ float Bs[16][128];
    const int t   = threadIdx.x;
    const int tx  = t & 15;        // col group: cols tx*8 .. tx*8+7
    const int ty  = t >> 4;        // row group: rows ty*4 .. ty*4+3
    const int row0 = blockIdx.x * 64;
    const int ar  = t >> 2;          // A load: row within tile
    const int aq  = (t & 3) << 2;    // A load: k offset (float4)
    const int bk0 = t >> 5, bc0 = (t & 31) << 2;
    const int bk1 = (t + 256) >> 5, bc1 = bc0;
    float acc[4][8];
#pragma unroll
    for (int r = 0; r < 4; ++r)
#pragma unroll
        for (int c = 0; c < 8; ++c) acc[r][c] = 0.f;
    const int arow = row0 + ar;

    for (int k0 = 0; k0 < K; k0 += 16) {
        float4 av = make_float4(0.f, 0.f, 0.f, 0.f);
        if (arow < M) av = *reinterpret_cast<const float4*>(&X[(size_t)arow * K + k0 + aq]);
        const float4 bv0 = *reinterpret_cast<const float4*>(&W[(size_t)(k0 + bk0) * 128 + bc0]);
        const float4 bv1 = *reinterpret_cast<const float4*>(&W[(size_t)(k0 + bk1) * 128 + bc1]);
        __syncthreads();
        As[aq + 0][ar] = av.x; As[aq + 1][ar] = av.y;
        As[aq + 2][ar] = av.z; As[aq + 3][ar] = av.w;
        *reinterpret_cast<float4*>(&Bs[bk0][bc0]) = bv0;
        *reinterpret_cast<float4*>(&Bs[bk1][bc1]) = bv1;
        __syncthreads();
#pragma unroll
        for (int kk = 0; kk < 16; ++kk) {
            const float4 a4 = *reinterpret_cast<const float4*>(&As[kk][ty << 2]);
            const float4 b0 = *reinterpret_cast<const float4*>(&Bs[kk][tx << 3]);
            const float4 b1 = *reinterpret_cast<const float4*>(&Bs[kk][(tx << 3) + 4]);
            const float aa[4] = {a4.x, a4.y, a4.z, a4.w};
            const float bb[8] = {b0.x, b0.y, b0.z, b0.w, b1.x, b1.y, b1.z, b1.w};
#pragma unroll
            for (int r = 0; r < 4; ++r)
#pragma unroll
                for (int c = 0; c < 8; ++c)
                    acc[r][c] = fmaf(aa[r], bb[c], acc[r][c]);
        }
    }
#pragma unroll
    for (int r = 0; r < 4; ++r) {
        const int grow = row0 + (ty << 2) + r;
        if (grow >= M) continue;
        float4 o0, o1;
        o0.x = acc[r][0]; o0.y = acc[r][1]; o0.z = acc[r][2]; o0.w = acc[r][3];
        o1.x = acc[r][4]; o1.y = acc[r][5]; o1.z = acc[r][6]; o1.w = acc[r][7];
        if (bias) {
            const int cb = tx << 3;
            o0.x += bias[cb + 0]; o0.y += bias[cb + 1]; o0.z += bias[cb + 2]; o0.w += bias[cb + 3];
            o1.x += bias[cb + 4]; o1.y += bias[cb + 5]; o1.z += bias[cb + 6]; o1.w += bias[cb + 7];
        }
        *reinterpret_cast<float4*>(&Y[(size_t)grow * 128 + (tx << 3)]) = o0;
        *reinterpret_cast<float4*>(&Y[(size_t)grow * 128 + (tx << 3) + 4]) = o1;
    }
}

// ---------------- CSR build (counting sort by dst) ----------------

__global__ void count_dst(const int* __restrict__ dst, int* __restrict__ cnt, int E) {
    int e = blockIdx.x * blockDim.x + threadIdx.x;
    if (e < E) atomicAdd(&cnt[dst[e]], 1);
}

__launch_bounds__(256)
__global__ void scan_phase1(const int* __restrict__ cnt, int* __restrict__ rs,
                            int* __restrict__ bsum, int N) {
    __shared__ int sh[256];
    const int t = threadIdx.x;
    const int base = blockIdx.x * 1024 + t * 4;
    int v0 = 0, v1 = 0, v2 = 0, v3 = 0;
    if (base + 0 < N) v0 = cnt[base + 0];
    if (base + 1 < N) v1 = cnt[base + 1];
    if (base + 2 < N) v2 = cnt[base + 2];
    if (base + 3 < N) v3 = cnt[base + 3];
    const int tot = v0 + v1 + v2 + v3;
    sh[t] = tot;
    __syncthreads();
#pragma unroll
    for (int off = 1; off < 256; off <<= 1) {
        int y = (t >= off) ? sh[t - off] : 0;
        __syncthreads();
        sh[t] += y;
        __syncthreads();
    }
    const int incl = sh[t];
    const int excl = incl - tot;
    if (base + 0 < N) rs[base + 0] = excl;
    if (base + 1 < N) rs[base + 1] = excl + v0;
    if (base + 2 < N) rs[base + 2] = excl + v0 + v1;
    if (base + 3 < N) rs[base + 3] = excl + v0 + v1 + v2;
    if (t == 255) bsum[blockIdx.x] = incl;
}

__global__ void scan_phase2(const int* __restrict__ bsum, int* __restrict__ boff, int nblk) {
    if (blockIdx.x == 0 && threadIdx.x == 0) {
        int acc = 0;
        for (int b = 0; b < nblk; ++b) { boff[b] = acc; acc += bsum[b]; }
        boff[nblk] = acc;
    }
}

__global__ void scan_phase3(int* __restrict__ rs, const int* __restrict__ boff, int N, int nblk) {
    int i = blockIdx.x * blockDim.x + threadIdx.x;
    if (i < N) rs[i] += boff[i >> 10];
    if (i == 0) rs[N] = boff[nblk];
}

__global__ void csr_fill(const int* __restrict__ dst, const int* __restrict__ src,
                         const int* __restrict__ rs, int* __restrict__ fil,
                         int* __restrict__ srt, int E) {
    int e = blockIdx.x * blockDim.x + threadIdx.x;
    if (e >= E) return;
    const int d = dst[e];
    const int pos = rs[d] + atomicAdd(&fil[d], 1);
    srt[pos] = src[e];
}

__global__ void csr_fill_norm(const int* __restrict__ dst, const int* __restrict__ src,
                              const float* __restrict__ ew, const int* __restrict__ rs,
                              int* __restrict__ fil, int* __restrict__ srt,
                              float* __restrict__ nrm, const float* __restrict__ dis, int E) {
    int e = blockIdx.x * blockDim.x + threadIdx.x;
    if (e >= E) return;
    const int d = dst[e];
    const int s = src[e];
    const int pos = rs[d] + atomicAdd(&fil[d], 1);
    srt[pos] = s;
    nrm[pos] = dis[s] * ew[e] * dis[d];
}

__global__ void deg_accum(const int* __restrict__ dst, const float* __restrict__ ew,
                          float* __restrict__ deg, int E) {
    int e = blockIdx.x * blockDim.x + threadIdx.x;
    if (e < E) atomicAdd(&deg[dst[e]], ew[e]);
}

__global__ void deg_to_dis(float* __restrict__ deg, int n) {
    int i = blockIdx.x * blockDim.x + threadIdx.x;
    if (i < n) {
        float d = deg[i];
        deg[i] = (d > 0.f) ? (1.0f / sqrtf(d)) : 0.f;
    }
}

// ---------------- gather aggregation: out[dst] += mean_{e in CSR[dst]} feat[src_e] ----------------
// one wave (64 lanes) per dst row, float2 per lane (128 cols)

__launch_bounds__(256)
__global__ void agg_mean(const float* __restrict__ feat, const int* __restrict__ rs,
                         const int* __restrict__ srt, float* __restrict__ out, int n_dst) {
    const int wave = threadIdx.x >> 6;
    const int lane = threadIdx.x & 63;
    const int row = blockIdx.x * 4 + wave;
    if (row >= n_dst) return;
    const int b = rs[row], e = rs[row + 1];
    const int cnt = e - b;
    if (cnt <= 0) return;
    float ax = 0.f, ay = 0.f;
    for (int j = b; j < e; ++j) {
        const int s = srt[j];
        const float2 v = *reinterpret_cast<const float2*>(&feat[(size_t)s * 128 + (lane << 1)]);
        ax += v.x; ay += v.y;
    }
    const float inv = 1.0f / (float)cnt;
    float2* o = reinterpret_cast<float2*>(&out[(size_t)row * 128 + (lane << 1)]);
    float2 cur = *o;
    cur.x += ax * inv; cur.y += ay * inv;
    *o = cur;
}

// ---------------- APPNP step ----------------

__launch_bounds__(256)
__global__ void appnp_step(const float* __restrict__ z, const float* __restrict__ x0,
                           const int* __restrict__ rs, const int* __restrict__ srt,
                           const float* __restrict__ nrm, const float* __restrict__ dis,
                           float* __restrict__ zo, int n) {
    const int wave = threadIdx.x >> 6;
    const int lane = threadIdx.x & 63;
    const int row = blockIdx.x * 4 + wave;
    if (row >= n) return;
    const int b = rs[row], e = rs[row + 1];
    float ax = 0.f, ay = 0.f;
    for (int j = b; j < e; ++j) {
        const int s = srt[j];
        const float w = nrm[j];
        const float2 v = *reinterpret_cast<const float2*>(&z[(size_t)s * 128 + (lane << 1)]);
        ax = fmaf(w, v.x, ax); ay = fmaf(w, v.y, ay);
    }
    const float d = dis[row];
    const float d2 = d * d;
    const size_t o = (size_t)row * 128 + (lane << 1);
    const float2 zr = *reinterpret_cast<const float2*>(&z[o]);
    const float2 xr = *reinterpret_cast<const float2*>(&x0[o]);
    float2 ov;
    ov.x = 0.8f * (ax + d2 * zr.x) + 0.2f * xr.x;
    ov.y = 0.8f * (ay + d2 * zr.y) + 0.2f * xr.y;
    *reinterpret_cast<float2*>(&zo[o]) = ov;
}

// ---------------- retrieval-weighted query injection ----------------

__global__ void qprep(const float* __restrict__ q, const float* __restrict__ Wq,
                      const float* __restrict__ bq, float* __restrict__ qv,
                      float* __restrict__ qn) {
    const int c = threadIdx.x;  // 128 threads
    float acc = 0.f;
    for (int k = 0; k < 512; ++k) acc = fmaf(q[k], Wq[(size_t)k * 128 + c], acc);
    qv[c] = acc + bq[c];
    if (c < 64) {
        float ss = 0.f;
        for (int k = c; k < 512; k += 64) { float v = q[k]; ss = fmaf(v, v, ss); }
        for (int off = 32; off; off >>= 1) ss += __shfl_xor(ss, off);
        if (c == 0) qn[0] = fmaxf(sqrtf(ss), 1e-12f);
    }
}

__launch_bounds__(256)
__global__ void wgt_kernel(const float* __restrict__ table_x, const float* __restrict__ q,
                           const float* __restrict__ qn, float* __restrict__ wgt) {
    const int wave = threadIdx.x >> 6;
    const int lane = threadIdx.x & 63;
    const int row = blockIdx.x * 4 + wave;
    if (row >= NT) return;
    const float* x = table_x + (size_t)row * 512;
    float dot = 0.f, ss = 0.f;
#pragma unroll
    for (int j = 0; j < 8; ++j) {
        const float xv = x[lane + 64 * j];
        const float qv_ = q[lane + 64 * j];
        dot = fmaf(xv, qv_, dot);
        ss = fmaf(xv, xv, ss);
    }
    for (int off = 32; off; off >>= 1) {
        dot += __shfl_xor(dot, off);
        ss += __shfl_xor(ss, off);
    }
    if (lane == 0) {
        const float nx = fmaxf(sqrtf(ss), 1e-12f);
        wgt[row] = fmaxf(dot, 0.f) / (nx * qn[0]);
    }
}

__global__ void x0z_kernel(float* __restrict__ x0, float* __restrict__ z,
                           const float* __restrict__ wgt, const float* __restrict__ qv, int n) {
    int i = blockIdx.x * blockDim.x + threadIdx.x;
    if (i >= n * 128) return;
    const int r = i >> 7, c = i & 127;
    const float v = x0[i] + wgt[r] * qv[c];
    x0[i] = v;
    z[i] = v;
}

__launch_bounds__(256)
__global__ void out_kernel(const float* __restrict__ z, const float* __restrict__ Wlin,
                           const float* __restrict__ blin, float* __restrict__ out, int n) {
    const int wave = threadIdx.x >> 6;
    const int lane = threadIdx.x & 63;
    const int row = blockIdx.x * 4 + wave;
    if (row >= n) return;
    float s = z[(size_t)row * 128 + lane] * Wlin[lane]
            + z[(size_t)row * 128 + 64 + lane] * Wlin[64 + lane];
    for (int off = 32; off; off >>= 1) s += __shfl_xor(s, off);
    if (lane == 0) out[row] = s + blin[0];
}

// ---------------- host ----------------

extern "C" void kernel_launch(void* const* d_in, const int* in_sizes, int n_in,
                              void* d_out, int out_size, void* d_ws, size_t ws_size,
                              hipStream_t stream) {
    const float* table_x  = (const float*)d_in[0];
    const float* column_x = (const float*)d_in[1];
    const float* q        = (const float*)d_in[2];
    const float* Wl1_tc  = (const float*)d_in[3];  const float* bl1_tc  = (const float*)d_in[4];  const float* Wr1_tc  = (const float*)d_in[5];
    const float* Wl1_rev = (const float*)d_in[6];  const float* bl1_rev = (const float*)d_in[7];  const float* Wr1_rev = (const float*)d_in[8];
    const float* Wl1_cs  = (const float*)d_in[9];  const float* bl1_cs  = (const float*)d_in[10]; const float* Wr1_cs  = (const float*)d_in[11];
    const float* Wl1_ns  = (const float*)d_in[12]; const float* bl1_ns  = (const float*)d_in[13]; const float* Wr1_ns  = (const float*)d_in[14];
    const float* Wl1_ds  = (const float*)d_in[15]; const float* bl1_ds  = (const float*)d_in[16]; const float* Wr1_ds  = (const float*)d_in[17];
    const float* Wl1_ts  = (const float*)d_in[18]; const float* bl1_ts  = (const float*)d_in[19]; const float* Wr1_ts  = (const float*)d_in[20];
    const float* Wl2_rev = (const float*)d_in[21]; const float* bl2_rev = (const float*)d_in[22]; /* Wr2_rev = d_in[23] */
    const float* Wl2_ts  = (const float*)d_in[24]; const float* bl2_ts  = (const float*)d_in[25]; /* Wr2_ts  = d_in[26] */
    const float* Wr2_rev = (const float*)d_in[23];
    const float* Wr2_ts  = (const float*)d_in[26];
    const float* Wq   = (const float*)d_in[27]; const float* bq   = (const float*)d_in[28];
    const float* Wlin = (const float*)d_in[29]; const float* blin = (const float*)d_in[30];
    const float* ts_ew = (const float*)d_in[31];
    const int* tc_src = (const int*)d_in[32];
    const int* tc_dst = (const int*)d_in[33];
    const int* cs_ei  = (const int*)d_in[34];
    const int* ns_ei  = (const int*)d_in[35];
    const int* ds_ei  = (const int*)d_in[36];
    const int* ts_ei  = (const int*)d_in[37];

    // ---- workspace carve ----
    char* w = (char*)d_ws;
    size_t off = 0;
    auto alloc = [&](size_t bytes) -> void* {
        void* p = w + off;
        off += (bytes + 255) & ~(size_t)255;
        return p;
    };
    float* f_bufPC = (float*)alloc((size_t)NC * 128 * 4);   // column-space projection buffer
    float* f_col1  = (float*)alloc((size_t)NC * 128 * 4);
    float* f_bufPT = (float*)alloc((size_t)NT * 128 * 4);   // table-space projection buffer
    float* f_tab1  = (float*)alloc((size_t)NT * 128 * 4);
    float* f_tab2  = (float*)alloc((size_t)NT * 128 * 4);   // becomes x0
    float* f_WrS1c = (float*)alloc(256 * 128 * 4);
    float* f_WrS1t = (float*)alloc(512 * 128 * 4);
    float* f_WrS2  = (float*)alloc(128 * 128 * 4);
    float* f_biasC  = (float*)alloc(128 * 4);
    float* f_biasT1 = (float*)alloc(128 * 4);
    float* f_biasT2 = (float*)alloc(128 * 4);
    float* f_qv  = (float*)alloc(128 * 4);
    float* f_qn  = (float*)alloc(256);
    float* f_wgt = (float*)alloc((size_t)NT * 4);
    float* f_dis = (float*)alloc((size_t)NT * 4);
    float* f_norm = (float*)alloc((size_t)E_TS * 4);
    int* i_cnt     = (int*)alloc((size_t)(NC + 1) * 4);     // shared count/fill scratch
    int* i_rs_tmp  = (int*)alloc((size_t)(NC + 1) * 4);     // tc/cs/ns/ds CSR row starts
    int* i_srt_tmp = (int*)alloc((size_t)E_SIM * 4);
    int* i_rs_rev  = (int*)alloc((size_t)(NT + 1) * 4);     // persists through layer 2
    int* i_srt_rev = (int*)alloc((size_t)E_TC * 4);
    int* i_rs_ts   = (int*)alloc((size_t)(NT + 1) * 4);     // persists through APPNP
    int* i_srt_ts  = (int*)alloc((size_t)E_TS * 4);
    int* i_bsum = (int*)alloc(512 * 4);
    int* i_boff = (int*)alloc(513 * 4);
    // z / znew live in f_bufPC (free after layer 2; NC*128 >= 2*NT*128)
    float* f_z    = f_bufPC;
    float* f_znew = f_bufPC + (size_t)NT * 128;
    if (off > ws_size) return;  // workspace too small: bail (bench will flag)

    auto cdiv = [](int a, int b) { return (a + b - 1) / b; };

    // ---- weight prep ----
    add4_kernel<<<cdiv(256 * 128, 256), 256, 0, stream>>>(Wr1_tc, Wr1_cs, Wr1_ns, Wr1_ds, f_WrS1c, 256 * 128);
    add4_kernel<<<1, 128, 0, stream>>>(bl1_tc, bl1_cs, bl1_ns, bl1_ds, f_biasC, 128);
    add4_kernel<<<cdiv(512 * 128, 256), 256, 0, stream>>>(Wr1_rev, Wr1_ts, nullptr, nullptr, f_WrS1t, 512 * 128);
    add4_kernel<<<1, 128, 0, stream>>>(bl1_rev, bl1_ts, nullptr, nullptr, f_biasT1, 128);
    add4_kernel<<<cdiv(128 * 128, 256), 256, 0, stream>>>(Wr2_rev, Wr2_ts, nullptr, nullptr, f_WrS2, 128 * 128);
    add4_kernel<<<1, 128, 0, stream>>>(bl2_rev, bl2_ts, nullptr, nullptr, f_biasT2, 128);
    qprep<<<1, 128, 0, stream>>>(q, Wq, bq, f_qv, f_qn);

    auto build_csr = [&](const int* dst, const int* src, int E, int N, int* rs, int* srt) {
        hipMemsetAsync(i_cnt, 0, (size_t)N * 4, stream);
        count_dst<<<cdiv(E, 256), 256, 0, stream>>>(dst, i_cnt, E);
        const int nblk = cdiv(N, 1024);
        scan_phase1<<<nblk, 256, 0, stream>>>(i_cnt, rs, i_bsum, N);
        scan_phase2<<<1, 1, 0, stream>>>(i_bsum, i_boff, nblk);
        scan_phase3<<<cdiv(N, 256), 256, 0, stream>>>(rs, i_boff, N, nblk);
        hipMemsetAsync(i_cnt, 0, (size_t)N * 4, stream);
        csr_fill<<<cdiv(E, 256), 256, 0, stream>>>(dst, src, rs, i_cnt, srt, E);
    };

    // ---- layer 1: col1 ----
    gemm_n128<<<cdiv(NC, 64), 256, 0, stream>>>(column_x, f_WrS1c, f_biasC, f_col1, NC, 256);
    gemm_n128<<<cdiv(NT, 64), 256, 0, stream>>>(table_x, Wl1_tc, nullptr, f_bufPT, NT, 512);
    build_csr(tc_dst, tc_src, E_TC, NC, i_rs_tmp, i_srt_tmp);
    agg_mean<<<cdiv(NC, 4), 256, 0, stream>>>(f_bufPT, i_rs_tmp, i_srt_tmp, f_col1, NC);

    gemm_n128<<<cdiv(NC, 64), 256, 0, stream>>>(column_x, Wl1_cs, nullptr, f_bufPC, NC, 256);
    build_csr(cs_ei + E_SIM, cs_ei, E_SIM, NC, i_rs_tmp, i_srt_tmp);
    agg_mean<<<cdiv(NC, 4), 256, 0, stream>>>(f_bufPC, i_rs_tmp, i_srt_tmp, f_col1, NC);

    gemm_n128<<<cdiv(NC, 64), 256, 0, stream>>>(column_x, Wl1_ns, nullptr, f_bufPC, NC, 256);
    build_csr(ns_ei + E_SIM, ns_ei, E_SIM, NC, i_rs_tmp, i_srt_tmp);
    agg_mean<<<cdiv(NC, 4), 256, 0, stream>>>(f_bufPC, i_rs_tmp, i_srt_tmp, f_col1, NC);

    gemm_n128<<<cdiv(NC, 64), 256, 0, stream>>>(column_x, Wl1_ds, nullptr, f_bufPC, NC, 256);
    build_csr(ds_ei + E_SIM, ds_ei, E_SIM, NC, i_rs_tmp, i_srt_tmp);
    agg_mean<<<cdiv(NC, 4), 256, 0, stream>>>(f_bufPC, i_rs_tmp, i_srt_tmp, f_col1, NC);

    // ---- layer 1: tab1 ----
    gemm_n128<<<cdiv(NT, 64), 256, 0, stream>>>(table_x, f_WrS1t, f_biasT1, f_tab1, NT, 512);
    build_csr(tc_src, tc_dst, E_TC, NT, i_rs_rev, i_srt_rev);  // reversed tc graph
    gemm_n128<<<cdiv(NC, 64), 256, 0, stream>>>(column_x, Wl1_rev, nullptr, f_bufPC, NC, 256);
    agg_mean<<<cdiv(NT, 4), 256, 0, stream>>>(f_bufPC, i_rs_rev, i_srt_rev, f_tab1, NT);

    // ts CSR + APPNP normalization (dis must precede norm fill)
    {
        const int* ts_src = ts_ei;
        const int* ts_dst = ts_ei + E_TS;
        hipMemsetAsync(i_cnt, 0, (size_t)NT * 4, stream);
        count_dst<<<cdiv(E_TS, 256), 256, 0, stream>>>(ts_dst, i_cnt, E_TS);
        const int nblk = cdiv(NT, 1024);
        scan_phase1<<<nblk, 256, 0, stream>>>(i_cnt, i_rs_ts, i_bsum, NT);
        scan_phase2<<<1, 1, 0, stream>>>(i_bsum, i_boff, nblk);
        scan_phase3<<<cdiv(NT, 256), 256, 0, stream>>>(i_rs_ts, i_boff, NT, nblk);
        fill_f32<<<cdiv(NT, 256), 256, 0, stream>>>(f_dis, 1.0f, NT);  // self-loop weight 1
        deg_accum<<<cdiv(E_TS, 256), 256, 0, stream>>>(ts_dst, ts_ew, f_dis, E_TS);
        deg_to_dis<<<cdiv(NT, 256), 256, 0, stream>>>(f_dis, NT);
        hipMemsetAsync(i_cnt, 0, (size_t)NT * 4, stream);
        csr_fill_norm<<<cdiv(E_TS, 256), 256, 0, stream>>>(ts_dst, ts_src, ts_ew, i_rs_ts,
                                                           i_cnt, i_srt_ts, f_norm, f_dis, E_TS);
    }
    gemm_n128<<<cdiv(NT, 64), 256, 0, stream>>>(table_x, Wl1_ts, nullptr, f_bufPT, NT, 512);
    agg_mean<<<cdiv(NT, 4), 256, 0, stream>>>(f_bufPT, i_rs_ts, i_srt_ts, f_tab1, NT);

    relu_kernel<<<cdiv(NC * 128 / 4, 256), 256, 0, stream>>>(f_col1, NC * 128 / 4);
    relu_kernel<<<cdiv(NT * 128 / 4, 256), 256, 0, stream>>>(f_tab1, NT * 128 / 4);

    // ---- layer 2 (table output only) ----
    gemm_n128<<<cdiv(NT, 64), 256, 0, stream>>>(f_tab1, f_WrS2, f_biasT2, f_tab2, NT, 128);
    gemm_n128<<<cdiv(NC, 64), 256, 0, stream>>>(f_col1, Wl2_rev, nullptr, f_bufPC, NC, 128);
    agg_mean<<<cdiv(NT, 4), 256, 0, stream>>>(f_bufPC, i_rs_rev, i_srt_rev, f_tab2, NT);
    gemm_n128<<<cdiv(NT, 64), 256, 0, stream>>>(f_tab1, Wl2_ts, nullptr, f_bufPT, NT, 128);
    agg_mean<<<cdiv(NT, 4), 256, 0, stream>>>(f_bufPT, i_rs_ts, i_srt_ts, f_tab2, NT);

    // ---- retrieval injection + APPNP ----
    wgt_kernel<<<cdiv(NT, 4), 256, 0, stream>>>(table_x, q, f_qn, f_wgt);
    x0z_kernel<<<cdiv(NT * 128, 256), 256, 0, stream>>>(f_tab2, f_z, f_wgt, f_qv, NT);

    float* zin = f_z;
    float* zout = f_znew;
    for (int it = 0; it < 10; ++it) {
        appnp_step<<<cdiv(NT, 4), 256, 0, stream>>>(zin, f_tab2, i_rs_ts, i_srt_ts,
                                                    f_norm, f_dis, zout, NT);
        float* tmp = zin; zin = zout; zout = tmp;
    }

    out_kernel<<<cdiv(NT, 4), 256, 0, stream>>>(zin, Wlin, blin, (float*)d_out, NT);
}

// Round 2
// 1371.991 us; speedup vs baseline: 1.8331x; 1.8331x over previous
//
#include <hip/hip_runtime.h>

#define NT 20000
#define NC 100000
#define DT 512
#define DC 256
#define E_TC 100000
#define E_SIM 800000
#define E_TS 640000

typedef float f32x4 __attribute__((ext_vector_type(4)));
typedef __bf16 bf16x8 __attribute__((ext_vector_type(8)));

// ---------------- small elementwise kernels ----------------

__global__ void add4_kernel(const float* __restrict__ a, const float* __restrict__ b,
                            const float* __restrict__ c, const float* __restrict__ d,
                            float* __restrict__ o, int n) {
    int i = blockIdx.x * blockDim.x + threadIdx.x;
    if (i < n) {
        float v = a[i] + b[i];
        if (c) v += c[i];
        if (d) v += d[i];
        o[i] = v;
    }
}

__global__ void fill_f32(float* __restrict__ p, float v, int n) {
    int i = blockIdx.x * blockDim.x + threadIdx.x;
    if (i < n) p[i] = v;
}

// Wt[n][k] = bf16( sum_i W_i[k][128 cols -> n] ), W_i are [K][128] f32
__global__ void wprep(const float* __restrict__ w0, const float* __restrict__ w1,
                      const float* __restrict__ w2, const float* __restrict__ w3,
                      __bf16* __restrict__ wt, int K) {
    int idx = blockIdx.x * blockDim.x + threadIdx.x;
    if (idx >= 128 * K) return;
    const int n = idx / K, k = idx - n * K;
    float s = w0[(size_t)k * 128 + n];
    if (w1) s += w1[(size_t)k * 128 + n];
    if (w2) s += w2[(size_t)k * 128 + n];
    if (w3) s += w3[(size_t)k * 128 + n];
    wt[(size_t)n * K + k] = (__bf16)s;
}

// collapsed layer-2 weight vectors + query scalars. 1 block, 128 threads.
// sc[0]=qdot, sc[1]=c0, sc[2]=qn
__global__ void vecprep(const float* __restrict__ q, const float* __restrict__ Wq,
                        const float* __restrict__ bq,
                        const float* __restrict__ Wr2_rev, const float* __restrict__ Wr2_ts,
                        const float* __restrict__ Wl2_rev, const float* __restrict__ Wl2_ts,
                        const float* __restrict__ bl2_rev, const float* __restrict__ bl2_ts,
                        const float* __restrict__ Wlin,
                        float* __restrict__ w2s, float* __restrict__ wrev,
                        float* __restrict__ wts, float* __restrict__ sc) {
    const int t = threadIdx.x;  // 0..127
    float a = 0.f, b = 0.f, c = 0.f;
    for (int h = 0; h < 128; ++h) {
        const float wl = Wlin[h];
        a = fmaf(Wr2_rev[(size_t)t * 128 + h] + Wr2_ts[(size_t)t * 128 + h], wl, a);
        b = fmaf(Wl2_rev[(size_t)t * 128 + h], wl, b);
        c = fmaf(Wl2_ts[(size_t)t * 128 + h], wl, c);
    }
    w2s[t] = a; wrev[t] = b; wts[t] = c;
    float qv = bq[t];
    for (int k = 0; k < 512; ++k) qv = fmaf(q[k], Wq[(size_t)k * 128 + t], qv);
    __shared__ float sh[128];
    // qdot
    sh[t] = qv * Wlin[t];
    __syncthreads();
    for (int st = 64; st >= 1; st >>= 1) { if (t < st) sh[t] += sh[t + st]; __syncthreads(); }
    if (t == 0) sc[0] = sh[0];
    __syncthreads();
    // c0
    sh[t] = (bl2_rev[t] + bl2_ts[t]) * Wlin[t];
    __syncthreads();
    for (int st = 64; st >= 1; st >>= 1) { if (t < st) sh[t] += sh[t + st]; __syncthreads(); }
    if (t == 0) sc[1] = sh[0];
    __syncthreads();
    // qn
    float ss = 0.f;
    for (int k = t; k < 512; k += 128) { const float v = q[k]; ss = fmaf(v, v, ss); }
    sh[t] = ss;
    __syncthreads();
    for (int st = 64; st >= 1; st >>= 1) { if (t < st) sh[t] += sh[t + st]; __syncthreads(); }
    if (t == 0) sc[2] = fmaxf(sqrtf(sh[0]), 1e-12f);
}

// ---------------- MFMA GEMM: Y[M,128] = X[M,K]f32 @ Wt[128,K]bf16^T (+bias) ----------------
// LDS-free: A-frags loaded f32 + converted in-register, B-frags direct bf16x8 (L2-hot).
// MF = row-frags per wave (wave covers MF*16 rows, all 128 cols). Block = 4 waves.

template<int K, int MF>
__launch_bounds__(256)
__global__ void gemm_mfma(const float* __restrict__ X, const __bf16* __restrict__ Wt,
                          const float* __restrict__ bias, float* __restrict__ Yf,
                          __bf16* __restrict__ Yb, int M) {
    const int lane = threadIdx.x & 63;
    const int wave = threadIdx.x >> 6;
    const int l15 = lane & 15;
    const int kg = lane >> 4;                         // 0..3
    const int rowbase = blockIdx.x * (MF * 64) + wave * (MF * 16);

    const float* baseA[MF];
#pragma unroll
    for (int m = 0; m < MF; ++m) {
        int r = rowbase + m * 16 + l15;
        r = (r < M) ? r : (M - 1);
        baseA[m] = X + (size_t)r * K + kg * 8;
    }
    const __bf16* baseB[8];
#pragma unroll
    for (int n = 0; n < 8; ++n)
        baseB[n] = Wt + (size_t)(n * 16 + l15) * K + kg * 8;

    f32x4 acc[MF][8];
#pragma unroll
    for (int m = 0; m < MF; ++m)
#pragma unroll
        for (int n = 0; n < 8; ++n) acc[m][n] = (f32x4)0.f;

    const int NS = K / 32;
#pragma unroll 2
    for (int ks = 0; ks < NS; ++ks) {
        bf16x8 af[MF];
#pragma unroll
        for (int m = 0; m < MF; ++m) {
            const float4 x0 = *reinterpret_cast<const float4*>(baseA[m] + ks * 32);
            const float4 x1 = *reinterpret_cast<const float4*>(baseA[m] + ks * 32 + 4);
            bf16x8 t;
            t[0] = (__bf16)x0.x; t[1] = (__bf16)x0.y; t[2] = (__bf16)x0.z; t[3] = (__bf16)x0.w;
            t[4] = (__bf16)x1.x; t[5] = (__bf16)x1.y; t[6] = (__bf16)x1.z; t[7] = (__bf16)x1.w;
            af[m] = t;
        }
        bf16x8 bf[8];
#pragma unroll
        for (int n = 0; n < 8; ++n)
            bf[n] = *reinterpret_cast<const bf16x8*>(baseB[n] + ks * 32);
#pragma unroll
        for (int m = 0; m < MF; ++m)
#pragma unroll
            for (int n = 0; n < 8; ++n)
                acc[m][n] = __builtin_amdgcn_mfma_f32_16x16x32_bf16(af[m], bf[n], acc[m][n], 0, 0, 0);
    }

    // epilogue: C layout col=lane&15, row=(lane>>4)*4+reg
#pragma unroll
    for (int n = 0; n < 8; ++n) {
        const int col = n * 16 + l15;
        const float bv = bias ? bias[col] : 0.f;
#pragma unroll
        for (int m = 0; m < MF; ++m) {
#pragma unroll
            for (int r = 0; r < 4; ++r) {
                const int row = rowbase + m * 16 + kg * 4 + r;
                if (row < M) {
                    const float v = acc[m][n][r] + bv;
                    if (Yf) Yf[(size_t)row * 128 + col] = v;
                    else    Yb[(size_t)row * 128 + col] = (__bf16)v;
                }
            }
        }
    }
}

// ---------------- CSR build (counting sort by dst) ----------------

__global__ void count_dst(const int* __restrict__ dst, int* __restrict__ cnt, int E) {
    int e = blockIdx.x * blockDim.x + threadIdx.x;
    if (e < E) atomicAdd(&cnt[dst[e]], 1);
}

__launch_bounds__(256)
__global__ void scan_phase1(const int* __restrict__ cnt, int* __restrict__ rs,
                            int* __restrict__ bsum, int N) {
    __shared__ int sh[256];
    const int t = threadIdx.x;
    const int base = blockIdx.x * 1024 + t * 4;
    int v0 = 0, v1 = 0, v2 = 0, v3 = 0;
    if (base + 0 < N) v0 = cnt[base + 0];
    if (base + 1 < N) v1 = cnt[base + 1];
    if (base + 2 < N) v2 = cnt[base + 2];
    if (base + 3 < N) v3 = cnt[base + 3];
    const int tot = v0 + v1 + v2 + v3;
    sh[t] = tot;
    __syncthreads();
#pragma unroll
    for (int off = 1; off < 256; off <<= 1) {
        int y = (t >= off) ? sh[t - off] : 0;
        __syncthreads();
        sh[t] += y;
        __syncthreads();
    }
    const int incl = sh[t];
    const int excl = incl - tot;
    if (base + 0 < N) rs[base + 0] = excl;
    if (base + 1 < N) rs[base + 1] = excl + v0;
    if (base + 2 < N) rs[base + 2] = excl + v0 + v1;
    if (base + 3 < N) rs[base + 3] = excl + v0 + v1 + v2;
    if (t == 255) bsum[blockIdx.x] = incl;
}

// single-wave shuffle scan over block sums (was single-thread: ~10us each)
__global__ void scan_phase2(const int* __restrict__ bsum, int* __restrict__ boff, int nblk) {
    const int l = threadIdx.x;  // 64 threads
    int carry = 0;
    for (int base = 0; base < nblk; base += 64) {
        const int v = (base + l < nblk) ? bsum[base + l] : 0;
        int inc = v;
#pragma unroll
        for (int off = 1; off < 64; off <<= 1) {
            const int y = __shfl_up(inc, off);
            if (l >= off) inc += y;
        }
        if (base + l < nblk) boff[base + l] = carry + inc - v;  // exclusive
        carry += __shfl(inc, 63);
    }
    if (l == 0) boff[nblk] = carry;
}

__global__ void scan_phase3(int* __restrict__ rs, const int* __restrict__ boff, int N, int nblk) {
    int i = blockIdx.x * blockDim.x + threadIdx.x;
    if (i < N) rs[i] += boff[i >> 10];
    if (i == 0) rs[N] = boff[nblk];
}

__global__ void csr_fill(const int* __restrict__ dst, const int* __restrict__ src,
                         const int* __restrict__ rs, int* __restrict__ fil,
                         int* __restrict__ srt, int E) {
    int e = blockIdx.x * blockDim.x + threadIdx.x;
    if (e >= E) return;
    const int d = dst[e];
    const int pos = rs[d] + atomicAdd(&fil[d], 1);
    srt[pos] = src[e];
}

__global__ void csr_fill_norm(const int* __restrict__ dst, const int* __restrict__ src,
                              const float* __restrict__ ew, const int* __restrict__ rs,
                              int* __restrict__ fil, int* __restrict__ srt,
                              float* __restrict__ nrm, const float* __restrict__ dis, int E) {
    int e = blockIdx.x * blockDim.x + threadIdx.x;
    if (e >= E) return;
    const int d = dst[e];
    const int s = src[e];
    const int pos = rs[d] + atomicAdd(&fil[d], 1);
    srt[pos] = s;
    nrm[pos] = dis[s] * ew[e] * dis[d];
}

__global__ void deg_accum(const int* __restrict__ dst, const float* __restrict__ ew,
                          float* __restrict__ deg, int E) {
    int e = blockIdx.x * blockDim.x + threadIdx.x;
    if (e < E) atomicAdd(&deg[dst[e]], ew[e]);
}

__global__ void deg_to_dis(float* __restrict__ deg, int n) {
    int i = blockIdx.x * blockDim.x + threadIdx.x;
    if (i < n) {
        float d = deg[i];
        deg[i] = (d > 0.f) ? (1.0f / sqrtf(d)) : 0.f;
    }
}

// ---------------- gather aggregation (bf16 features): out[dst] += mean feat[src] ----------------
// one wave per dst row; lane reads 2 bf16 (4B) -> 256B/row coalesced

__launch_bounds__(256)
__global__ void agg_bf16(const __bf16* __restrict__ feat, const int* __restrict__ rs,
                         const int* __restrict__ srt, float* __restrict__ out, int n_dst) {
    const int wave = threadIdx.x >> 6;
    const int lane = threadIdx.x & 63;
    const int row = blockIdx.x * 4 + wave;
    if (row >= n_dst) return;
    const int b = rs[row], e = rs[row + 1];
    const int cnt = e - b;
    if (cnt <= 0) return;
    float ax = 0.f, ay = 0.f;
    for (int j = b; j < e; ++j) {
        const int s = srt[j];
        const unsigned int v = *reinterpret_cast<const unsigned int*>(&feat[(size_t)s * 128 + (lane << 1)]);
        float lo, hi;
        {
            unsigned int ul = (v & 0xffffu) << 16;
            unsigned int uh = v & 0xffff0000u;
            lo = __builtin_bit_cast(float, ul);
            hi = __builtin_bit_cast(float, uh);
        }
        ax += lo; ay += hi;
    }
    const float inv = 1.0f / (float)cnt;
    float2* o = reinterpret_cast<float2*>(&out[(size_t)row * 128 + (lane << 1)]);
    float2 cur = *o;
    cur.x += ax * inv; cur.y += ay * inv;
    *o = cur;
}

// ---------------- collapsed tail ----------------

// y[row] = dot(relu(x[row]), w) — one wave/row
__launch_bounds__(256)
__global__ void dotv1(const float* __restrict__ x, const float* __restrict__ w,
                      float* __restrict__ y, int n) {
    const int wave = threadIdx.x >> 6;
    const int lane = threadIdx.x & 63;
    const int row = blockIdx.x * 4 + wave;
    if (row >= n) return;
    const float2 v = *reinterpret_cast<const float2*>(&x[(size_t)row * 128 + (lane << 1)]);
    const float2 wv = *reinterpret_cast<const float2*>(&w[lane << 1]);
    float s = fmaxf(v.x, 0.f) * wv.x + fmaxf(v.y, 0.f) * wv.y;
#pragma unroll
    for (int off = 32; off; off >>= 1) s += __shfl_xor(s, off);
    if (lane == 0) y[row] = s;
}

// two dots of relu(x[row]) with wa, wb
__launch_bounds__(256)
__global__ void dotv2(const float* __restrict__ x, const float* __restrict__ wa,
                      const float* __restrict__ wb, float* __restrict__ ya,
                      float* __restrict__ yb, int n) {
    const int wave = threadIdx.x >> 6;
    const int lane = threadIdx.x & 63;
    const int row = blockIdx.x * 4 + wave;
    if (row >= n) return;
    const float2 v = *reinterpret_cast<const float2*>(&x[(size_t)row * 128 + (lane << 1)]);
    const float2 va = *reinterpret_cast<const float2*>(&wa[lane << 1]);
    const float2 vb = *reinterpret_cast<const float2*>(&wb[lane << 1]);
    const float rx = fmaxf(v.x, 0.f), ry = fmaxf(v.y, 0.f);
    float sa = rx * va.x + ry * va.y;
    float sb = rx * vb.x + ry * vb.y;
#pragma unroll
    for (int off = 32; off; off >>= 1) { sa += __shfl_xor(sa, off); sb += __shfl_xor(sb, off); }
    if (lane == 0) { ya[row] = sa; yb[row] = sb; }
}

__launch_bounds__(256)
__global__ void wgt_kernel(const float* __restrict__ table_x, const float* __restrict__ q,
                           const float* __restrict__ sc, float* __restrict__ wgt) {
    const int wave = threadIdx.x >> 6;
    const int lane = threadIdx.x & 63;
    const int row = blockIdx.x * 4 + wave;
    if (row >= NT) return;
    const float* x = table_x + (size_t)row * 512;
    float dot = 0.f, ss = 0.f;
#pragma unroll
    for (int j = 0; j < 8; ++j) {
        const float xv = x[lane + 64 * j];
        const float qv_ = q[lane + 64 * j];
        dot = fmaf(xv, qv_, dot);
        ss = fmaf(xv, xv, ss);
    }
#pragma unroll
    for (int off = 32; off; off >>= 1) {
        dot += __shfl_xor(dot, off);
        ss += __shfl_xor(ss, off);
    }
    if (lane == 0) {
        const float nx = fmaxf(sqrtf(ss), 1e-12f);
        wgt[row] = fmaxf(dot, 0.f) / (nx * sc[2]);
    }
}

// y0[i] = tabv_s[i] + mean_rev(colv) + mean_ts(tabv_t) + c0 + wgt[i]*qdot
// 16 lanes per row
__launch_bounds__(256)
__global__ void y0_kernel(const float* __restrict__ tabv_s, const float* __restrict__ colv,
                          const float* __restrict__ tabv_t,
                          const int* __restrict__ rs_rev, const int* __restrict__ srt_rev,
                          const int* __restrict__ rs_ts, const int* __restrict__ srt_ts,
                          const float* __restrict__ wgt, const float* __restrict__ sc,
                          float* __restrict__ y0, int n) {
    const int row = blockIdx.x * 16 + (threadIdx.x >> 4);
    const int l = threadIdx.x & 15;
    if (row >= n) return;
    float s1 = 0.f, s2 = 0.f;
    const int b1 = rs_rev[row], e1 = rs_rev[row + 1];
    for (int j = b1 + l; j < e1; j += 16) s1 += colv[srt_rev[j]];
    const int b2 = rs_ts[row], e2 = rs_ts[row + 1];
    for (int j = b2 + l; j < e2; j += 16) s2 += tabv_t[srt_ts[j]];
#pragma unroll
    for (int off = 8; off; off >>= 1) { s1 += __shfl_xor(s1, off); s2 += __shfl_xor(s2, off); }
    if (l == 0) {
        const int c1 = e1 - b1, c2 = e2 - b2;
        float v = tabv_s[row] + sc[1] + wgt[row] * sc[0];
        if (c1 > 0) v += s1 / (float)c1;
        if (c2 > 0) v += s2 / (float)c2;
        y0[row] = v;
    }
}

// scalar APPNP step; 16 lanes per row
__launch_bounds__(256)
__global__ void appnp_s(const float* __restrict__ z, const float* __restrict__ y0,
                        const int* __restrict__ rs, const int* __restrict__ srt,
                        const float* __restrict__ nrm, const float* __restrict__ dis,
                        float* __restrict__ zo, int n) {
    const int row = blockIdx.x * 16 + (threadIdx.x >> 4);
    const int l = threadIdx.x & 15;
    if (row >= n) return;
    const int b = rs[row], e = rs[row + 1];
    float s = 0.f;
    for (int j = b + l; j < e; j += 16) s = fmaf(nrm[j], z[srt[j]], s);
#pragma unroll
    for (int off = 8; off; off >>= 1) s += __shfl_xor(s, off);
    if (l == 0) {
        const float d = dis[row];
        zo[row] = 0.8f * (s + d * d * z[row]) + 0.2f * y0[row];
    }
}

__global__ void final_add(const float* __restrict__ z, const float* __restrict__ blin,
                          float* __restrict__ out, int n) {
    int i = blockIdx.x * blockDim.x + threadIdx.x;
    if (i < n) out[i] = z[i] + blin[0];
}

// ---------------- host ----------------

extern "C" void kernel_launch(void* const* d_in, const int* in_sizes, int n_in,
                              void* d_out, int out_size, void* d_ws, size_t ws_size,
                              hipStream_t stream) {
    const float* table_x  = (const float*)d_in[0];
    const float* column_x = (const float*)d_in[1];
    const float* q        = (const float*)d_in[2];
    const float* Wl1_tc  = (const float*)d_in[3];  const float* bl1_tc  = (const float*)d_in[4];  const float* Wr1_tc  = (const float*)d_in[5];
    const float* Wl1_rev = (const float*)d_in[6];  const float* bl1_rev = (const float*)d_in[7];  const float* Wr1_rev = (const float*)d_in[8];
    const float* Wl1_cs  = (const float*)d_in[9];  const float* bl1_cs  = (const float*)d_in[10]; const float* Wr1_cs  = (const float*)d_in[11];
    const float* Wl1_ns  = (const float*)d_in[12]; const float* bl1_ns  = (const float*)d_in[13]; const float* Wr1_ns  = (const float*)d_in[14];
    const float* Wl1_ds  = (const float*)d_in[15]; const float* bl1_ds  = (const float*)d_in[16]; const float* Wr1_ds  = (const float*)d_in[17];
    const float* Wl1_ts  = (const float*)d_in[18]; const float* bl1_ts  = (const float*)d_in[19]; const float* Wr1_ts  = (const float*)d_in[20];
    const float* Wl2_rev = (const float*)d_in[21]; const float* bl2_rev = (const float*)d_in[22]; const float* Wr2_rev = (const float*)d_in[23];
    const float* Wl2_ts  = (const float*)d_in[24]; const float* bl2_ts  = (const float*)d_in[25]; const float* Wr2_ts  = (const float*)d_in[26];
    const float* Wq   = (const float*)d_in[27]; const float* bq   = (const float*)d_in[28];
    const float* Wlin = (const float*)d_in[29]; const float* blin = (const float*)d_in[30];
    const float* ts_ew = (const float*)d_in[31];
    const int* tc_src = (const int*)d_in[32];
    const int* tc_dst = (const int*)d_in[33];
    const int* cs_ei  = (const int*)d_in[34];
    const int* ns_ei  = (const int*)d_in[35];
    const int* ds_ei  = (const int*)d_in[36];
    const int* ts_ei  = (const int*)d_in[37];

    // ---- workspace carve ----
    char* w = (char*)d_ws;
    size_t off = 0;
    auto alloc = [&](size_t bytes) -> void* {
        void* p = w + off;
        off += (bytes + 255) & ~(size_t)255;
        return p;
    };
    __bf16* projC = (__bf16*)alloc((size_t)NC * 128 * 2);
    __bf16* projT = (__bf16*)alloc((size_t)NT * 128 * 2);
    float* f_col1 = (float*)alloc((size_t)NC * 128 * 4);
    float* f_tab1 = (float*)alloc((size_t)NT * 128 * 4);
    float* f_colv = (float*)alloc((size_t)NC * 4);
    float* f_tvs  = (float*)alloc((size_t)NT * 4);
    float* f_tvt  = (float*)alloc((size_t)NT * 4);
    float* f_wgt  = (float*)alloc((size_t)NT * 4);
    float* f_dis  = (float*)alloc((size_t)NT * 4);
    float* f_y0   = (float*)alloc((size_t)NT * 4);
    float* f_za   = (float*)alloc((size_t)NT * 4);
    float* f_zb   = (float*)alloc((size_t)NT * 4);
    float* f_norm = (float*)alloc((size_t)E_TS * 4);
    __bf16* WtS1c  = (__bf16*)alloc((size_t)128 * 256 * 2);
    __bf16* Wt_cs  = (__bf16*)alloc((size_t)128 * 256 * 2);
    __bf16* Wt_ns  = (__bf16*)alloc((size_t)128 * 256 * 2);
    __bf16* Wt_ds  = (__bf16*)alloc((size_t)128 * 256 * 2);
    __bf16* Wt_rev = (__bf16*)alloc((size_t)128 * 256 * 2);
    __bf16* Wt_tc  = (__bf16*)alloc((size_t)128 * 512 * 2);
    __bf16* WtS1t  = (__bf16*)alloc((size_t)128 * 512 * 2);
    __bf16* Wt_ts  = (__bf16*)alloc((size_t)128 * 512 * 2);
    float* f_biasC  = (float*)alloc(128 * 4);
    float* f_biasT1 = (float*)alloc(128 * 4);
    float* f_w2s  = (float*)alloc(128 * 4);
    float* f_wrev = (float*)alloc(128 * 4);
    float* f_wts  = (float*)alloc(128 * 4);
    float* f_sc   = (float*)alloc(16 * 4);
    int* i_cnt     = (int*)alloc((size_t)(NC + 1) * 4);
    int* i_rs_tmp  = (int*)alloc((size_t)(NC + 1) * 4);
    int* i_srt_tmp = (int*)alloc((size_t)E_SIM * 4);
    int* i_rs_rev  = (int*)alloc((size_t)(NT + 1) * 4);
    int* i_srt_rev = (int*)alloc((size_t)E_TC * 4);
    int* i_rs_ts   = (int*)alloc((size_t)(NT + 1) * 4);
    int* i_srt_ts  = (int*)alloc((size_t)E_TS * 4);
    int* i_bsum = (int*)alloc(512 * 4);
    int* i_boff = (int*)alloc(513 * 4);
    if (off > ws_size) return;

    auto cdiv = [](int a, int b) { return (a + b - 1) / b; };

    // ---- weight/vector prep ----
    wprep<<<cdiv(128 * 256, 256), 256, 0, stream>>>(Wr1_tc, Wr1_cs, Wr1_ns, Wr1_ds, WtS1c, 256);
    wprep<<<cdiv(128 * 256, 256), 256, 0, stream>>>(Wl1_cs, nullptr, nullptr, nullptr, Wt_cs, 256);
    wprep<<<cdiv(128 * 256, 256), 256, 0, stream>>>(Wl1_ns, nullptr, nullptr, nullptr, Wt_ns, 256);
    wprep<<<cdiv(128 * 256, 256), 256, 0, stream>>>(Wl1_ds, nullptr, nullptr, nullptr, Wt_ds, 256);
    wprep<<<cdiv(128 * 256, 256), 256, 0, stream>>>(Wl1_rev, nullptr, nullptr, nullptr, Wt_rev, 256);
    wprep<<<cdiv(128 * 512, 256), 256, 0, stream>>>(Wl1_tc, nullptr, nullptr, nullptr, Wt_tc, 512);
    wprep<<<cdiv(128 * 512, 256), 256, 0, stream>>>(Wr1_rev, Wr1_ts, nullptr, nullptr, WtS1t, 512);
    wprep<<<cdiv(128 * 512, 256), 256, 0, stream>>>(Wl1_ts, nullptr, nullptr, nullptr, Wt_ts, 512);
    add4_kernel<<<1, 128, 0, stream>>>(bl1_tc, bl1_cs, bl1_ns, bl1_ds, f_biasC, 128);
    add4_kernel<<<1, 128, 0, stream>>>(bl1_rev, bl1_ts, nullptr, nullptr, f_biasT1, 128);
    vecprep<<<1, 128, 0, stream>>>(q, Wq, bq, Wr2_rev, Wr2_ts, Wl2_rev, Wl2_ts,
                                   bl2_rev, bl2_ts, Wlin, f_w2s, f_wrev, f_wts, f_sc);

    auto build_csr = [&](const int* dst, const int* src, int E, int N, int* rs, int* srt) {
        hipMemsetAsync(i_cnt, 0, (size_t)N * 4, stream);
        count_dst<<<cdiv(E, 256), 256, 0, stream>>>(dst, i_cnt, E);
        const int nblk = cdiv(N, 1024);
        scan_phase1<<<nblk, 256, 0, stream>>>(i_cnt, rs, i_bsum, N);
        scan_phase2<<<1, 64, 0, stream>>>(i_bsum, i_boff, nblk);
        scan_phase3<<<cdiv(N, 256), 256, 0, stream>>>(rs, i_boff, N, nblk);
        hipMemsetAsync(i_cnt, 0, (size_t)N * 4, stream);
        csr_fill<<<cdiv(E, 256), 256, 0, stream>>>(dst, src, rs, i_cnt, srt, E);
    };

    const int gNC = cdiv(NC, 128);  // MF=2 -> 128 rows/block
    const int gNT = cdiv(NT, 64);   // MF=1 -> 64 rows/block

    // ---- layer 1: col1 ----
    gemm_mfma<256, 2><<<gNC, 256, 0, stream>>>(column_x, WtS1c, f_biasC, f_col1, nullptr, NC);
    gemm_mfma<512, 1><<<gNT, 256, 0, stream>>>(table_x, Wt_tc, nullptr, nullptr, projT, NT);
    build_csr(tc_dst, tc_src, E_TC, NC, i_rs_tmp, i_srt_tmp);
    agg_bf16<<<cdiv(NC, 4), 256, 0, stream>>>(projT, i_rs_tmp, i_srt_tmp, f_col1, NC);

    gemm_mfma<256, 2><<<gNC, 256, 0, stream>>>(column_x, Wt_cs, nullptr, nullptr, projC, NC);
    build_csr(cs_ei + E_SIM, cs_ei, E_SIM, NC, i_rs_tmp, i_srt_tmp);
    agg_bf16<<<cdiv(NC, 4), 256, 0, stream>>>(projC, i_rs_tmp, i_srt_tmp, f_col1, NC);

    gemm_mfma<256, 2><<<gNC, 256, 0, stream>>>(column_x, Wt_ns, nullptr, nullptr, projC, NC);
    build_csr(ns_ei + E_SIM, ns_ei, E_SIM, NC, i_rs_tmp, i_srt_tmp);
    agg_bf16<<<cdiv(NC, 4), 256, 0, stream>>>(projC, i_rs_tmp, i_srt_tmp, f_col1, NC);

    gemm_mfma<256, 2><<<gNC, 256, 0, stream>>>(column_x, Wt_ds, nullptr, nullptr, projC, NC);
    build_csr(ds_ei + E_SIM, ds_ei, E_SIM, NC, i_rs_tmp, i_srt_tmp);
    agg_bf16<<<cdiv(NC, 4), 256, 0, stream>>>(projC, i_rs_tmp, i_srt_tmp, f_col1, NC);

    // ---- layer 1: tab1 ----
    gemm_mfma<512, 1><<<gNT, 256, 0, stream>>>(table_x, WtS1t, f_biasT1, f_tab1, nullptr, NT);
    build_csr(tc_src, tc_dst, E_TC, NT, i_rs_rev, i_srt_rev);
    gemm_mfma<256, 2><<<gNC, 256, 0, stream>>>(column_x, Wt_rev, nullptr, nullptr, projC, NC);
    agg_bf16<<<cdiv(NT, 4), 256, 0, stream>>>(projC, i_rs_rev, i_srt_rev, f_tab1, NT);

    // ts CSR + APPNP normalization
    {
        const int* ts_src = ts_ei;
        const int* ts_dst = ts_ei + E_TS;
        hipMemsetAsync(i_cnt, 0, (size_t)NT * 4, stream);
        count_dst<<<cdiv(E_TS, 256), 256, 0, stream>>>(ts_dst, i_cnt, E_TS);
        const int nblk = cdiv(NT, 1024);
        scan_phase1<<<nblk, 256, 0, stream>>>(i_cnt, i_rs_ts, i_bsum, NT);
        scan_phase2<<<1, 64, 0, stream>>>(i_bsum, i_boff, nblk);
        scan_phase3<<<cdiv(NT, 256), 256, 0, stream>>>(i_rs_ts, i_boff, NT, nblk);
        fill_f32<<<cdiv(NT, 256), 256, 0, stream>>>(f_dis, 1.0f, NT);
        deg_accum<<<cdiv(E_TS, 256), 256, 0, stream>>>(ts_dst, ts_ew, f_dis, E_TS);
        deg_to_dis<<<cdiv(NT, 256), 256, 0, stream>>>(f_dis, NT);
        hipMemsetAsync(i_cnt, 0, (size_t)NT * 4, stream);
        csr_fill_norm<<<cdiv(E_TS, 256), 256, 0, stream>>>(ts_dst, ts_src, ts_ew, i_rs_ts,
                                                           i_cnt, i_srt_ts, f_norm, f_dis, E_TS);
    }
    gemm_mfma<512, 1><<<gNT, 256, 0, stream>>>(table_x, Wt_ts, nullptr, nullptr, projT, NT);
    agg_bf16<<<cdiv(NT, 4), 256, 0, stream>>>(projT, i_rs_ts, i_srt_ts, f_tab1, NT);

    // ---- collapsed tail (relu fused into dots) ----
    dotv1<<<cdiv(NC, 4), 256, 0, stream>>>(f_col1, f_wrev, f_colv, NC);
    dotv2<<<cdiv(NT, 4), 256, 0, stream>>>(f_tab1, f_w2s, f_wts, f_tvs, f_tvt, NT);
    wgt_kernel<<<cdiv(NT, 4), 256, 0, stream>>>(table_x, q, f_sc, f_wgt);
    y0_kernel<<<cdiv(NT, 16), 256, 0, stream>>>(f_tvs, f_colv, f_tvt, i_rs_rev, i_srt_rev,
                                                i_rs_ts, i_srt_ts, f_wgt, f_sc, f_y0, NT);

    // ---- scalar APPNP ----
    const float* zin = f_y0;
    float* zout = f_za;
    for (int it = 0; it < 10; ++it) {
        appnp_s<<<cdiv(NT, 16), 256, 0, stream>>>(zin, f_y0, i_rs_ts, i_srt_ts,
                                                  f_norm, f_dis, zout, NT);
        zin = zout;
        zout = (zout == f_za) ? f_zb : f_za;
    }

    final_add<<<cdiv(NT, 256), 256, 0, stream>>>(zin, blin, (float*)d_out, NT);
}

// Round 3
// 1255.161 us; speedup vs baseline: 2.0037x; 1.0931x over previous
//
#include <hip/hip_runtime.h>

#define NT 20000
#define NC 100000
#define DT 512
#define DC 256
#define E_TC 100000
#define E_SIM 800000
#define E_TS 640000

typedef float f32x4 __attribute__((ext_vector_type(4)));
typedef __bf16 bf16x8 __attribute__((ext_vector_type(8)));

// ---------------- small elementwise kernels ----------------

__global__ void add4_kernel(const float* __restrict__ a, const float* __restrict__ b,
                            const float* __restrict__ c, const float* __restrict__ d,
                            float* __restrict__ o, int n) {
    int i = blockIdx.x * blockDim.x + threadIdx.x;
    if (i < n) {
        float v = a[i] + b[i];
        if (c) v += c[i];
        if (d) v += d[i];
        o[i] = v;
    }
}

__global__ void fill_f32(float* __restrict__ p, float v, int n) {
    int i = blockIdx.x * blockDim.x + threadIdx.x;
    if (i < n) p[i] = v;
}

// Wt[n][k] = bf16( sum_i W_i[k][128 cols -> n] ), W_i are [K][128] f32
__global__ void wprep(const float* __restrict__ w0, const float* __restrict__ w1,
                      const float* __restrict__ w2, const float* __restrict__ w3,
                      __bf16* __restrict__ wt, int K) {
    int idx = blockIdx.x * blockDim.x + threadIdx.x;
    if (idx >= 128 * K) return;
    const int n = idx / K, k = idx - n * K;
    float s = w0[(size_t)k * 128 + n];
    if (w1) s += w1[(size_t)k * 128 + n];
    if (w2) s += w2[(size_t)k * 128 + n];
    if (w3) s += w3[(size_t)k * 128 + n];
    wt[(size_t)n * K + k] = (__bf16)s;
}

// collapsed layer-2 weight vectors + query scalars. 1 block, 128 threads.
// sc[0]=qdot, sc[1]=c0, sc[2]=qn
__global__ void vecprep(const float* __restrict__ q, const float* __restrict__ Wq,
                        const float* __restrict__ bq,
                        const float* __restrict__ Wr2_rev, const float* __restrict__ Wr2_ts,
                        const float* __restrict__ Wl2_rev, const float* __restrict__ Wl2_ts,
                        const float* __restrict__ bl2_rev, const float* __restrict__ bl2_ts,
                        const float* __restrict__ Wlin,
                        float* __restrict__ w2s, float* __restrict__ wrev,
                        float* __restrict__ wts, float* __restrict__ sc) {
    const int t = threadIdx.x;  // 0..127
    float a = 0.f, b = 0.f, c = 0.f;
    for (int h = 0; h < 128; ++h) {
        const float wl = Wlin[h];
        a = fmaf(Wr2_rev[(size_t)t * 128 + h] + Wr2_ts[(size_t)t * 128 + h], wl, a);
        b = fmaf(Wl2_rev[(size_t)t * 128 + h], wl, b);
        c = fmaf(Wl2_ts[(size_t)t * 128 + h], wl, c);
    }
    w2s[t] = a; wrev[t] = b; wts[t] = c;
    float qv = bq[t];
    for (int k = 0; k < 512; ++k) qv = fmaf(q[k], Wq[(size_t)k * 128 + t], qv);
    __shared__ float sh[128];
    sh[t] = qv * Wlin[t];
    __syncthreads();
    for (int st = 64; st >= 1; st >>= 1) { if (t < st) sh[t] += sh[t + st]; __syncthreads(); }
    if (t == 0) sc[0] = sh[0];
    __syncthreads();
    sh[t] = (bl2_rev[t] + bl2_ts[t]) * Wlin[t];
    __syncthreads();
    for (int st = 64; st >= 1; st >>= 1) { if (t < st) sh[t] += sh[t + st]; __syncthreads(); }
    if (t == 0) sc[1] = sh[0];
    __syncthreads();
    float ss = 0.f;
    for (int k = t; k < 512; k += 128) { const float v = q[k]; ss = fmaf(v, v, ss); }
    sh[t] = ss;
    __syncthreads();
    for (int st = 64; st >= 1; st >>= 1) { if (t < st) sh[t] += sh[t + st]; __syncthreads(); }
    if (t == 0) sc[2] = fmaxf(sqrtf(sh[0]), 1e-12f);
}

// ---------------- multi-output MFMA GEMM ----------------
// Y_o[M,128](bf16) = X[M,K]f32 @ Wt_o[128,K]bf16^T; output 0 optionally +bias.
// LDS-free, 64 rows/block (1 row-frag per wave), reads X once for all NOUT outputs.

template<int NOUT> struct BPack { const __bf16* wt[NOUT]; };
template<int NOUT> struct YPack { __bf16* yb[NOUT]; };

template<int K, int NOUT>
__launch_bounds__(256)
__global__ void gemm_multi(const float* __restrict__ X, BPack<NOUT> wp,
                           const float* __restrict__ bias, YPack<NOUT> yp, int M) {
    const int lane = threadIdx.x & 63;
    const int wave = threadIdx.x >> 6;
    const int l15 = lane & 15;
    const int kg = lane >> 4;                         // 0..3
    const int rowbase = blockIdx.x * 64 + wave * 16;
    int r = rowbase + l15;
    r = (r < M) ? r : (M - 1);
    const float* baseA = X + (size_t)r * K + kg * 8;
    const size_t boff = (size_t)l15 * K + kg * 8;

    f32x4 acc[NOUT][8];
#pragma unroll
    for (int o = 0; o < NOUT; ++o)
#pragma unroll
        for (int n = 0; n < 8; ++n) acc[o][n] = (f32x4)0.f;

    for (int ks = 0; ks < K / 32; ++ks) {
        const float4 x0 = *reinterpret_cast<const float4*>(baseA + ks * 32);
        const float4 x1 = *reinterpret_cast<const float4*>(baseA + ks * 32 + 4);
        bf16x8 af;
        af[0] = (__bf16)x0.x; af[1] = (__bf16)x0.y; af[2] = (__bf16)x0.z; af[3] = (__bf16)x0.w;
        af[4] = (__bf16)x1.x; af[5] = (__bf16)x1.y; af[6] = (__bf16)x1.z; af[7] = (__bf16)x1.w;
#pragma unroll
        for (int o = 0; o < NOUT; ++o) {
#pragma unroll
            for (int n = 0; n < 8; ++n) {
                const bf16x8 bf = *reinterpret_cast<const bf16x8*>(wp.wt[o] + (size_t)(n * 16) * K + boff + ks * 32);
                acc[o][n] = __builtin_amdgcn_mfma_f32_16x16x32_bf16(af, bf, acc[o][n], 0, 0, 0);
            }
        }
    }
    // C layout: col=lane&15, row=(lane>>4)*4+reg
#pragma unroll
    for (int o = 0; o < NOUT; ++o) {
        __bf16* Y = yp.yb[o];
#pragma unroll
        for (int n = 0; n < 8; ++n) {
            const int col = n * 16 + l15;
            const float bv = (o == 0 && bias) ? bias[col] : 0.f;
#pragma unroll
            for (int rr = 0; rr < 4; ++rr) {
                const int row = rowbase + kg * 4 + rr;
                if (row < M) Y[(size_t)row * 128 + col] = (__bf16)(acc[o][n][rr] + bv);
            }
        }
    }
}

// ---------------- CSR build (counting sort by dst, interleaved multi-graph) ----------------

__global__ void count_g(const int* __restrict__ dst, int* __restrict__ cnt, int E, int g, int ng) {
    int e = blockIdx.x * blockDim.x + threadIdx.x;
    if (e < E) atomicAdd(&cnt[dst[e] * ng + g], 1);
}

__launch_bounds__(256)
__global__ void scan_phase1(const int* __restrict__ cnt, int* __restrict__ rs,
                            int* __restrict__ bsum, int N) {
    __shared__ int sh[256];
    const int t = threadIdx.x;
    const int base = blockIdx.x * 1024 + t * 4;
    int v0 = 0, v1 = 0, v2 = 0, v3 = 0;
    if (base + 0 < N) v0 = cnt[base + 0];
    if (base + 1 < N) v1 = cnt[base + 1];
    if (base + 2 < N) v2 = cnt[base + 2];
    if (base + 3 < N) v3 = cnt[base + 3];
    const int tot = v0 + v1 + v2 + v3;
    sh[t] = tot;
    __syncthreads();
#pragma unroll
    for (int off = 1; off < 256; off <<= 1) {
        int y = (t >= off) ? sh[t - off] : 0;
        __syncthreads();
        sh[t] += y;
        __syncthreads();
    }
    const int incl = sh[t];
    const int excl = incl - tot;
    if (base + 0 < N) rs[base + 0] = excl;
    if (base + 1 < N) rs[base + 1] = excl + v0;
    if (base + 2 < N) rs[base + 2] = excl + v0 + v1;
    if (base + 3 < N) rs[base + 3] = excl + v0 + v1 + v2;
    if (t == 255) bsum[blockIdx.x] = incl;
}

__global__ void scan_phase2(const int* __restrict__ bsum, int* __restrict__ boff, int nblk) {
    const int l = threadIdx.x;  // 64 threads
    int carry = 0;
    for (int base = 0; base < nblk; base += 64) {
        const int v = (base + l < nblk) ? bsum[base + l] : 0;
        int inc = v;
#pragma unroll
        for (int off = 1; off < 64; off <<= 1) {
            const int y = __shfl_up(inc, off);
            if (l >= off) inc += y;
        }
        if (base + l < nblk) boff[base + l] = carry + inc - v;
        carry += __shfl(inc, 63);
    }
    if (l == 0) boff[nblk] = carry;
}

__global__ void scan_phase3(int* __restrict__ rs, const int* __restrict__ boff, int N, int nblk) {
    int i = blockIdx.x * blockDim.x + threadIdx.x;
    if (i < N) rs[i] += boff[i >> 10];
    if (i == 0) rs[N] = boff[nblk];
}

// fill with concatenated-feature-space src index + per-edge 1/cnt scale
__global__ void csr_fill_g(const int* __restrict__ dst, const int* __restrict__ src,
                           const int* __restrict__ rs, int* __restrict__ fil,
                           int* __restrict__ srt, float* __restrict__ scl,
                           int E, int g, int ng, int srcoff) {
    int e = blockIdx.x * blockDim.x + threadIdx.x;
    if (e >= E) return;
    const int key = dst[e] * ng + g;
    const int b = rs[key];
    const int pos = b + atomicAdd(&fil[key], 1);
    srt[pos] = srcoff + src[e];
    scl[pos] = 1.0f / (float)(rs[key + 1] - b);
}

__global__ void csr_fill_norm(const int* __restrict__ dst, const int* __restrict__ src,
                              const float* __restrict__ ew, const int* __restrict__ rs,
                              int* __restrict__ fil, int* __restrict__ srt,
                              float* __restrict__ nrm, const float* __restrict__ dis, int E) {
    int e = blockIdx.x * blockDim.x + threadIdx.x;
    if (e >= E) return;
    const int d = dst[e];
    const int s = src[e];
    const int pos = rs[d] + atomicAdd(&fil[d], 1);
    srt[pos] = s;
    nrm[pos] = dis[s] * ew[e] * dis[d];
}

__global__ void deg_accum(const int* __restrict__ dst, const float* __restrict__ ew,
                          float* __restrict__ deg, int E) {
    int e = blockIdx.x * blockDim.x + threadIdx.x;
    if (e < E) atomicAdd(&deg[dst[e]], ew[e]);
}

__global__ void deg_to_dis(float* __restrict__ deg, int n) {
    int i = blockIdx.x * blockDim.x + threadIdx.x;
    if (i < n) {
        float d = deg[i];
        deg[i] = (d > 0.f) ? (1.0f / sqrtf(d)) : 0.f;
    }
}

// ---------------- fused row kernels ----------------
// One wave per dst row. 16 lanes per edge-slot (16B = 8 bf16 per lane), 4 slots.
// colv[row] = dot(relu(self_row + sum_g mean_g), wvec)

__launch_bounds__(256)
__global__ void col_fused(const __bf16* __restrict__ selfRow, const __bf16* __restrict__ featCat,
                          const int* __restrict__ rs, const int* __restrict__ srt,
                          const float* __restrict__ scl, const float* __restrict__ wvec,
                          float* __restrict__ outv, int ng, int n) {
    const int wave = threadIdx.x >> 6;
    const int lane = threadIdx.x & 63;
    const int sg = lane >> 4;      // edge slot 0..3
    const int sl = lane & 15;      // col group: cols sl*8..sl*8+7
    const int row = blockIdx.x * 4 + wave;
    if (row >= n) return;
    const int b = rs[row * ng], e = rs[row * ng + ng];
    float s8[8] = {0.f, 0.f, 0.f, 0.f, 0.f, 0.f, 0.f, 0.f};
    for (int j = b + sg; j < e; j += 4) {
        const int s = srt[j];
        const float w = scl[j];
        const bf16x8 v = *reinterpret_cast<const bf16x8*>(&featCat[(size_t)s * 128 + sl * 8]);
#pragma unroll
        for (int t = 0; t < 8; ++t) s8[t] = fmaf(w, (float)v[t], s8[t]);
    }
    // combine edge slots (lanes differing in bits 4,5)
#pragma unroll
    for (int t = 0; t < 8; ++t) {
        s8[t] += __shfl_xor(s8[t], 16);
        s8[t] += __shfl_xor(s8[t], 32);
    }
    const bf16x8 g = *reinterpret_cast<const bf16x8*>(&selfRow[(size_t)row * 128 + sl * 8]);
    const float4 w0 = *reinterpret_cast<const float4*>(&wvec[sl * 8]);
    const float4 w1 = *reinterpret_cast<const float4*>(&wvec[sl * 8 + 4]);
    const float ww[8] = {w0.x, w0.y, w0.z, w0.w, w1.x, w1.y, w1.z, w1.w};
    float d = 0.f;
#pragma unroll
    for (int t = 0; t < 8; ++t) d = fmaf(fmaxf(s8[t] + (float)g[t], 0.f), ww[t], d);
#pragma unroll
    for (int off = 8; off; off >>= 1) d += __shfl_xor(d, off);
    if (lane == 0) outv[row] = d;
}

// same but two dot vectors -> ya, yb
__launch_bounds__(256)
__global__ void tab_fused(const __bf16* __restrict__ selfRow, const __bf16* __restrict__ featCat,
                          const int* __restrict__ rs, const int* __restrict__ srt,
                          const float* __restrict__ scl,
                          const float* __restrict__ wa, const float* __restrict__ wb,
                          float* __restrict__ ya, float* __restrict__ yb, int ng, int n) {
    const int wave = threadIdx.x >> 6;
    const int lane = threadIdx.x & 63;
    const int sg = lane >> 4;
    const int sl = lane & 15;
    const int row = blockIdx.x * 4 + wave;
    if (row >= n) return;
    const int b = rs[row * ng], e = rs[row * ng + ng];
    float s8[8] = {0.f, 0.f, 0.f, 0.f, 0.f, 0.f, 0.f, 0.f};
    for (int j = b + sg; j < e; j += 4) {
        const int s = srt[j];
        const float w = scl[j];
        const bf16x8 v = *reinterpret_cast<const bf16x8*>(&featCat[(size_t)s * 128 + sl * 8]);
#pragma unroll
        for (int t = 0; t < 8; ++t) s8[t] = fmaf(w, (float)v[t], s8[t]);
    }
#pragma unroll
    for (int t = 0; t < 8; ++t) {
        s8[t] += __shfl_xor(s8[t], 16);
        s8[t] += __shfl_xor(s8[t], 32);
    }
    const bf16x8 g = *reinterpret_cast<const bf16x8*>(&selfRow[(size_t)row * 128 + sl * 8]);
    const float4 a0 = *reinterpret_cast<const float4*>(&wa[sl * 8]);
    const float4 a1 = *reinterpret_cast<const float4*>(&wa[sl * 8 + 4]);
    const float4 b0 = *reinterpret_cast<const float4*>(&wb[sl * 8]);
    const float4 b1 = *reinterpret_cast<const float4*>(&wb[sl * 8 + 4]);
    const float wwa[8] = {a0.x, a0.y, a0.z, a0.w, a1.x, a1.y, a1.z, a1.w};
    const float wwb[8] = {b0.x, b0.y, b0.z, b0.w, b1.x, b1.y, b1.z, b1.w};
    float da = 0.f, db = 0.f;
#pragma unroll
    for (int t = 0; t < 8; ++t) {
        const float rv = fmaxf(s8[t] + (float)g[t], 0.f);
        da = fmaf(rv, wwa[t], da);
        db = fmaf(rv, wwb[t], db);
    }
#pragma unroll
    for (int off = 8; off; off >>= 1) { da += __shfl_xor(da, off); db += __shfl_xor(db, off); }
    if (lane == 0) { ya[row] = da; yb[row] = db; }
}

// ---------------- tail ----------------

__launch_bounds__(256)
__global__ void wgt_kernel(const float* __restrict__ table_x, const float* __restrict__ q,
                           const float* __restrict__ sc, float* __restrict__ wgt) {
    const int wave = threadIdx.x >> 6;
    const int lane = threadIdx.x & 63;
    const int row = blockIdx.x * 4 + wave;
    if (row >= NT) return;
    const float* x = table_x + (size_t)row * 512;
    float dot = 0.f, ss = 0.f;
#pragma unroll
    for (int j = 0; j < 8; ++j) {
        const float xv = x[lane + 64 * j];
        const float qv_ = q[lane + 64 * j];
        dot = fmaf(xv, qv_, dot);
        ss = fmaf(xv, xv, ss);
    }
#pragma unroll
    for (int off = 32; off; off >>= 1) {
        dot += __shfl_xor(dot, off);
        ss += __shfl_xor(ss, off);
    }
    if (lane == 0) {
        const float nx = fmaxf(sqrtf(ss), 1e-12f);
        wgt[row] = fmaxf(dot, 0.f) / (nx * sc[2]);
    }
}

// y0[i] = tvs[i] + sum_j scl2[j]*val2[srt2[j]] + c0 + wgt[i]*qdot ; 16 lanes/row
__launch_bounds__(256)
__global__ void y0_joint(const float* __restrict__ tvs, const float* __restrict__ val2,
                         const int* __restrict__ rs2, const int* __restrict__ srt2,
                         const float* __restrict__ scl2, const float* __restrict__ wgt,
                         const float* __restrict__ sc, float* __restrict__ y0, int n) {
    const int row = blockIdx.x * 16 + (threadIdx.x >> 4);
    const int l = threadIdx.x & 15;
    if (row >= n) return;
    const int b = rs2[row * 2], e = rs2[row * 2 + 2];
    float s = 0.f;
    for (int j = b + l; j < e; j += 16) s = fmaf(scl2[j], val2[srt2[j]], s);
#pragma unroll
    for (int off = 8; off; off >>= 1) s += __shfl_xor(s, off);
    if (l == 0) y0[row] = tvs[row] + sc[1] + wgt[row] * sc[0] + s;
}

// scalar APPNP step; 16 lanes per row
__launch_bounds__(256)
__global__ void appnp_s(const float* __restrict__ z, const float* __restrict__ y0,
                        const int* __restrict__ rs, const int* __restrict__ srt,
                        const float* __restrict__ nrm, const float* __restrict__ dis,
                        float* __restrict__ zo, int n) {
    const int row = blockIdx.x * 16 + (threadIdx.x >> 4);
    const int l = threadIdx.x & 15;
    if (row >= n) return;
    const int b = rs[row], e = rs[row + 1];
    float s = 0.f;
    for (int j = b + l; j < e; j += 16) s = fmaf(nrm[j], z[srt[j]], s);
#pragma unroll
    for (int off = 8; off; off >>= 1) s += __shfl_xor(s, off);
    if (l == 0) {
        const float d = dis[row];
        zo[row] = 0.8f * (s + d * d * z[row]) + 0.2f * y0[row];
    }
}

__global__ void final_add(const float* __restrict__ z, const float* __restrict__ blin,
                          float* __restrict__ out, int n) {
    int i = blockIdx.x * blockDim.x + threadIdx.x;
    if (i < n) out[i] = z[i] + blin[0];
}

// ---------------- host ----------------

extern "C" void kernel_launch(void* const* d_in, const int* in_sizes, int n_in,
                              void* d_out, int out_size, void* d_ws, size_t ws_size,
                              hipStream_t stream) {
    const float* table_x  = (const float*)d_in[0];
    const float* column_x = (const float*)d_in[1];
    const float* q        = (const float*)d_in[2];
    const float* Wl1_tc  = (const float*)d_in[3];  const float* bl1_tc  = (const float*)d_in[4];  const float* Wr1_tc  = (const float*)d_in[5];
    const float* Wl1_rev = (const float*)d_in[6];  const float* bl1_rev = (const float*)d_in[7];  const float* Wr1_rev = (const float*)d_in[8];
    const float* Wl1_cs  = (const float*)d_in[9];  const float* bl1_cs  = (const float*)d_in[10]; const float* Wr1_cs  = (const float*)d_in[11];
    const float* Wl1_ns  = (const float*)d_in[12]; const float* bl1_ns  = (const float*)d_in[13]; const float* Wr1_ns  = (const float*)d_in[14];
    const float* Wl1_ds  = (const float*)d_in[15]; const float* bl1_ds  = (const float*)d_in[16]; const float* Wr1_ds  = (const float*)d_in[17];
    const float* Wl1_ts  = (const float*)d_in[18]; const float* bl1_ts  = (const float*)d_in[19]; const float* Wr1_ts  = (const float*)d_in[20];
    const float* Wl2_rev = (const float*)d_in[21]; const float* bl2_rev = (const float*)d_in[22]; const float* Wr2_rev = (const float*)d_in[23];
    const float* Wl2_ts  = (const float*)d_in[24]; const float* bl2_ts  = (const float*)d_in[25]; const float* Wr2_ts  = (const float*)d_in[26];
    const float* Wq   = (const float*)d_in[27]; const float* bq   = (const float*)d_in[28];
    const float* Wlin = (const float*)d_in[29]; const float* blin = (const float*)d_in[30];
    const float* ts_ew = (const float*)d_in[31];
    const int* tc_src = (const int*)d_in[32];
    const int* tc_dst = (const int*)d_in[33];
    const int* cs_ei  = (const int*)d_in[34];
    const int* ns_ei  = (const int*)d_in[35];
    const int* ds_ei  = (const int*)d_in[36];
    const int* ts_ei  = (const int*)d_in[37];

    // ---- workspace carve ----
    char* w = (char*)d_ws;
    size_t off = 0;
    auto alloc = [&](size_t bytes) -> void* {
        void* p = w + off;
        off += (bytes + 255) & ~(size_t)255;
        return p;
    };
    // concatenated feature spaces (single allocs -> guaranteed contiguous slices)
    __bf16* featC = (__bf16*)alloc(((size_t)3 * NC + NT) * 128 * 2);  // cs | ns | ds | tc
    __bf16* featT = (__bf16*)alloc(((size_t)NC + NT) * 128 * 2);      // rev | ts
    __bf16* projC_cs  = featC;
    __bf16* projC_ns  = featC + (size_t)NC * 128;
    __bf16* projC_ds  = featC + (size_t)2 * NC * 128;
    __bf16* projT_tc  = featC + (size_t)3 * NC * 128;
    __bf16* projC_rev = featT;
    __bf16* projT_ts  = featT + (size_t)NC * 128;
    __bf16* gemmC = (__bf16*)alloc((size_t)NC * 128 * 2);  // self term (incl bias)
    __bf16* gemmT = (__bf16*)alloc((size_t)NT * 128 * 2);
    float* val2  = (float*)alloc((size_t)(NC + NT) * 4);   // colv | tvt
    float* f_colv = val2;
    float* f_tvt  = val2 + NC;
    float* f_tvs = (float*)alloc((size_t)NT * 4);
    float* f_wgt = (float*)alloc((size_t)NT * 4);
    float* f_dis = (float*)alloc((size_t)NT * 4);
    float* f_y0  = (float*)alloc((size_t)NT * 4);
    float* f_za  = (float*)alloc((size_t)NT * 4);
    float* f_zb  = (float*)alloc((size_t)NT * 4);
    float* f_norm = (float*)alloc((size_t)E_TS * 4);
    __bf16* WtS1c  = (__bf16*)alloc((size_t)128 * 256 * 2);
    __bf16* Wt_cs  = (__bf16*)alloc((size_t)128 * 256 * 2);
    __bf16* Wt_ns  = (__bf16*)alloc((size_t)128 * 256 * 2);
    __bf16* Wt_ds  = (__bf16*)alloc((size_t)128 * 256 * 2);
    __bf16* Wt_rev = (__bf16*)alloc((size_t)128 * 256 * 2);
    __bf16* Wt_tc  = (__bf16*)alloc((size_t)128 * 512 * 2);
    __bf16* WtS1t  = (__bf16*)alloc((size_t)128 * 512 * 2);
    __bf16* Wt_ts  = (__bf16*)alloc((size_t)128 * 512 * 2);
    float* f_biasC  = (float*)alloc(128 * 4);
    float* f_biasT1 = (float*)alloc(128 * 4);
    float* f_w2s  = (float*)alloc(128 * 4);
    float* f_wrev = (float*)alloc(128 * 4);
    float* f_wts  = (float*)alloc(128 * 4);
    float* f_sc   = (float*)alloc(16 * 4);
    int* i_cnt  = (int*)alloc((size_t)(4 * NC + 1) * 4);   // shared count/fill scratch (max size)
    int* i_rs4  = (int*)alloc((size_t)(4 * NC + 1) * 4);
    int* i_srt4 = (int*)alloc((size_t)(3 * E_SIM + E_TC) * 4);
    float* f_scl4 = (float*)alloc((size_t)(3 * E_SIM + E_TC) * 4);
    int* i_rs2  = (int*)alloc((size_t)(2 * NT + 1) * 4);
    int* i_srt2 = (int*)alloc((size_t)(E_TC + E_TS) * 4);
    float* f_scl2 = (float*)alloc((size_t)(E_TC + E_TS) * 4);
    int* i_rs_ts  = (int*)alloc((size_t)(NT + 1) * 4);
    int* i_srt_ts = (int*)alloc((size_t)E_TS * 4);
    int* i_bsum = (int*)alloc(512 * 4);
    int* i_boff = (int*)alloc(513 * 4);
    if (off > ws_size) return;

    auto cdiv = [](int a, int b) { return (a + b - 1) / b; };

    // ---- weight/vector prep ----
    wprep<<<cdiv(128 * 256, 256), 256, 0, stream>>>(Wr1_tc, Wr1_cs, Wr1_ns, Wr1_ds, WtS1c, 256);
    wprep<<<cdiv(128 * 256, 256), 256, 0, stream>>>(Wl1_cs, nullptr, nullptr, nullptr, Wt_cs, 256);
    wprep<<<cdiv(128 * 256, 256), 256, 0, stream>>>(Wl1_ns, nullptr, nullptr, nullptr, Wt_ns, 256);
    wprep<<<cdiv(128 * 256, 256), 256, 0, stream>>>(Wl1_ds, nullptr, nullptr, nullptr, Wt_ds, 256);
    wprep<<<cdiv(128 * 256, 256), 256, 0, stream>>>(Wl1_rev, nullptr, nullptr, nullptr, Wt_rev, 256);
    wprep<<<cdiv(128 * 512, 256), 256, 0, stream>>>(Wl1_tc, nullptr, nullptr, nullptr, Wt_tc, 512);
    wprep<<<cdiv(128 * 512, 256), 256, 0, stream>>>(Wr1_rev, Wr1_ts, nullptr, nullptr, WtS1t, 512);
    wprep<<<cdiv(128 * 512, 256), 256, 0, stream>>>(Wl1_ts, nullptr, nullptr, nullptr, Wt_ts, 512);
    add4_kernel<<<1, 128, 0, stream>>>(bl1_tc, bl1_cs, bl1_ns, bl1_ds, f_biasC, 128);
    add4_kernel<<<1, 128, 0, stream>>>(bl1_rev, bl1_ts, nullptr, nullptr, f_biasT1, 128);
    vecprep<<<1, 128, 0, stream>>>(q, Wq, bq, Wr2_rev, Wr2_ts, Wl2_rev, Wl2_ts,
                                   bl2_rev, bl2_ts, Wlin, f_w2s, f_wrev, f_wts, f_sc);

    // ---- GEMMs (3 passes total) ----
    {
        BPack<3> wp; wp.wt[0] = WtS1c; wp.wt[1] = Wt_cs; wp.wt[2] = Wt_ns;
        YPack<3> yp; yp.yb[0] = gemmC; yp.yb[1] = projC_cs; yp.yb[2] = projC_ns;
        gemm_multi<256, 3><<<cdiv(NC, 64), 256, 0, stream>>>(column_x, wp, f_biasC, yp, NC);
    }
    {
        BPack<2> wp; wp.wt[0] = Wt_ds; wp.wt[1] = Wt_rev;
        YPack<2> yp; yp.yb[0] = projC_ds; yp.yb[1] = projC_rev;
        gemm_multi<256, 2><<<cdiv(NC, 64), 256, 0, stream>>>(column_x, wp, nullptr, yp, NC);
    }
    {
        BPack<3> wp; wp.wt[0] = WtS1t; wp.wt[1] = Wt_tc; wp.wt[2] = Wt_ts;
        YPack<3> yp; yp.yb[0] = gemmT; yp.yb[1] = projT_tc; yp.yb[2] = projT_ts;
        gemm_multi<512, 3><<<cdiv(NT, 64), 256, 0, stream>>>(table_x, wp, f_biasT1, yp, NT);
    }

    auto scan = [&](int* rs, int N) {
        const int nblk = cdiv(N, 1024);
        scan_phase1<<<nblk, 256, 0, stream>>>(i_cnt, rs, i_bsum, N);
        scan_phase2<<<1, 64, 0, stream>>>(i_bsum, i_boff, nblk);
        scan_phase3<<<cdiv(N, 256), 256, 0, stream>>>(rs, i_boff, N, nblk);
    };

    // ---- joint column-side CSR (cs, ns, ds, tc), ng=4 ----
    hipMemsetAsync(i_cnt, 0, (size_t)4 * NC * 4, stream);
    count_g<<<cdiv(E_SIM, 256), 256, 0, stream>>>(cs_ei + E_SIM, i_cnt, E_SIM, 0, 4);
    count_g<<<cdiv(E_SIM, 256), 256, 0, stream>>>(ns_ei + E_SIM, i_cnt, E_SIM, 1, 4);
    count_g<<<cdiv(E_SIM, 256), 256, 0, stream>>>(ds_ei + E_SIM, i_cnt, E_SIM, 2, 4);
    count_g<<<cdiv(E_TC, 256), 256, 0, stream>>>(tc_dst, i_cnt, E_TC, 3, 4);
    scan(i_rs4, 4 * NC);
    hipMemsetAsync(i_cnt, 0, (size_t)4 * NC * 4, stream);
    csr_fill_g<<<cdiv(E_SIM, 256), 256, 0, stream>>>(cs_ei + E_SIM, cs_ei, i_rs4, i_cnt, i_srt4, f_scl4, E_SIM, 0, 4, 0);
    csr_fill_g<<<cdiv(E_SIM, 256), 256, 0, stream>>>(ns_ei + E_SIM, ns_ei, i_rs4, i_cnt, i_srt4, f_scl4, E_SIM, 1, 4, NC);
    csr_fill_g<<<cdiv(E_SIM, 256), 256, 0, stream>>>(ds_ei + E_SIM, ds_ei, i_rs4, i_cnt, i_srt4, f_scl4, E_SIM, 2, 4, 2 * NC);
    csr_fill_g<<<cdiv(E_TC, 256), 256, 0, stream>>>(tc_dst, tc_src, i_rs4, i_cnt, i_srt4, f_scl4, E_TC, 3, 4, 3 * NC);

    // ---- joint table-side CSR (rev, ts), ng=2 ----
    hipMemsetAsync(i_cnt, 0, (size_t)2 * NT * 4, stream);
    count_g<<<cdiv(E_TC, 256), 256, 0, stream>>>(tc_src, i_cnt, E_TC, 0, 2);
    count_g<<<cdiv(E_TS, 256), 256, 0, stream>>>(ts_ei + E_TS, i_cnt, E_TS, 1, 2);
    scan(i_rs2, 2 * NT);
    hipMemsetAsync(i_cnt, 0, (size_t)2 * NT * 4, stream);
    csr_fill_g<<<cdiv(E_TC, 256), 256, 0, stream>>>(tc_src, tc_dst, i_rs2, i_cnt, i_srt2, f_scl2, E_TC, 0, 2, 0);
    csr_fill_g<<<cdiv(E_TS, 256), 256, 0, stream>>>(ts_ei + E_TS, ts_ei, i_rs2, i_cnt, i_srt2, f_scl2, E_TS, 1, 2, NC);

    // ---- ts CSR + APPNP normalization ----
    {
        const int* ts_src = ts_ei;
        const int* ts_dst = ts_ei + E_TS;
        hipMemsetAsync(i_cnt, 0, (size_t)NT * 4, stream);
        count_g<<<cdiv(E_TS, 256), 256, 0, stream>>>(ts_dst, i_cnt, E_TS, 0, 1);
        scan(i_rs_ts, NT);
        fill_f32<<<cdiv(NT, 256), 256, 0, stream>>>(f_dis, 1.0f, NT);
        deg_accum<<<cdiv(E_TS, 256), 256, 0, stream>>>(ts_dst, ts_ew, f_dis, E_TS);
        deg_to_dis<<<cdiv(NT, 256), 256, 0, stream>>>(f_dis, NT);
        hipMemsetAsync(i_cnt, 0, (size_t)NT * 4, stream);
        csr_fill_norm<<<cdiv(E_TS, 256), 256, 0, stream>>>(ts_dst, ts_src, ts_ew, i_rs_ts,
                                                           i_cnt, i_srt_ts, f_norm, f_dis, E_TS);
    }

    // ---- fused aggregation + relu + dot ----
    col_fused<<<cdiv(NC, 4), 256, 0, stream>>>(gemmC, featC, i_rs4, i_srt4, f_scl4,
                                               f_wrev, f_colv, 4, NC);
    tab_fused<<<cdiv(NT, 4), 256, 0, stream>>>(gemmT, featT, i_rs2, i_srt2, f_scl2,
                                               f_w2s, f_wts, f_tvs, f_tvt, 2, NT);

    // ---- tail ----
    wgt_kernel<<<cdiv(NT, 4), 256, 0, stream>>>(table_x, q, f_sc, f_wgt);
    y0_joint<<<cdiv(NT, 16), 256, 0, stream>>>(f_tvs, val2, i_rs2, i_srt2, f_scl2,
                                               f_wgt, f_sc, f_y0, NT);

    const float* zin = f_y0;
    float* zout = f_za;
    for (int it = 0; it < 10; ++it) {
        appnp_s<<<cdiv(NT, 16), 256, 0, stream>>>(zin, f_y0, i_rs_ts, i_srt_ts,
                                                  f_norm, f_dis, zout, NT);
        zin = zout;
        zout = (zout == f_za) ? f_zb : f_za;
    }

    final_add<<<cdiv(NT, 256), 256, 0, stream>>>(zin, blin, (float*)d_out, NT);
}

// Round 4
// 1029.857 us; speedup vs baseline: 2.4421x; 1.2188x over previous
//
#include <hip/hip_runtime.h>

#define NT 20000
#define NC 100000
#define DT 512
#define DC 256
#define E_TC 100000
#define E_SIM 800000
#define E_TS 640000

typedef float f32x4 __attribute__((ext_vector_type(4)));
typedef __bf16 bf16x8 __attribute__((ext_vector_type(8)));

// ---------------- small elementwise kernels ----------------

__global__ void add4_kernel(const float* __restrict__ a, const float* __restrict__ b,
                            const float* __restrict__ c, const float* __restrict__ d,
                            float* __restrict__ o, int n) {
    int i = blockIdx.x * blockDim.x + threadIdx.x;
    if (i < n) {
        float v = a[i] + b[i];
        if (c) v += c[i];
        if (d) v += d[i];
        o[i] = v;
    }
}

__global__ void fill_f32(float* __restrict__ p, float v, int n) {
    int i = blockIdx.x * blockDim.x + threadIdx.x;
    if (i < n) p[i] = v;
}

// Wt[n][k] = bf16( sum_i W_i[k][128 cols -> n] ), W_i are [K][128] f32
__global__ void wprep(const float* __restrict__ w0, const float* __restrict__ w1,
                      const float* __restrict__ w2, const float* __restrict__ w3,
                      __bf16* __restrict__ wt, int K) {
    int idx = blockIdx.x * blockDim.x + threadIdx.x;
    if (idx >= 128 * K) return;
    const int n = idx / K, k = idx - n * K;
    float s = w0[(size_t)k * 128 + n];
    if (w1) s += w1[(size_t)k * 128 + n];
    if (w2) s += w2[(size_t)k * 128 + n];
    if (w3) s += w3[(size_t)k * 128 + n];
    wt[(size_t)n * K + k] = (__bf16)s;
}

// collapsed layer-2 weight vectors + query scalars. 1 block, 128 threads.
// sc[0]=qdot, sc[1]=c0, sc[2]=qn
__global__ void vecprep(const float* __restrict__ q, const float* __restrict__ Wq,
                        const float* __restrict__ bq,
                        const float* __restrict__ Wr2_rev, const float* __restrict__ Wr2_ts,
                        const float* __restrict__ Wl2_rev, const float* __restrict__ Wl2_ts,
                        const float* __restrict__ bl2_rev, const float* __restrict__ bl2_ts,
                        const float* __restrict__ Wlin,
                        float* __restrict__ w2s, float* __restrict__ wrev,
                        float* __restrict__ wts, float* __restrict__ sc) {
    const int t = threadIdx.x;  // 0..127
    float a = 0.f, b = 0.f, c = 0.f;
    for (int h = 0; h < 128; ++h) {
        const float wl = Wlin[h];
        a = fmaf(Wr2_rev[(size_t)t * 128 + h] + Wr2_ts[(size_t)t * 128 + h], wl, a);
        b = fmaf(Wl2_rev[(size_t)t * 128 + h], wl, b);
        c = fmaf(Wl2_ts[(size_t)t * 128 + h], wl, c);
    }
    w2s[t] = a; wrev[t] = b; wts[t] = c;
    float qv = bq[t];
    for (int k = 0; k < 512; ++k) qv = fmaf(q[k], Wq[(size_t)k * 128 + t], qv);
    __shared__ float sh[128];
    sh[t] = qv * Wlin[t];
    __syncthreads();
    for (int st = 64; st >= 1; st >>= 1) { if (t < st) sh[t] += sh[t + st]; __syncthreads(); }
    if (t == 0) sc[0] = sh[0];
    __syncthreads();
    sh[t] = (bl2_rev[t] + bl2_ts[t]) * Wlin[t];
    __syncthreads();
    for (int st = 64; st >= 1; st >>= 1) { if (t < st) sh[t] += sh[t + st]; __syncthreads(); }
    if (t == 0) sc[1] = sh[0];
    __syncthreads();
    float ss = 0.f;
    for (int k = t; k < 512; k += 128) { const float v = q[k]; ss = fmaf(v, v, ss); }
    sh[t] = ss;
    __syncthreads();
    for (int st = 64; st >= 1; st >>= 1) { if (t < st) sh[t] += sh[t + st]; __syncthreads(); }
    if (t == 0) sc[2] = fmaxf(sqrtf(sh[0]), 1e-12f);
}

// ---------------- LDS-staged MFMA GEMM ----------------
// Y[M,128](bf16) = X[M,K]f32 @ Wt[128,K]bf16^T (+bias). One output per pass.
// Block: 256 threads (4 waves), M-tile 128 (32 rows/wave, acc[2][8]).
// B staged per 128-k chunk in LDS (32 KB), XOR-swizzled 16B units: slot ^= (row&7)
// -> 2-way bank aliasing (free) on both write and ds_read_b128.

template<int K>
__launch_bounds__(256, 3)
__global__ void gemm_lds(const float* __restrict__ X, const __bf16* __restrict__ Wt,
                         const float* __restrict__ bias, __bf16* __restrict__ Y, int M) {
    __shared__ __bf16 Bs[128 * 128];   // [row n][128 k-chunk], swizzled
    const int t = threadIdx.x;
    const int lane = t & 63;
    const int wave = t >> 6;
    const int l15 = lane & 15;
    const int kg = lane >> 4;          // 0..3
    const int rowbase = blockIdx.x * 128 + wave * 32;

    const float* baseA[2];
#pragma unroll
    for (int m = 0; m < 2; ++m) {
        int r = rowbase + m * 16 + l15;
        r = (r < M) ? r : (M - 1);
        baseA[m] = X + (size_t)r * K + kg * 8;
    }

    f32x4 acc[2][8];
#pragma unroll
    for (int m = 0; m < 2; ++m)
#pragma unroll
        for (int n = 0; n < 8; ++n) acc[m][n] = (f32x4)0.f;

#pragma unroll
    for (int c = 0; c < K / 128; ++c) {
        if (c) __syncthreads();
        // stage 128x128 bf16 chunk: 2048 16B-units, 8 per thread
#pragma unroll
        for (int i = 0; i < 8; ++i) {
            const int u = t + i * 256;
            const int row = u >> 4;
            const int ku = u & 15;
            const bf16x8 v = *reinterpret_cast<const bf16x8*>(Wt + (size_t)row * K + c * 128 + ku * 8);
            *reinterpret_cast<bf16x8*>(&Bs[row * 128 + ((ku ^ (row & 7)) << 3)]) = v;
        }
        __syncthreads();
#pragma unroll
        for (int ks = 0; ks < 4; ++ks) {
            bf16x8 af[2];
#pragma unroll
            for (int m = 0; m < 2; ++m) {
                const float4 x0 = *reinterpret_cast<const float4*>(baseA[m] + c * 128 + ks * 32);
                const float4 x1 = *reinterpret_cast<const float4*>(baseA[m] + c * 128 + ks * 32 + 4);
                bf16x8 tt;
                tt[0] = (__bf16)x0.x; tt[1] = (__bf16)x0.y; tt[2] = (__bf16)x0.z; tt[3] = (__bf16)x0.w;
                tt[4] = (__bf16)x1.x; tt[5] = (__bf16)x1.y; tt[6] = (__bf16)x1.z; tt[7] = (__bf16)x1.w;
                af[m] = tt;
            }
            const int ku = ks * 4 + kg;
#pragma unroll
            for (int n = 0; n < 8; ++n) {
                const int r = n * 16 + l15;
                const bf16x8 bf = *reinterpret_cast<const bf16x8*>(&Bs[r * 128 + ((ku ^ (r & 7)) << 3)]);
                acc[0][n] = __builtin_amdgcn_mfma_f32_16x16x32_bf16(af[0], bf, acc[0][n], 0, 0, 0);
                acc[1][n] = __builtin_amdgcn_mfma_f32_16x16x32_bf16(af[1], bf, acc[1][n], 0, 0, 0);
            }
        }
    }
    // C layout: col = n*16 + l15, row = rowbase + m*16 + kg*4 + rr
#pragma unroll
    for (int n = 0; n < 8; ++n) {
        const int col = n * 16 + l15;
        const float bv = bias ? bias[col] : 0.f;
#pragma unroll
        for (int m = 0; m < 2; ++m) {
#pragma unroll
            for (int rr = 0; rr < 4; ++rr) {
                const int row = rowbase + m * 16 + kg * 4 + rr;
                if (row < M) Y[(size_t)row * 128 + col] = (__bf16)(acc[m][n][rr] + bv);
            }
        }
    }
}

// ---------------- CSR build (counting sort by dst, interleaved multi-graph) ----------------

__global__ void count_g(const int* __restrict__ dst, int* __restrict__ cnt, int E, int g, int ng) {
    int e = blockIdx.x * blockDim.x + threadIdx.x;
    if (e < E) atomicAdd(&cnt[dst[e] * ng + g], 1);
}

__launch_bounds__(256)
__global__ void scan_phase1(const int* __restrict__ cnt, int* __restrict__ rs,
                            int* __restrict__ bsum, int N) {
    __shared__ int sh[256];
    const int t = threadIdx.x;
    const int base = blockIdx.x * 1024 + t * 4;
    int v0 = 0, v1 = 0, v2 = 0, v3 = 0;
    if (base + 0 < N) v0 = cnt[base + 0];
    if (base + 1 < N) v1 = cnt[base + 1];
    if (base + 2 < N) v2 = cnt[base + 2];
    if (base + 3 < N) v3 = cnt[base + 3];
    const int tot = v0 + v1 + v2 + v3;
    sh[t] = tot;
    __syncthreads();
#pragma unroll
    for (int off = 1; off < 256; off <<= 1) {
        int y = (t >= off) ? sh[t - off] : 0;
        __syncthreads();
        sh[t] += y;
        __syncthreads();
    }
    const int incl = sh[t];
    const int excl = incl - tot;
    if (base + 0 < N) rs[base + 0] = excl;
    if (base + 1 < N) rs[base + 1] = excl + v0;
    if (base + 2 < N) rs[base + 2] = excl + v0 + v1;
    if (base + 3 < N) rs[base + 3] = excl + v0 + v1 + v2;
    if (t == 255) bsum[blockIdx.x] = incl;
}

__global__ void scan_phase2(const int* __restrict__ bsum, int* __restrict__ boff, int nblk) {
    const int l = threadIdx.x;  // 64 threads
    int carry = 0;
    for (int base = 0; base < nblk; base += 64) {
        const int v = (base + l < nblk) ? bsum[base + l] : 0;
        int inc = v;
#pragma unroll
        for (int off = 1; off < 64; off <<= 1) {
            const int y = __shfl_up(inc, off);
            if (l >= off) inc += y;
        }
        if (base + l < nblk) boff[base + l] = carry + inc - v;
        carry += __shfl(inc, 63);
    }
    if (l == 0) boff[nblk] = carry;
}

__global__ void scan_phase3(int* __restrict__ rs, const int* __restrict__ boff, int N, int nblk) {
    int i = blockIdx.x * blockDim.x + threadIdx.x;
    if (i < N) rs[i] += boff[i >> 10];
    if (i == 0) rs[N] = boff[nblk];
}

// fill with concatenated-feature-space src index + per-edge 1/cnt scale
__global__ void csr_fill_g(const int* __restrict__ dst, const int* __restrict__ src,
                           const int* __restrict__ rs, int* __restrict__ fil,
                           int* __restrict__ srt, float* __restrict__ scl,
                           int E, int g, int ng, int srcoff) {
    int e = blockIdx.x * blockDim.x + threadIdx.x;
    if (e >= E) return;
    const int key = dst[e] * ng + g;
    const int b = rs[key];
    const int pos = b + atomicAdd(&fil[key], 1);
    srt[pos] = srcoff + src[e];
    scl[pos] = 1.0f / (float)(rs[key + 1] - b);
}

__global__ void csr_fill_norm(const int* __restrict__ dst, const int* __restrict__ src,
                              const float* __restrict__ ew, const int* __restrict__ rs,
                              int* __restrict__ fil, int* __restrict__ srt,
                              float* __restrict__ nrm, const float* __restrict__ dis, int E) {
    int e = blockIdx.x * blockDim.x + threadIdx.x;
    if (e >= E) return;
    const int d = dst[e];
    const int s = src[e];
    const int pos = rs[d] + atomicAdd(&fil[d], 1);
    srt[pos] = s;
    nrm[pos] = dis[s] * ew[e] * dis[d];
}

__global__ void deg_accum(const int* __restrict__ dst, const float* __restrict__ ew,
                          float* __restrict__ deg, int E) {
    int e = blockIdx.x * blockDim.x + threadIdx.x;
    if (e < E) atomicAdd(&deg[dst[e]], ew[e]);
}

__global__ void deg_to_dis(float* __restrict__ deg, int n) {
    int i = blockIdx.x * blockDim.x + threadIdx.x;
    if (i < n) {
        float d = deg[i];
        deg[i] = (d > 0.f) ? (1.0f / sqrtf(d)) : 0.f;
    }
}

// ---------------- fused row kernels ----------------
// One wave per dst row. 16 lanes per edge-slot (16B = 8 bf16 per lane), 4 slots.
// colv[row] = dot(relu(self_row + sum_g mean_g), wvec)

__launch_bounds__(256)
__global__ void col_fused(const __bf16* __restrict__ selfRow, const __bf16* __restrict__ featCat,
                          const int* __restrict__ rs, const int* __restrict__ srt,
                          const float* __restrict__ scl, const float* __restrict__ wvec,
                          float* __restrict__ outv, int ng, int n) {
    const int wave = threadIdx.x >> 6;
    const int lane = threadIdx.x & 63;
    const int sg = lane >> 4;      // edge slot 0..3
    const int sl = lane & 15;      // col group: cols sl*8..sl*8+7
    const int row = blockIdx.x * 4 + wave;
    if (row >= n) return;
    const int b = rs[row * ng], e = rs[row * ng + ng];
    float s8[8] = {0.f, 0.f, 0.f, 0.f, 0.f, 0.f, 0.f, 0.f};
    for (int j = b + sg; j < e; j += 4) {
        const int s = srt[j];
        const float w = scl[j];
        const bf16x8 v = *reinterpret_cast<const bf16x8*>(&featCat[(size_t)s * 128 + sl * 8]);
#pragma unroll
        for (int t = 0; t < 8; ++t) s8[t] = fmaf(w, (float)v[t], s8[t]);
    }
    // combine edge slots (lanes differing in bits 4,5)
#pragma unroll
    for (int t = 0; t < 8; ++t) {
        s8[t] += __shfl_xor(s8[t], 16);
        s8[t] += __shfl_xor(s8[t], 32);
    }
    const bf16x8 g = *reinterpret_cast<const bf16x8*>(&selfRow[(size_t)row * 128 + sl * 8]);
    const float4 w0 = *reinterpret_cast<const float4*>(&wvec[sl * 8]);
    const float4 w1 = *reinterpret_cast<const float4*>(&wvec[sl * 8 + 4]);
    const float ww[8] = {w0.x, w0.y, w0.z, w0.w, w1.x, w1.y, w1.z, w1.w};
    float d = 0.f;
#pragma unroll
    for (int t = 0; t < 8; ++t) d = fmaf(fmaxf(s8[t] + (float)g[t], 0.f), ww[t], d);
#pragma unroll
    for (int off = 8; off; off >>= 1) d += __shfl_xor(d, off);
    if (lane == 0) outv[row] = d;
}

// same but two dot vectors -> ya, yb
__launch_bounds__(256)
__global__ void tab_fused(const __bf16* __restrict__ selfRow, const __bf16* __restrict__ featCat,
                          const int* __restrict__ rs, const int* __restrict__ srt,
                          const float* __restrict__ scl,
                          const float* __restrict__ wa, const float* __restrict__ wb,
                          float* __restrict__ ya, float* __restrict__ yb, int ng, int n) {
    const int wave = threadIdx.x >> 6;
    const int lane = threadIdx.x & 63;
    const int sg = lane >> 4;
    const int sl = lane & 15;
    const int row = blockIdx.x * 4 + wave;
    if (row >= n) return;
    const int b = rs[row * ng], e = rs[row * ng + ng];
    float s8[8] = {0.f, 0.f, 0.f, 0.f, 0.f, 0.f, 0.f, 0.f};
    for (int j = b + sg; j < e; j += 4) {
        const int s = srt[j];
        const float w = scl[j];
        const bf16x8 v = *reinterpret_cast<const bf16x8*>(&featCat[(size_t)s * 128 + sl * 8]);
#pragma unroll
        for (int t = 0; t < 8; ++t) s8[t] = fmaf(w, (float)v[t], s8[t]);
    }
#pragma unroll
    for (int t = 0; t < 8; ++t) {
        s8[t] += __shfl_xor(s8[t], 16);
        s8[t] += __shfl_xor(s8[t], 32);
    }
    const bf16x8 g = *reinterpret_cast<const bf16x8*>(&selfRow[(size_t)row * 128 + sl * 8]);
    const float4 a0 = *reinterpret_cast<const float4*>(&wa[sl * 8]);
    const float4 a1 = *reinterpret_cast<const float4*>(&wa[sl * 8 + 4]);
    const float4 b0 = *reinterpret_cast<const float4*>(&wb[sl * 8]);
    const float4 b1 = *reinterpret_cast<const float4*>(&wb[sl * 8 + 4]);
    const float wwa[8] = {a0.x, a0.y, a0.z, a0.w, a1.x, a1.y, a1.z, a1.w};
    const float wwb[8] = {b0.x, b0.y, b0.z, b0.w, b1.x, b1.y, b1.z, b1.w};
    float da = 0.f, db = 0.f;
#pragma unroll
    for (int t = 0; t < 8; ++t) {
        const float rv = fmaxf(s8[t] + (float)g[t], 0.f);
        da = fmaf(rv, wwa[t], da);
        db = fmaf(rv, wwb[t], db);
    }
#pragma unroll
    for (int off = 8; off; off >>= 1) { da += __shfl_xor(da, off); db += __shfl_xor(db, off); }
    if (lane == 0) { ya[row] = da; yb[row] = db; }
}

// ---------------- tail ----------------

__launch_bounds__(256)
__global__ void wgt_kernel(const float* __restrict__ table_x, const float* __restrict__ q,
                           const float* __restrict__ sc, float* __restrict__ wgt) {
    const int wave = threadIdx.x >> 6;
    const int lane = threadIdx.x & 63;
    const int row = blockIdx.x * 4 + wave;
    if (row >= NT) return;
    const float* x = table_x + (size_t)row * 512;
    float dot = 0.f, ss = 0.f;
#pragma unroll
    for (int j = 0; j < 8; ++j) {
        const float xv = x[lane + 64 * j];
        const float qv_ = q[lane + 64 * j];
        dot = fmaf(xv, qv_, dot);
        ss = fmaf(xv, xv, ss);
    }
#pragma unroll
    for (int off = 32; off; off >>= 1) {
        dot += __shfl_xor(dot, off);
        ss += __shfl_xor(ss, off);
    }
    if (lane == 0) {
        const float nx = fmaxf(sqrtf(ss), 1e-12f);
        wgt[row] = fmaxf(dot, 0.f) / (nx * sc[2]);
    }
}

// y0[i] = tvs[i] + sum_j scl2[j]*val2[srt2[j]] + c0 + wgt[i]*qdot ; 16 lanes/row
__launch_bounds__(256)
__global__ void y0_joint(const float* __restrict__ tvs, const float* __restrict__ val2,
                         const int* __restrict__ rs2, const int* __restrict__ srt2,
                         const float* __restrict__ scl2, const float* __restrict__ wgt,
                         const float* __restrict__ sc, float* __restrict__ y0, int n) {
    const int row = blockIdx.x * 16 + (threadIdx.x >> 4);
    const int l = threadIdx.x & 15;
    if (row >= n) return;
    const int b = rs2[row * 2], e = rs2[row * 2 + 2];
    float s = 0.f;
    for (int j = b + l; j < e; j += 16) s = fmaf(scl2[j], val2[srt2[j]], s);
#pragma unroll
    for (int off = 8; off; off >>= 1) s += __shfl_xor(s, off);
    if (l == 0) y0[row] = tvs[row] + sc[1] + wgt[row] * sc[0] + s;
}

// scalar APPNP step; 16 lanes per row
__launch_bounds__(256)
__global__ void appnp_s(const float* __restrict__ z, const float* __restrict__ y0,
                        const int* __restrict__ rs, const int* __restrict__ srt,
                        const float* __restrict__ nrm, const float* __restrict__ dis,
                        float* __restrict__ zo, int n) {
    const int row = blockIdx.x * 16 + (threadIdx.x >> 4);
    const int l = threadIdx.x & 15;
    if (row >= n) return;
    const int b = rs[row], e = rs[row + 1];
    float s = 0.f;
    for (int j = b + l; j < e; j += 16) s = fmaf(nrm[j], z[srt[j]], s);
#pragma unroll
    for (int off = 8; off; off >>= 1) s += __shfl_xor(s, off);
    if (l == 0) {
        const float d = dis[row];
        zo[row] = 0.8f * (s + d * d * z[row]) + 0.2f * y0[row];
    }
}

__global__ void final_add(const float* __restrict__ z, const float* __restrict__ blin,
                          float* __restrict__ out, int n) {
    int i = blockIdx.x * blockDim.x + threadIdx.x;
    if (i < n) out[i] = z[i] + blin[0];
}

// ---------------- host ----------------

extern "C" void kernel_launch(void* const* d_in, const int* in_sizes, int n_in,
                              void* d_out, int out_size, void* d_ws, size_t ws_size,
                              hipStream_t stream) {
    const float* table_x  = (const float*)d_in[0];
    const float* column_x = (const float*)d_in[1];
    const float* q        = (const float*)d_in[2];
    const float* Wl1_tc  = (const float*)d_in[3];  const float* bl1_tc  = (const float*)d_in[4];  const float* Wr1_tc  = (const float*)d_in[5];
    const float* Wl1_rev = (const float*)d_in[6];  const float* bl1_rev = (const float*)d_in[7];  const float* Wr1_rev = (const float*)d_in[8];
    const float* Wl1_cs  = (const float*)d_in[9];  const float* bl1_cs  = (const float*)d_in[10]; const float* Wr1_cs  = (const float*)d_in[11];
    const float* Wl1_ns  = (const float*)d_in[12]; const float* bl1_ns  = (const float*)d_in[13]; const float* Wr1_ns  = (const float*)d_in[14];
    const float* Wl1_ds  = (const float*)d_in[15]; const float* bl1_ds  = (const float*)d_in[16]; const float* Wr1_ds  = (const float*)d_in[17];
    const float* Wl1_ts  = (const float*)d_in[18]; const float* bl1_ts  = (const float*)d_in[19]; const float* Wr1_ts  = (const float*)d_in[20];
    const float* Wl2_rev = (const float*)d_in[21]; const float* bl2_rev = (const float*)d_in[22]; const float* Wr2_rev = (const float*)d_in[23];
    const float* Wl2_ts  = (const float*)d_in[24]; const float* bl2_ts  = (const float*)d_in[25]; const float* Wr2_ts  = (const float*)d_in[26];
    const float* Wq   = (const float*)d_in[27]; const float* bq   = (const float*)d_in[28];
    const float* Wlin = (const float*)d_in[29]; const float* blin = (const float*)d_in[30];
    const float* ts_ew = (const float*)d_in[31];
    const int* tc_src = (const int*)d_in[32];
    const int* tc_dst = (const int*)d_in[33];
    const int* cs_ei  = (const int*)d_in[34];
    const int* ns_ei  = (const int*)d_in[35];
    const int* ds_ei  = (const int*)d_in[36];
    const int* ts_ei  = (const int*)d_in[37];

    // ---- workspace carve ----
    char* w = (char*)d_ws;
    size_t off = 0;
    auto alloc = [&](size_t bytes) -> void* {
        void* p = w + off;
        off += (bytes + 255) & ~(size_t)255;
        return p;
    };
    // concatenated feature spaces (single allocs -> guaranteed contiguous slices)
    __bf16* featC = (__bf16*)alloc(((size_t)3 * NC + NT) * 128 * 2);  // cs | ns | ds | tc
    __bf16* featT = (__bf16*)alloc(((size_t)NC + NT) * 128 * 2);      // rev | ts
    __bf16* projC_cs  = featC;
    __bf16* projC_ns  = featC + (size_t)NC * 128;
    __bf16* projC_ds  = featC + (size_t)2 * NC * 128;
    __bf16* projT_tc  = featC + (size_t)3 * NC * 128;
    __bf16* projC_rev = featT;
    __bf16* projT_ts  = featT + (size_t)NC * 128;
    __bf16* gemmC = (__bf16*)alloc((size_t)NC * 128 * 2);  // self term (incl bias)
    __bf16* gemmT = (__bf16*)alloc((size_t)NT * 128 * 2);
    float* val2  = (float*)alloc((size_t)(NC + NT) * 4);   // colv | tvt
    float* f_colv = val2;
    float* f_tvt  = val2 + NC;
    float* f_tvs = (float*)alloc((size_t)NT * 4);
    float* f_wgt = (float*)alloc((size_t)NT * 4);
    float* f_dis = (float*)alloc((size_t)NT * 4);
    float* f_y0  = (float*)alloc((size_t)NT * 4);
    float* f_za  = (float*)alloc((size_t)NT * 4);
    float* f_zb  = (float*)alloc((size_t)NT * 4);
    float* f_norm = (float*)alloc((size_t)E_TS * 4);
    __bf16* WtS1c  = (__bf16*)alloc((size_t)128 * 256 * 2);
    __bf16* Wt_cs  = (__bf16*)alloc((size_t)128 * 256 * 2);
    __bf16* Wt_ns  = (__bf16*)alloc((size_t)128 * 256 * 2);
    __bf16* Wt_ds  = (__bf16*)alloc((size_t)128 * 256 * 2);
    __bf16* Wt_rev = (__bf16*)alloc((size_t)128 * 256 * 2);
    __bf16* Wt_tc  = (__bf16*)alloc((size_t)128 * 512 * 2);
    __bf16* WtS1t  = (__bf16*)alloc((size_t)128 * 512 * 2);
    __bf16* Wt_ts  = (__bf16*)alloc((size_t)128 * 512 * 2);
    float* f_biasC  = (float*)alloc(128 * 4);
    float* f_biasT1 = (float*)alloc(128 * 4);
    float* f_w2s  = (float*)alloc(128 * 4);
    float* f_wrev = (float*)alloc(128 * 4);
    float* f_wts  = (float*)alloc(128 * 4);
    float* f_sc   = (float*)alloc(16 * 4);
    int* i_cnt  = (int*)alloc((size_t)(4 * NC + 1) * 4);   // shared count/fill scratch (max size)
    int* i_rs4  = (int*)alloc((size_t)(4 * NC + 1) * 4);
    int* i_srt4 = (int*)alloc((size_t)(3 * E_SIM + E_TC) * 4);
    float* f_scl4 = (float*)alloc((size_t)(3 * E_SIM + E_TC) * 4);
    int* i_rs2  = (int*)alloc((size_t)(2 * NT + 1) * 4);
    int* i_srt2 = (int*)alloc((size_t)(E_TC + E_TS) * 4);
    float* f_scl2 = (float*)alloc((size_t)(E_TC + E_TS) * 4);
    int* i_rs_ts  = (int*)alloc((size_t)(NT + 1) * 4);
    int* i_srt_ts = (int*)alloc((size_t)E_TS * 4);
    int* i_bsum = (int*)alloc(512 * 4);
    int* i_boff = (int*)alloc(513 * 4);
    if (off > ws_size) return;

    auto cdiv = [](int a, int b) { return (a + b - 1) / b; };

    // ---- weight/vector prep ----
    wprep<<<cdiv(128 * 256, 256), 256, 0, stream>>>(Wr1_tc, Wr1_cs, Wr1_ns, Wr1_ds, WtS1c, 256);
    wprep<<<cdiv(128 * 256, 256), 256, 0, stream>>>(Wl1_cs, nullptr, nullptr, nullptr, Wt_cs, 256);
    wprep<<<cdiv(128 * 256, 256), 256, 0, stream>>>(Wl1_ns, nullptr, nullptr, nullptr, Wt_ns, 256);
    wprep<<<cdiv(128 * 256, 256), 256, 0, stream>>>(Wl1_ds, nullptr, nullptr, nullptr, Wt_ds, 256);
    wprep<<<cdiv(128 * 256, 256), 256, 0, stream>>>(Wl1_rev, nullptr, nullptr, nullptr, Wt_rev, 256);
    wprep<<<cdiv(128 * 512, 256), 256, 0, stream>>>(Wl1_tc, nullptr, nullptr, nullptr, Wt_tc, 512);
    wprep<<<cdiv(128 * 512, 256), 256, 0, stream>>>(Wr1_rev, Wr1_ts, nullptr, nullptr, WtS1t, 512);
    wprep<<<cdiv(128 * 512, 256), 256, 0, stream>>>(Wl1_ts, nullptr, nullptr, nullptr, Wt_ts, 512);
    add4_kernel<<<1, 128, 0, stream>>>(bl1_tc, bl1_cs, bl1_ns, bl1_ds, f_biasC, 128);
    add4_kernel<<<1, 128, 0, stream>>>(bl1_rev, bl1_ts, nullptr, nullptr, f_biasT1, 128);
    vecprep<<<1, 128, 0, stream>>>(q, Wq, bq, Wr2_rev, Wr2_ts, Wl2_rev, Wl2_ts,
                                   bl2_rev, bl2_ts, Wlin, f_w2s, f_wrev, f_wts, f_sc);

    // ---- GEMMs: LDS-staged, one output per pass ----
    const int gC = cdiv(NC, 128), gT = cdiv(NT, 128);
    gemm_lds<256><<<gC, 256, 0, stream>>>(column_x, WtS1c, f_biasC, gemmC, NC);
    gemm_lds<256><<<gC, 256, 0, stream>>>(column_x, Wt_cs, nullptr, projC_cs, NC);
    gemm_lds<256><<<gC, 256, 0, stream>>>(column_x, Wt_ns, nullptr, projC_ns, NC);
    gemm_lds<256><<<gC, 256, 0, stream>>>(column_x, Wt_ds, nullptr, projC_ds, NC);
    gemm_lds<256><<<gC, 256, 0, stream>>>(column_x, Wt_rev, nullptr, projC_rev, NC);
    gemm_lds<512><<<gT, 256, 0, stream>>>(table_x, WtS1t, f_biasT1, gemmT, NT);
    gemm_lds<512><<<gT, 256, 0, stream>>>(table_x, Wt_tc, nullptr, projT_tc, NT);
    gemm_lds<512><<<gT, 256, 0, stream>>>(table_x, Wt_ts, nullptr, projT_ts, NT);

    auto scan = [&](int* rs, int N) {
        const int nblk = cdiv(N, 1024);
        scan_phase1<<<nblk, 256, 0, stream>>>(i_cnt, rs, i_bsum, N);
        scan_phase2<<<1, 64, 0, stream>>>(i_bsum, i_boff, nblk);
        scan_phase3<<<cdiv(N, 256), 256, 0, stream>>>(rs, i_boff, N, nblk);
    };

    // ---- joint column-side CSR (cs, ns, ds, tc), ng=4 ----
    hipMemsetAsync(i_cnt, 0, (size_t)4 * NC * 4, stream);
    count_g<<<cdiv(E_SIM, 256), 256, 0, stream>>>(cs_ei + E_SIM, i_cnt, E_SIM, 0, 4);
    count_g<<<cdiv(E_SIM, 256), 256, 0, stream>>>(ns_ei + E_SIM, i_cnt, E_SIM, 1, 4);
    count_g<<<cdiv(E_SIM, 256), 256, 0, stream>>>(ds_ei + E_SIM, i_cnt, E_SIM, 2, 4);
    count_g<<<cdiv(E_TC, 256), 256, 0, stream>>>(tc_dst, i_cnt, E_TC, 3, 4);
    scan(i_rs4, 4 * NC);
    hipMemsetAsync(i_cnt, 0, (size_t)4 * NC * 4, stream);
    csr_fill_g<<<cdiv(E_SIM, 256), 256, 0, stream>>>(cs_ei + E_SIM, cs_ei, i_rs4, i_cnt, i_srt4, f_scl4, E_SIM, 0, 4, 0);
    csr_fill_g<<<cdiv(E_SIM, 256), 256, 0, stream>>>(ns_ei + E_SIM, ns_ei, i_rs4, i_cnt, i_srt4, f_scl4, E_SIM, 1, 4, NC);
    csr_fill_g<<<cdiv(E_SIM, 256), 256, 0, stream>>>(ds_ei + E_SIM, ds_ei, i_rs4, i_cnt, i_srt4, f_scl4, E_SIM, 2, 4, 2 * NC);
    csr_fill_g<<<cdiv(E_TC, 256), 256, 0, stream>>>(tc_dst, tc_src, i_rs4, i_cnt, i_srt4, f_scl4, E_TC, 3, 4, 3 * NC);

    // ---- joint table-side CSR (rev, ts), ng=2 ----
    hipMemsetAsync(i_cnt, 0, (size_t)2 * NT * 4, stream);
    count_g<<<cdiv(E_TC, 256), 256, 0, stream>>>(tc_src, i_cnt, E_TC, 0, 2);
    count_g<<<cdiv(E_TS, 256), 256, 0, stream>>>(ts_ei + E_TS, i_cnt, E_TS, 1, 2);
    scan(i_rs2, 2 * NT);
    hipMemsetAsync(i_cnt, 0, (size_t)2 * NT * 4, stream);
    csr_fill_g<<<cdiv(E_TC, 256), 256, 0, stream>>>(tc_src, tc_dst, i_rs2, i_cnt, i_srt2, f_scl2, E_TC, 0, 2, 0);
    csr_fill_g<<<cdiv(E_TS, 256), 256, 0, stream>>>(ts_ei + E_TS, ts_ei, i_rs2, i_cnt, i_srt2, f_scl2, E_TS, 1, 2, NC);

    // ---- ts CSR + APPNP normalization ----
    {
        const int* ts_src = ts_ei;
        const int* ts_dst = ts_ei + E_TS;
        hipMemsetAsync(i_cnt, 0, (size_t)NT * 4, stream);
        count_g<<<cdiv(E_TS, 256), 256, 0, stream>>>(ts_dst, i_cnt, E_TS, 0, 1);
        scan(i_rs_ts, NT);
        fill_f32<<<cdiv(NT, 256), 256, 0, stream>>>(f_dis, 1.0f, NT);
        deg_accum<<<cdiv(E_TS, 256), 256, 0, stream>>>(ts_dst, ts_ew, f_dis, E_TS);
        deg_to_dis<<<cdiv(NT, 256), 256, 0, stream>>>(f_dis, NT);
        hipMemsetAsync(i_cnt, 0, (size_t)NT * 4, stream);
        csr_fill_norm<<<cdiv(E_TS, 256), 256, 0, stream>>>(ts_dst, ts_src, ts_ew, i_rs_ts,
                                                           i_cnt, i_srt_ts, f_norm, f_dis, E_TS);
    }

    // ---- fused aggregation + relu + dot ----
    col_fused<<<cdiv(NC, 4), 256, 0, stream>>>(gemmC, featC, i_rs4, i_srt4, f_scl4,
                                               f_wrev, f_colv, 4, NC);
    tab_fused<<<cdiv(NT, 4), 256, 0, stream>>>(gemmT, featT, i_rs2, i_srt2, f_scl2,
                                               f_w2s, f_wts, f_tvs, f_tvt, 2, NT);

    // ---- tail ----
    wgt_kernel<<<cdiv(NT, 4), 256, 0, stream>>>(table_x, q, f_sc, f_wgt);
    y0_joint<<<cdiv(NT, 16), 256, 0, stream>>>(f_tvs, val2, i_rs2, i_srt2, f_scl2,
                                               f_wgt, f_sc, f_y0, NT);

    const float* zin = f_y0;
    float* zout = f_za;
    for (int it = 0; it < 10; ++it) {
        appnp_s<<<cdiv(NT, 16), 256, 0, stream>>>(zin, f_y0, i_rs_ts, i_srt_ts,
                                                  f_norm, f_dis, zout, NT);
        zin = zout;
        zout = (zout == f_za) ? f_zb : f_za;
    }

    final_add<<<cdiv(NT, 256), 256, 0, stream>>>(zin, blin, (float*)d_out, NT);
}

// Round 5
// 795.501 us; speedup vs baseline: 3.1615x; 1.2946x over previous
//
#include <hip/hip_runtime.h>

#define NT 20000
#define NC 100000
#define DT 512
#define DC 256
#define E_TC 100000
#define E_SIM 800000
#define E_TS 640000

#define NKEY (4 * NC + 2 * NT + NT)          // 460000 joint CSR keys
#define NED_AB (3 * E_SIM + E_TC + E_TC + E_TS)  // 3240000 edges regions A+B
#define NED_ALL (NED_AB + E_TS)              // 3880000 total arena entries

typedef float f32x4 __attribute__((ext_vector_type(4)));
typedef __bf16 bf16x8 __attribute__((ext_vector_type(8)));

// ---------------- prep kernels ----------------

struct WD { const float* w0; const float* w1; const float* w2; const float* w3;
            __bf16* out; int K; int kshift; int ebase; };
struct WD8 { WD d[8]; };

__global__ void wprep_all(WD8 ds, int total) {
    int i = blockIdx.x * blockDim.x + threadIdx.x;
    if (i >= total) return;
#pragma unroll
    for (int s = 7; s >= 0; --s) {
        if (i >= ds.d[s].ebase) {
            const WD d = ds.d[s];
            const int idx = i - d.ebase;
            const int n = idx >> d.kshift;
            const int k = idx & (d.K - 1);
            float v = d.w0[(size_t)k * 128 + n];
            if (d.w1) v += d.w1[(size_t)k * 128 + n];
            if (d.w2) v += d.w2[(size_t)k * 128 + n];
            if (d.w3) v += d.w3[(size_t)k * 128 + n];
            d.out[(size_t)n * d.K + k] = (__bf16)v;
            return;
        }
    }
}

// collapsed layer-2 weight vectors + query scalars + layer-1 biases. 1 block/128 thr.
// sc[0]=qdot, sc[1]=c0, sc[2]=qn
__global__ void vecprep(const float* __restrict__ q, const float* __restrict__ Wq,
                        const float* __restrict__ bq,
                        const float* __restrict__ Wr2_rev, const float* __restrict__ Wr2_ts,
                        const float* __restrict__ Wl2_rev, const float* __restrict__ Wl2_ts,
                        const float* __restrict__ bl2_rev, const float* __restrict__ bl2_ts,
                        const float* __restrict__ Wlin,
                        const float* __restrict__ bl1_tc, const float* __restrict__ bl1_cs,
                        const float* __restrict__ bl1_ns, const float* __restrict__ bl1_ds,
                        const float* __restrict__ bl1_rev, const float* __restrict__ bl1_ts,
                        float* __restrict__ biasC, float* __restrict__ biasT1,
                        float* __restrict__ w2s, float* __restrict__ wrev,
                        float* __restrict__ wts, float* __restrict__ sc) {
    const int t = threadIdx.x;  // 0..127
    biasC[t] = bl1_tc[t] + bl1_cs[t] + bl1_ns[t] + bl1_ds[t];
    biasT1[t] = bl1_rev[t] + bl1_ts[t];
    float a = 0.f, b = 0.f, c = 0.f;
    for (int h = 0; h < 128; ++h) {
        const float wl = Wlin[h];
        a = fmaf(Wr2_rev[(size_t)t * 128 + h] + Wr2_ts[(size_t)t * 128 + h], wl, a);
        b = fmaf(Wl2_rev[(size_t)t * 128 + h], wl, b);
        c = fmaf(Wl2_ts[(size_t)t * 128 + h], wl, c);
    }
    w2s[t] = a; wrev[t] = b; wts[t] = c;
    float qv = bq[t];
    for (int k = 0; k < 512; ++k) qv = fmaf(q[k], Wq[(size_t)k * 128 + t], qv);
    __shared__ float sh[128];
    sh[t] = qv * Wlin[t];
    __syncthreads();
    for (int st = 64; st >= 1; st >>= 1) { if (t < st) sh[t] += sh[t + st]; __syncthreads(); }
    if (t == 0) sc[0] = sh[0];
    __syncthreads();
    sh[t] = (bl2_rev[t] + bl2_ts[t]) * Wlin[t];
    __syncthreads();
    for (int st = 64; st >= 1; st >>= 1) { if (t < st) sh[t] += sh[t + st]; __syncthreads(); }
    if (t == 0) sc[1] = sh[0];
    __syncthreads();
    float ss = 0.f;
    for (int k = t; k < 512; k += 128) { const float v = q[k]; ss = fmaf(v, v, ss); }
    sh[t] = ss;
    __syncthreads();
    for (int st = 64; st >= 1; st >>= 1) { if (t < st) sh[t] += sh[t + st]; __syncthreads(); }
    if (t == 0) sc[2] = fmaxf(sqrtf(sh[0]), 1e-12f);
}

// ---------------- A-resident multi-output MFMA GEMMs ----------------
// col: K=256, 5 outputs. Block 256 thr, 4 waves x 32 rows = 128-row M-tile.
// A frags in registers (read X once); per output stage B panel (64KB LDS,
// XOR-swizzled 16B units slot^=(row&7)) then 8 ksteps x 16 MFMA.

struct B5 { const __bf16* p[5]; };
struct Y5 { __bf16* p[5]; };

__launch_bounds__(256, 2)
__global__ void gemm_col5(const float* __restrict__ X, B5 wp, const float* __restrict__ bias,
                          Y5 yp, int M) {
    __shared__ __bf16 Bs[128 * 256];   // 64 KB
    const int t = threadIdx.x;
    const int lane = t & 63;
    const int wave = t >> 6;
    const int l15 = lane & 15;
    const int kg = lane >> 4;
    const int rowbase = blockIdx.x * 128 + wave * 32;

    bf16x8 af[2][8];
#pragma unroll
    for (int m = 0; m < 2; ++m) {
        int r = rowbase + m * 16 + l15;
        r = (r < M) ? r : (M - 1);
        const float* baseA = X + (size_t)r * 256 + kg * 8;
#pragma unroll
        for (int ks = 0; ks < 8; ++ks) {
            const float4 x0 = *reinterpret_cast<const float4*>(baseA + ks * 32);
            const float4 x1 = *reinterpret_cast<const float4*>(baseA + ks * 32 + 4);
            bf16x8 tt;
            tt[0] = (__bf16)x0.x; tt[1] = (__bf16)x0.y; tt[2] = (__bf16)x0.z; tt[3] = (__bf16)x0.w;
            tt[4] = (__bf16)x1.x; tt[5] = (__bf16)x1.y; tt[6] = (__bf16)x1.z; tt[7] = (__bf16)x1.w;
            af[m][ks] = tt;
        }
    }

#pragma unroll
    for (int o = 0; o < 5; ++o) {
        __syncthreads();
        const __bf16* Wt = wp.p[o];
#pragma unroll
        for (int i = 0; i < 16; ++i) {
            const int u = t + i * 256;
            const int row = u >> 5;
            const int ku = u & 31;
            const bf16x8 v = *reinterpret_cast<const bf16x8*>(Wt + (size_t)row * 256 + ku * 8);
            *reinterpret_cast<bf16x8*>(&Bs[row * 256 + ((ku ^ (row & 7)) << 3)]) = v;
        }
        __syncthreads();
        f32x4 acc[2][8];
#pragma unroll
        for (int m = 0; m < 2; ++m)
#pragma unroll
            for (int n = 0; n < 8; ++n) acc[m][n] = (f32x4)0.f;
#pragma unroll
        for (int ks = 0; ks < 8; ++ks) {
            const int ku = ks * 4 + kg;
#pragma unroll
            for (int n = 0; n < 8; ++n) {
                const int r = n * 16 + l15;
                const bf16x8 bf = *reinterpret_cast<const bf16x8*>(&Bs[r * 256 + ((ku ^ (r & 7)) << 3)]);
                acc[0][n] = __builtin_amdgcn_mfma_f32_16x16x32_bf16(af[0][ks], bf, acc[0][n], 0, 0, 0);
                acc[1][n] = __builtin_amdgcn_mfma_f32_16x16x32_bf16(af[1][ks], bf, acc[1][n], 0, 0, 0);
            }
        }
        __bf16* Y = yp.p[o];
#pragma unroll
        for (int n = 0; n < 8; ++n) {
            const int col = n * 16 + l15;
            const float bv = (o == 0) ? bias[col] : 0.f;
#pragma unroll
            for (int m = 0; m < 2; ++m)
#pragma unroll
                for (int rr = 0; rr < 4; ++rr) {
                    const int row = rowbase + m * 16 + kg * 4 + rr;
                    if (row < M) Y[(size_t)row * 128 + col] = (__bf16)(acc[m][n][rr] + bv);
                }
        }
    }
}

// tab: K=512, 3 outputs, 64-row M-tile (4 waves x 16 rows), fused retrieval wgt.
struct B3 { const __bf16* p[3]; };
struct Y3 { __bf16* p[3]; };

__launch_bounds__(256, 2)
__global__ void gemm_tab3(const float* __restrict__ X, B3 wp, const float* __restrict__ bias,
                          Y3 yp, const float* __restrict__ q, const float* __restrict__ sc,
                          float* __restrict__ wgt, int M) {
    __shared__ __bf16 Bs[128 * 256];   // 64 KB (half-K chunk)
    const int t = threadIdx.x;
    const int lane = t & 63;
    const int wave = t >> 6;
    const int l15 = lane & 15;
    const int kg = lane >> 4;
    const int rowbase = blockIdx.x * 64 + wave * 16;
    const int r0 = rowbase + l15;
    const bool rv = r0 < M;
    const int rc = rv ? r0 : (M - 1);
    const float* baseA = X + (size_t)rc * 512 + kg * 8;

    bf16x8 af[16];
    float dot = 0.f, ss = 0.f;
#pragma unroll
    for (int ks = 0; ks < 16; ++ks) {
        const float4 x0 = *reinterpret_cast<const float4*>(baseA + ks * 32);
        const float4 x1 = *reinterpret_cast<const float4*>(baseA + ks * 32 + 4);
        const float4 q0 = *reinterpret_cast<const float4*>(q + kg * 8 + ks * 32);
        const float4 q1 = *reinterpret_cast<const float4*>(q + kg * 8 + ks * 32 + 4);
        dot += x0.x * q0.x + x0.y * q0.y + x0.z * q0.z + x0.w * q0.w
             + x1.x * q1.x + x1.y * q1.y + x1.z * q1.z + x1.w * q1.w;
        ss += x0.x * x0.x + x0.y * x0.y + x0.z * x0.z + x0.w * x0.w
            + x1.x * x1.x + x1.y * x1.y + x1.z * x1.z + x1.w * x1.w;
        bf16x8 tt;
        tt[0] = (__bf16)x0.x; tt[1] = (__bf16)x0.y; tt[2] = (__bf16)x0.z; tt[3] = (__bf16)x0.w;
        tt[4] = (__bf16)x1.x; tt[5] = (__bf16)x1.y; tt[6] = (__bf16)x1.z; tt[7] = (__bf16)x1.w;
        af[ks] = tt;
    }
    dot += __shfl_xor(dot, 16); dot += __shfl_xor(dot, 32);
    ss  += __shfl_xor(ss, 16);  ss  += __shfl_xor(ss, 32);
    if (lane < 16 && rv) {
        const float nx = fmaxf(sqrtf(ss), 1e-12f);
        wgt[r0] = fmaxf(dot, 0.f) / (nx * sc[2]);
    }

#pragma unroll
    for (int o = 0; o < 3; ++o) {
        f32x4 acc[8];
#pragma unroll
        for (int n = 0; n < 8; ++n) acc[n] = (f32x4)0.f;
        const __bf16* Wt = wp.p[o];
#pragma unroll
        for (int c = 0; c < 2; ++c) {
            __syncthreads();
#pragma unroll
            for (int i = 0; i < 16; ++i) {
                const int u = t + i * 256;
                const int row = u >> 5;
                const int ku = u & 31;
                const bf16x8 v = *reinterpret_cast<const bf16x8*>(Wt + (size_t)row * 512 + c * 256 + ku * 8);
                *reinterpret_cast<bf16x8*>(&Bs[row * 256 + ((ku ^ (row & 7)) << 3)]) = v;
            }
            __syncthreads();
#pragma unroll
            for (int ks = 0; ks < 8; ++ks) {
                const int ku = ks * 4 + kg;
#pragma unroll
                for (int n = 0; n < 8; ++n) {
                    const int r = n * 16 + l15;
                    const bf16x8 bf = *reinterpret_cast<const bf16x8*>(&Bs[r * 256 + ((ku ^ (r & 7)) << 3)]);
                    acc[n] = __builtin_amdgcn_mfma_f32_16x16x32_bf16(af[c * 8 + ks], bf, acc[n], 0, 0, 0);
                }
            }
        }
        __bf16* Y = yp.p[o];
#pragma unroll
        for (int n = 0; n < 8; ++n) {
            const int col = n * 16 + l15;
            const float bv = (o == 0) ? bias[col] : 0.f;
#pragma unroll
            for (int rr = 0; rr < 4; ++rr) {
                const int row = rowbase + kg * 4 + rr;
                if (row < M) Y[(size_t)row * 128 + col] = (__bf16)(acc[n][rr] + bv);
            }
        }
    }
}

// ---------------- single-arena CSR build ----------------

struct ED { const int* dst; const int* src; int E; int ebase; int ng; int g; int keybase; int srcoff; };
struct ED7 { ED d[7]; };
struct ED6 { ED d[6]; };

__global__ void count_all(ED7 ds, int* __restrict__ cnt, int total) {
    int e = blockIdx.x * blockDim.x + threadIdx.x;
    if (e >= total) return;
#pragma unroll
    for (int i = 6; i >= 0; --i) {
        if (e >= ds.d[i].ebase) {
            const ED d = ds.d[i];
            const int le = e - d.ebase;
            atomicAdd(&cnt[d.keybase + d.dst[le] * d.ng + d.g], 1);
            return;
        }
    }
}

__global__ void fill_all(ED6 ds, const int* __restrict__ rs, int* __restrict__ fil,
                         int* __restrict__ idx, float* __restrict__ val, int total) {
    int e = blockIdx.x * blockDim.x + threadIdx.x;
    if (e >= total) return;
#pragma unroll
    for (int i = 5; i >= 0; --i) {
        if (e >= ds.d[i].ebase) {
            const ED d = ds.d[i];
            const int le = e - d.ebase;
            const int key = d.keybase + d.dst[le] * d.ng + d.g;
            const int b = rs[key];
            const int pos = b + atomicAdd(&fil[key], 1);
            idx[pos] = d.srcoff + d.src[le];
            val[pos] = 1.0f / (float)(rs[key + 1] - b);
            return;
        }
    }
}

__launch_bounds__(256)
__global__ void scan_phase1(const int* __restrict__ cnt, int* __restrict__ rs,
                            int* __restrict__ bsum, int N) {
    __shared__ int sh[256];
    const int t = threadIdx.x;
    const int base = blockIdx.x * 1024 + t * 4;
    int v0 = 0, v1 = 0, v2 = 0, v3 = 0;
    if (base + 0 < N) v0 = cnt[base + 0];
    if (base + 1 < N) v1 = cnt[base + 1];
    if (base + 2 < N) v2 = cnt[base + 2];
    if (base + 3 < N) v3 = cnt[base + 3];
    const int tot = v0 + v1 + v2 + v3;
    sh[t] = tot;
    __syncthreads();
#pragma unroll
    for (int off = 1; off < 256; off <<= 1) {
        int y = (t >= off) ? sh[t - off] : 0;
        __syncthreads();
        sh[t] += y;
        __syncthreads();
    }
    const int incl = sh[t];
    const int excl = incl - tot;
    if (base + 0 < N) rs[base + 0] = excl;
    if (base + 1 < N) rs[base + 1] = excl + v0;
    if (base + 2 < N) rs[base + 2] = excl + v0 + v1;
    if (base + 3 < N) rs[base + 3] = excl + v0 + v1 + v2;
    if (t == 255) bsum[blockIdx.x] = incl;
}

__global__ void scan_phase2(const int* __restrict__ bsum, int* __restrict__ boff, int nblk) {
    const int l = threadIdx.x;  // 64 threads
    int carry = 0;
    for (int base = 0; base < nblk; base += 64) {
        const int v = (base + l < nblk) ? bsum[base + l] : 0;
        int inc = v;
#pragma unroll
        for (int off = 1; off < 64; off <<= 1) {
            const int y = __shfl_up(inc, off);
            if (l >= off) inc += y;
        }
        if (base + l < nblk) boff[base + l] = carry + inc - v;
        carry += __shfl(inc, 63);
    }
    if (l == 0) boff[nblk] = carry;
}

__global__ void scan_phase3(int* __restrict__ rs, const int* __restrict__ boff, int N, int nblk) {
    int i = blockIdx.x * blockDim.x + threadIdx.x;
    if (i < N) rs[i] += boff[i >> 10];
    if (i == 0) rs[N] = boff[nblk];
}

__global__ void csr_fill_norm(const int* __restrict__ dst, const int* __restrict__ src,
                              const float* __restrict__ ew, const int* __restrict__ rs,
                              int* __restrict__ fil, int* __restrict__ idx,
                              float* __restrict__ val, const float* __restrict__ dis,
                              int keybase, int E) {
    int e = blockIdx.x * blockDim.x + threadIdx.x;
    if (e >= E) return;
    const int d = dst[e];
    const int s = src[e];
    const int key = keybase + d;
    const int pos = rs[key] + atomicAdd(&fil[key], 1);
    idx[pos] = s;
    val[pos] = dis[s] * ew[e] * dis[d];
}

__global__ void deg_accum(const int* __restrict__ dst, const float* __restrict__ ew,
                          float* __restrict__ deg, int E) {
    int e = blockIdx.x * blockDim.x + threadIdx.x;
    if (e < E) atomicAdd(&deg[dst[e]], ew[e]);
}

__global__ void deg_to_dis(float* __restrict__ deg, int n) {
    int i = blockIdx.x * blockDim.x + threadIdx.x;
    if (i < n) {
        float d = deg[i];
        deg[i] = (d > 0.f) ? (1.0f / sqrtf(d)) : 0.f;
    }
}

__global__ void fill_f32(float* __restrict__ p, float v, int n) {
    int i = blockIdx.x * blockDim.x + threadIdx.x;
    if (i < n) p[i] = v;
}

// ---------------- fused row kernels ----------------
// One wave per dst row; 4 edge-slots x 16 lanes (16B/lane); edge loop unrolled x2.

__launch_bounds__(256)
__global__ void col_fused(const __bf16* __restrict__ selfRow, const __bf16* __restrict__ featCat,
                          const int* __restrict__ rs, const int* __restrict__ srt,
                          const float* __restrict__ scl, const float* __restrict__ wvec,
                          float* __restrict__ outv, int ng, int n) {
    const int wave = threadIdx.x >> 6;
    const int lane = threadIdx.x & 63;
    const int sg = lane >> 4;
    const int sl = lane & 15;
    const int row = blockIdx.x * 4 + wave;
    if (row >= n) return;
    const int b = rs[row * ng], e = rs[row * ng + ng];
    float s8[8] = {0.f, 0.f, 0.f, 0.f, 0.f, 0.f, 0.f, 0.f};
    int j = b + sg;
    for (; j + 4 < e; j += 8) {
        const int s0 = srt[j], s1 = srt[j + 4];
        const float w0 = scl[j], w1 = scl[j + 4];
        const bf16x8 v0 = *reinterpret_cast<const bf16x8*>(&featCat[(size_t)s0 * 128 + sl * 8]);
        const bf16x8 v1 = *reinterpret_cast<const bf16x8*>(&featCat[(size_t)s1 * 128 + sl * 8]);
#pragma unroll
        for (int t = 0; t < 8; ++t) {
            s8[t] = fmaf(w0, (float)v0[t], s8[t]);
            s8[t] = fmaf(w1, (float)v1[t], s8[t]);
        }
    }
    if (j < e) {
        const int s0 = srt[j];
        const float w0 = scl[j];
        const bf16x8 v0 = *reinterpret_cast<const bf16x8*>(&featCat[(size_t)s0 * 128 + sl * 8]);
#pragma unroll
        for (int t = 0; t < 8; ++t) s8[t] = fmaf(w0, (float)v0[t], s8[t]);
    }
#pragma unroll
    for (int t = 0; t < 8; ++t) {
        s8[t] += __shfl_xor(s8[t], 16);
        s8[t] += __shfl_xor(s8[t], 32);
    }
    const bf16x8 g = *reinterpret_cast<const bf16x8*>(&selfRow[(size_t)row * 128 + sl * 8]);
    const float4 w0 = *reinterpret_cast<const float4*>(&wvec[sl * 8]);
    const float4 w1 = *reinterpret_cast<const float4*>(&wvec[sl * 8 + 4]);
    const float ww[8] = {w0.x, w0.y, w0.z, w0.w, w1.x, w1.y, w1.z, w1.w};
    float d = 0.f;
#pragma unroll
    for (int t = 0; t < 8; ++t) d = fmaf(fmaxf(s8[t] + (float)g[t], 0.f), ww[t], d);
#pragma unroll
    for (int off = 8; off; off >>= 1) d += __shfl_xor(d, off);
    if (lane == 0) outv[row] = d;
}

__launch_bounds__(256)
__global__ void tab_fused(const __bf16* __restrict__ selfRow, const __bf16* __restrict__ featCat,
                          const int* __restrict__ rs, const int* __restrict__ srt,
                          const float* __restrict__ scl,
                          const float* __restrict__ wa, const float* __restrict__ wb,
                          float* __restrict__ ya, float* __restrict__ yb, int ng, int n) {
    const int wave = threadIdx.x >> 6;
    const int lane = threadIdx.x & 63;
    const int sg = lane >> 4;
    const int sl = lane & 15;
    const int row = blockIdx.x * 4 + wave;
    if (row >= n) return;
    const int b = rs[row * ng], e = rs[row * ng + ng];
    float s8[8] = {0.f, 0.f, 0.f, 0.f, 0.f, 0.f, 0.f, 0.f};
    int j = b + sg;
    for (; j + 4 < e; j += 8) {
        const int s0 = srt[j], s1 = srt[j + 4];
        const float w0 = scl[j], w1 = scl[j + 4];
        const bf16x8 v0 = *reinterpret_cast<const bf16x8*>(&featCat[(size_t)s0 * 128 + sl * 8]);
        const bf16x8 v1 = *reinterpret_cast<const bf16x8*>(&featCat[(size_t)s1 * 128 + sl * 8]);
#pragma unroll
        for (int t = 0; t < 8; ++t) {
            s8[t] = fmaf(w0, (float)v0[t], s8[t]);
            s8[t] = fmaf(w1, (float)v1[t], s8[t]);
        }
    }
    if (j < e) {
        const int s0 = srt[j];
        const float w0 = scl[j];
        const bf16x8 v0 = *reinterpret_cast<const bf16x8*>(&featCat[(size_t)s0 * 128 + sl * 8]);
#pragma unroll
        for (int t = 0; t < 8; ++t) s8[t] = fmaf(w0, (float)v0[t], s8[t]);
    }
#pragma unroll
    for (int t = 0; t < 8; ++t) {
        s8[t] += __shfl_xor(s8[t], 16);
        s8[t] += __shfl_xor(s8[t], 32);
    }
    const bf16x8 g = *reinterpret_cast<const bf16x8*>(&selfRow[(size_t)row * 128 + sl * 8]);
    const float4 a0 = *reinterpret_cast<const float4*>(&wa[sl * 8]);
    const float4 a1 = *reinterpret_cast<const float4*>(&wa[sl * 8 + 4]);
    const float4 b0 = *reinterpret_cast<const float4*>(&wb[sl * 8]);
    const float4 b1 = *reinterpret_cast<const float4*>(&wb[sl * 8 + 4]);
    const float wwa[8] = {a0.x, a0.y, a0.z, a0.w, a1.x, a1.y, a1.z, a1.w};
    const float wwb[8] = {b0.x, b0.y, b0.z, b0.w, b1.x, b1.y, b1.z, b1.w};
    float da = 0.f, db = 0.f;
#pragma unroll
    for (int t = 0; t < 8; ++t) {
        const float rv = fmaxf(s8[t] + (float)g[t], 0.f);
        da = fmaf(rv, wwa[t], da);
        db = fmaf(rv, wwb[t], db);
    }
#pragma unroll
    for (int off = 8; off; off >>= 1) { da += __shfl_xor(da, off); db += __shfl_xor(db, off); }
    if (lane == 0) { ya[row] = da; yb[row] = db; }
}

// ---------------- tail ----------------

// y0[i] = tvs[i] + sum_j scl[j]*val2[idx[j]] + c0 + wgt[i]*qdot ; 16 lanes/row
__launch_bounds__(256)
__global__ void y0_joint(const float* __restrict__ tvs, const float* __restrict__ val2,
                         const int* __restrict__ rs2, const int* __restrict__ srt2,
                         const float* __restrict__ scl2, const float* __restrict__ wgt,
                         const float* __restrict__ sc, float* __restrict__ y0, int n) {
    const int row = blockIdx.x * 16 + (threadIdx.x >> 4);
    const int l = threadIdx.x & 15;
    if (row >= n) return;
    const int b = rs2[row * 2], e = rs2[row * 2 + 2];
    float s = 0.f;
    for (int j = b + l; j < e; j += 16) s = fmaf(scl2[j], val2[srt2[j]], s);
#pragma unroll
    for (int off = 8; off; off >>= 1) s += __shfl_xor(s, off);
    if (l == 0) y0[row] = tvs[row] + sc[1] + wgt[row] * sc[0] + s;
}

// scalar APPNP step; 16 lanes/row; unroll x2; optional fused final output
__launch_bounds__(256)
__global__ void appnp_s(const float* __restrict__ z, const float* __restrict__ y0,
                        const int* __restrict__ rs, const int* __restrict__ srt,
                        const float* __restrict__ nrm, const float* __restrict__ dis,
                        float* __restrict__ zo, const float* __restrict__ blin,
                        float* __restrict__ out, int n, int last) {
    const int row = blockIdx.x * 16 + (threadIdx.x >> 4);
    const int l = threadIdx.x & 15;
    if (row >= n) return;
    const int b = rs[row], e = rs[row + 1];
    float s = 0.f;
    int j = b + l;
    for (; j + 16 < e; j += 32) {
        const int i0 = srt[j], i1 = srt[j + 16];
        const float w0 = nrm[j], w1 = nrm[j + 16];
        s = fmaf(w0, z[i0], s);
        s = fmaf(w1, z[i1], s);
    }
    if (j < e) s = fmaf(nrm[j], z[srt[j]], s);
#pragma unroll
    for (int off = 8; off; off >>= 1) s += __shfl_xor(s, off);
    if (l == 0) {
        const float d = dis[row];
        const float v = 0.8f * (s + d * d * z[row]) + 0.2f * y0[row];
        if (last) out[row] = v + blin[0];
        else zo[row] = v;
    }
}

// ---------------- host ----------------

extern "C" void kernel_launch(void* const* d_in, const int* in_sizes, int n_in,
                              void* d_out, int out_size, void* d_ws, size_t ws_size,
                              hipStream_t stream) {
    const float* table_x  = (const float*)d_in[0];
    const float* column_x = (const float*)d_in[1];
    const float* q        = (const float*)d_in[2];
    const float* Wl1_tc  = (const float*)d_in[3];  const float* bl1_tc  = (const float*)d_in[4];  const float* Wr1_tc  = (const float*)d_in[5];
    const float* Wl1_rev = (const float*)d_in[6];  const float* bl1_rev = (const float*)d_in[7];  const float* Wr1_rev = (const float*)d_in[8];
    const float* Wl1_cs  = (const float*)d_in[9];  const float* bl1_cs  = (const float*)d_in[10]; const float* Wr1_cs  = (const float*)d_in[11];
    const float* Wl1_ns  = (const float*)d_in[12]; const float* bl1_ns  = (const float*)d_in[13]; const float* Wr1_ns  = (const float*)d_in[14];
    const float* Wl1_ds  = (const float*)d_in[15]; const float* bl1_ds  = (const float*)d_in[16]; const float* Wr1_ds  = (const float*)d_in[17];
    const float* Wl1_ts  = (const float*)d_in[18]; const float* bl1_ts  = (const float*)d_in[19]; const float* Wr1_ts  = (const float*)d_in[20];
    const float* Wl2_rev = (const float*)d_in[21]; const float* bl2_rev = (const float*)d_in[22]; const float* Wr2_rev = (const float*)d_in[23];
    const float* Wl2_ts  = (const float*)d_in[24]; const float* bl2_ts  = (const float*)d_in[25]; const float* Wr2_ts  = (const float*)d_in[26];
    const float* Wq   = (const float*)d_in[27]; const float* bq   = (const float*)d_in[28];
    const float* Wlin = (const float*)d_in[29]; const float* blin = (const float*)d_in[30];
    const float* ts_ew = (const float*)d_in[31];
    const int* tc_src = (const int*)d_in[32];
    const int* tc_dst = (const int*)d_in[33];
    const int* cs_ei  = (const int*)d_in[34];
    const int* ns_ei  = (const int*)d_in[35];
    const int* ds_ei  = (const int*)d_in[36];
    const int* ts_ei  = (const int*)d_in[37];

    // ---- workspace carve ----
    char* w = (char*)d_ws;
    size_t off = 0;
    auto alloc = [&](size_t bytes) -> void* {
        void* p = w + off;
        off += (bytes + 255) & ~(size_t)255;
        return p;
    };
    __bf16* featC = (__bf16*)alloc(((size_t)3 * NC + NT) * 128 * 2);  // cs | ns | ds | tc
    __bf16* featT = (__bf16*)alloc(((size_t)NC + NT) * 128 * 2);      // rev | ts
    __bf16* projC_cs  = featC;
    __bf16* projC_ns  = featC + (size_t)NC * 128;
    __bf16* projC_ds  = featC + (size_t)2 * NC * 128;
    __bf16* projT_tc  = featC + (size_t)3 * NC * 128;
    __bf16* projC_rev = featT;
    __bf16* projT_ts  = featT + (size_t)NC * 128;
    __bf16* gemmC = (__bf16*)alloc((size_t)NC * 128 * 2);
    __bf16* gemmT = (__bf16*)alloc((size_t)NT * 128 * 2);
    float* val2  = (float*)alloc((size_t)(NC + NT) * 4);   // colv | tvt
    float* f_colv = val2;
    float* f_tvt  = val2 + NC;
    float* f_tvs = (float*)alloc((size_t)NT * 4);
    float* f_wgt = (float*)alloc((size_t)NT * 4);
    float* f_dis = (float*)alloc((size_t)NT * 4);
    float* f_y0  = (float*)alloc((size_t)NT * 4);
    float* f_za  = (float*)alloc((size_t)NT * 4);
    float* f_zb  = (float*)alloc((size_t)NT * 4);
    __bf16* WtS1c  = (__bf16*)alloc((size_t)128 * 256 * 2);
    __bf16* Wt_cs  = (__bf16*)alloc((size_t)128 * 256 * 2);
    __bf16* Wt_ns  = (__bf16*)alloc((size_t)128 * 256 * 2);
    __bf16* Wt_ds  = (__bf16*)alloc((size_t)128 * 256 * 2);
    __bf16* Wt_rev = (__bf16*)alloc((size_t)128 * 256 * 2);
    __bf16* Wt_tc  = (__bf16*)alloc((size_t)128 * 512 * 2);
    __bf16* WtS1t  = (__bf16*)alloc((size_t)128 * 512 * 2);
    __bf16* Wt_ts  = (__bf16*)alloc((size_t)128 * 512 * 2);
    float* f_biasC  = (float*)alloc(128 * 4);
    float* f_biasT1 = (float*)alloc(128 * 4);
    float* f_w2s  = (float*)alloc(128 * 4);
    float* f_wrev = (float*)alloc(128 * 4);
    float* f_wts  = (float*)alloc(128 * 4);
    float* f_sc   = (float*)alloc(16 * 4);
    int* i_cnt = (int*)alloc((size_t)(NKEY + 1) * 4);
    int* i_rs  = (int*)alloc((size_t)(NKEY + 1) * 4);
    int* ed_idx = (int*)alloc((size_t)NED_ALL * 4);
    float* ed_val = (float*)alloc((size_t)NED_ALL * 4);
    int* i_bsum = (int*)alloc(512 * 4);
    int* i_boff = (int*)alloc(513 * 4);
    if (off > ws_size) return;

    auto cdiv = [](int a, int b) { return (a + b - 1) / b; };

    // ---- weight/vector prep (2 dispatches) ----
    {
        WD8 ds;
        int eb = 0;
        auto set = [&](int i, const float* a, const float* b2, const float* c, const float* d2,
                       __bf16* o, int K, int ksh) {
            ds.d[i] = {a, b2, c, d2, o, K, ksh, eb};
            eb += 128 * K;
        };
        set(0, Wr1_tc, Wr1_cs, Wr1_ns, Wr1_ds, WtS1c, 256, 8);
        set(1, Wl1_cs, nullptr, nullptr, nullptr, Wt_cs, 256, 8);
        set(2, Wl1_ns, nullptr, nullptr, nullptr, Wt_ns, 256, 8);
        set(3, Wl1_ds, nullptr, nullptr, nullptr, Wt_ds, 256, 8);
        set(4, Wl1_rev, nullptr, nullptr, nullptr, Wt_rev, 256, 8);
        set(5, Wl1_tc, nullptr, nullptr, nullptr, Wt_tc, 512, 9);
        set(6, Wr1_rev, Wr1_ts, nullptr, nullptr, WtS1t, 512, 9);
        set(7, Wl1_ts, nullptr, nullptr, nullptr, Wt_ts, 512, 9);
        wprep_all<<<cdiv(eb, 256), 256, 0, stream>>>(ds, eb);
    }
    vecprep<<<1, 128, 0, stream>>>(q, Wq, bq, Wr2_rev, Wr2_ts, Wl2_rev, Wl2_ts,
                                   bl2_rev, bl2_ts, Wlin, bl1_tc, bl1_cs, bl1_ns, bl1_ds,
                                   bl1_rev, bl1_ts, f_biasC, f_biasT1,
                                   f_w2s, f_wrev, f_wts, f_sc);

    // ---- GEMMs: A-resident, X read once per side ----
    {
        B5 wp; wp.p[0] = WtS1c; wp.p[1] = Wt_cs; wp.p[2] = Wt_ns; wp.p[3] = Wt_ds; wp.p[4] = Wt_rev;
        Y5 yp; yp.p[0] = gemmC; yp.p[1] = projC_cs; yp.p[2] = projC_ns; yp.p[3] = projC_ds; yp.p[4] = projC_rev;
        gemm_col5<<<cdiv(NC, 128), 256, 0, stream>>>(column_x, wp, f_biasC, yp, NC);
    }
    {
        B3 wp; wp.p[0] = WtS1t; wp.p[1] = Wt_tc; wp.p[2] = Wt_ts;
        Y3 yp; yp.p[0] = gemmT; yp.p[1] = projT_tc; yp.p[2] = projT_ts;
        gemm_tab3<<<cdiv(NT, 64), 256, 0, stream>>>(table_x, wp, f_biasT1, yp, q, f_sc, f_wgt, NT);
    }

    // ---- single-arena CSR build ----
    const int KB_COL = 0, KB_TAB = 4 * NC, KB_TS = 4 * NC + 2 * NT;
    ED7 cds;
    cds.d[0] = {cs_ei + E_SIM, cs_ei, E_SIM, 0,                       4, 0, KB_COL, 0};
    cds.d[1] = {ns_ei + E_SIM, ns_ei, E_SIM, E_SIM,                   4, 1, KB_COL, NC};
    cds.d[2] = {ds_ei + E_SIM, ds_ei, E_SIM, 2 * E_SIM,               4, 2, KB_COL, 2 * NC};
    cds.d[3] = {tc_dst, tc_src, E_TC, 3 * E_SIM,                      4, 3, KB_COL, 3 * NC};
    cds.d[4] = {tc_src, tc_dst, E_TC, 3 * E_SIM + E_TC,               2, 0, KB_TAB, 0};
    cds.d[5] = {ts_ei + E_TS, ts_ei, E_TS, 3 * E_SIM + 2 * E_TC,      2, 1, KB_TAB, NC};
    cds.d[6] = {ts_ei + E_TS, ts_ei, E_TS, 3 * E_SIM + 2 * E_TC + E_TS, 1, 0, KB_TS, 0};
    const int totalC = 3 * E_SIM + 2 * E_TC + 2 * E_TS;

    hipMemsetAsync(i_cnt, 0, (size_t)NKEY * 4, stream);
    count_all<<<cdiv(totalC, 256), 256, 0, stream>>>(cds, i_cnt, totalC);
    {
        const int nblk = cdiv(NKEY, 1024);
        scan_phase1<<<nblk, 256, 0, stream>>>(i_cnt, i_rs, i_bsum, NKEY);
        scan_phase2<<<1, 64, 0, stream>>>(i_bsum, i_boff, nblk);
        scan_phase3<<<cdiv(NKEY, 256), 256, 0, stream>>>(i_rs, i_boff, NKEY, nblk);
    }
    hipMemsetAsync(i_cnt, 0, (size_t)NKEY * 4, stream);
    {
        ED6 fds;
        for (int i = 0; i < 6; ++i) fds.d[i] = cds.d[i];
        fill_all<<<cdiv(NED_AB, 256), 256, 0, stream>>>(fds, i_rs, i_cnt, ed_idx, ed_val, NED_AB);
    }
    fill_f32<<<cdiv(NT, 256), 256, 0, stream>>>(f_dis, 1.0f, NT);
    deg_accum<<<cdiv(E_TS, 256), 256, 0, stream>>>(ts_ei + E_TS, ts_ew, f_dis, E_TS);
    deg_to_dis<<<cdiv(NT, 256), 256, 0, stream>>>(f_dis, NT);
    csr_fill_norm<<<cdiv(E_TS, 256), 256, 0, stream>>>(ts_ei + E_TS, ts_ei, ts_ew, i_rs,
                                                       i_cnt, ed_idx, ed_val, f_dis, KB_TS, E_TS);

    // ---- fused aggregation + relu + dot ----
    col_fused<<<cdiv(NC, 4), 256, 0, stream>>>(gemmC, featC, i_rs + KB_COL, ed_idx, ed_val,
                                               f_wrev, f_colv, 4, NC);
    tab_fused<<<cdiv(NT, 4), 256, 0, stream>>>(gemmT, featT, i_rs + KB_TAB, ed_idx, ed_val,
                                               f_w2s, f_wts, f_tvs, f_tvt, 2, NT);

    // ---- tail ----
    y0_joint<<<cdiv(NT, 16), 256, 0, stream>>>(f_tvs, val2, i_rs + KB_TAB, ed_idx, ed_val,
                                               f_wgt, f_sc, f_y0, NT);

    const float* zin = f_y0;
    float* zout = f_za;
    for (int it = 0; it < 10; ++it) {
        const int last = (it == 9);
        appnp_s<<<cdiv(NT, 16), 256, 0, stream>>>(zin, f_y0, i_rs + KB_TS, ed_idx, ed_val,
                                                  f_dis, zout, blin, (float*)d_out, NT, last);
        zin = zout;
        zout = (zout == f_za) ? f_zb : f_za;
    }
}

// Round 6
// 769.252 us; speedup vs baseline: 3.2694x; 1.0341x over previous
//
#include <hip/hip_runtime.h>

#define NT 20000
#define NC 100000
#define DT 512
#define DC 256
#define E_TC 100000
#define E_SIM 800000
#define E_TS 640000

#define KB_COL 0
#define KB_TAB (4 * NC)
#define KB_TS  (4 * NC + 2 * NT)
#define NKEY   (4 * NC + 2 * NT + NT)            // 460000 joint CSR keys
#define NED_AB (3 * E_SIM + E_TC + E_TC + E_TS)  // 3240000 edges regions A+B

typedef float f32x4 __attribute__((ext_vector_type(4)));
typedef __bf16 bf16x8 __attribute__((ext_vector_type(8)));

// ---------------- prep kernels ----------------

struct WD { const float* w0; const float* w1; const float* w2; const float* w3;
            __bf16* out; int K; int kshift; int ebase; };
struct WD8 { WD d[8]; };

__global__ void wprep_all(WD8 ds, int total) {
    int i = blockIdx.x * blockDim.x + threadIdx.x;
    if (i >= total) return;
#pragma unroll
    for (int s = 7; s >= 0; --s) {
        if (i >= ds.d[s].ebase) {
            const WD d = ds.d[s];
            const int idx = i - d.ebase;
            const int n = idx >> d.kshift;
            const int k = idx & (d.K - 1);
            float v = d.w0[(size_t)k * 128 + n];
            if (d.w1) v += d.w1[(size_t)k * 128 + n];
            if (d.w2) v += d.w2[(size_t)k * 128 + n];
            if (d.w3) v += d.w3[(size_t)k * 128 + n];
            d.out[(size_t)n * d.K + k] = (__bf16)v;
            return;
        }
    }
}

// collapsed layer-2 weight vectors + query scalars + layer-1 biases. 1 block/128 thr.
// sc[0]=qdot, sc[1]=c0, sc[2]=qn
__global__ void vecprep(const float* __restrict__ q, const float* __restrict__ Wq,
                        const float* __restrict__ bq,
                        const float* __restrict__ Wr2_rev, const float* __restrict__ Wr2_ts,
                        const float* __restrict__ Wl2_rev, const float* __restrict__ Wl2_ts,
                        const float* __restrict__ bl2_rev, const float* __restrict__ bl2_ts,
                        const float* __restrict__ Wlin,
                        const float* __restrict__ bl1_tc, const float* __restrict__ bl1_cs,
                        const float* __restrict__ bl1_ns, const float* __restrict__ bl1_ds,
                        const float* __restrict__ bl1_rev, const float* __restrict__ bl1_ts,
                        float* __restrict__ biasC, float* __restrict__ biasT1,
                        float* __restrict__ w2s, float* __restrict__ wrev,
                        float* __restrict__ wts, float* __restrict__ sc) {
    const int t = threadIdx.x;  // 0..127
    biasC[t] = bl1_tc[t] + bl1_cs[t] + bl1_ns[t] + bl1_ds[t];
    biasT1[t] = bl1_rev[t] + bl1_ts[t];
    float a = 0.f, b = 0.f, c = 0.f;
    for (int h = 0; h < 128; ++h) {
        const float wl = Wlin[h];
        a = fmaf(Wr2_rev[(size_t)t * 128 + h] + Wr2_ts[(size_t)t * 128 + h], wl, a);
        b = fmaf(Wl2_rev[(size_t)t * 128 + h], wl, b);
        c = fmaf(Wl2_ts[(size_t)t * 128 + h], wl, c);
    }
    w2s[t] = a; wrev[t] = b; wts[t] = c;
    float qv = bq[t];
    for (int k = 0; k < 512; ++k) qv = fmaf(q[k], Wq[(size_t)k * 128 + t], qv);
    __shared__ float sh[128];
    sh[t] = qv * Wlin[t];
    __syncthreads();
    for (int st = 64; st >= 1; st >>= 1) { if (t < st) sh[t] += sh[t + st]; __syncthreads(); }
    if (t == 0) sc[0] = sh[0];
    __syncthreads();
    sh[t] = (bl2_rev[t] + bl2_ts[t]) * Wlin[t];
    __syncthreads();
    for (int st = 64; st >= 1; st >>= 1) { if (t < st) sh[t] += sh[t + st]; __syncthreads(); }
    if (t == 0) sc[1] = sh[0];
    __syncthreads();
    float ss = 0.f;
    for (int k = t; k < 512; k += 128) { const float v = q[k]; ss = fmaf(v, v, ss); }
    sh[t] = ss;
    __syncthreads();
    for (int st = 64; st >= 1; st >>= 1) { if (t < st) sh[t] += sh[t + st]; __syncthreads(); }
    if (t == 0) sc[2] = fmaxf(sqrtf(sh[0]), 1e-12f);
}

// ---------------- A-resident multi-output MFMA GEMMs ----------------

struct B5 { const __bf16* p[5]; };
struct Y5 { __bf16* p[5]; };

__launch_bounds__(256, 2)
__global__ void gemm_col5(const float* __restrict__ X, B5 wp, const float* __restrict__ bias,
                          Y5 yp, int M) {
    __shared__ __bf16 Bs[128 * 256];   // 64 KB
    const int t = threadIdx.x;
    const int lane = t & 63;
    const int wave = t >> 6;
    const int l15 = lane & 15;
    const int kg = lane >> 4;
    const int rowbase = blockIdx.x * 128 + wave * 32;

    bf16x8 af[2][8];
#pragma unroll
    for (int m = 0; m < 2; ++m) {
        int r = rowbase + m * 16 + l15;
        r = (r < M) ? r : (M - 1);
        const float* baseA = X + (size_t)r * 256 + kg * 8;
#pragma unroll
        for (int ks = 0; ks < 8; ++ks) {
            const float4 x0 = *reinterpret_cast<const float4*>(baseA + ks * 32);
            const float4 x1 = *reinterpret_cast<const float4*>(baseA + ks * 32 + 4);
            bf16x8 tt;
            tt[0] = (__bf16)x0.x; tt[1] = (__bf16)x0.y; tt[2] = (__bf16)x0.z; tt[3] = (__bf16)x0.w;
            tt[4] = (__bf16)x1.x; tt[5] = (__bf16)x1.y; tt[6] = (__bf16)x1.z; tt[7] = (__bf16)x1.w;
            af[m][ks] = tt;
        }
    }

#pragma unroll
    for (int o = 0; o < 5; ++o) {
        __syncthreads();
        const __bf16* Wt = wp.p[o];
#pragma unroll
        for (int i = 0; i < 16; ++i) {
            const int u = t + i * 256;
            const int row = u >> 5;
            const int ku = u & 31;
            const bf16x8 v = *reinterpret_cast<const bf16x8*>(Wt + (size_t)row * 256 + ku * 8);
            *reinterpret_cast<bf16x8*>(&Bs[row * 256 + ((ku ^ (row & 7)) << 3)]) = v;
        }
        __syncthreads();
        f32x4 acc[2][8];
#pragma unroll
        for (int m = 0; m < 2; ++m)
#pragma unroll
            for (int n = 0; n < 8; ++n) acc[m][n] = (f32x4)0.f;
#pragma unroll
        for (int ks = 0; ks < 8; ++ks) {
            const int ku = ks * 4 + kg;
#pragma unroll
            for (int n = 0; n < 8; ++n) {
                const int r = n * 16 + l15;
                const bf16x8 bf = *reinterpret_cast<const bf16x8*>(&Bs[r * 256 + ((ku ^ (r & 7)) << 3)]);
                acc[0][n] = __builtin_amdgcn_mfma_f32_16x16x32_bf16(af[0][ks], bf, acc[0][n], 0, 0, 0);
                acc[1][n] = __builtin_amdgcn_mfma_f32_16x16x32_bf16(af[1][ks], bf, acc[1][n], 0, 0, 0);
            }
        }
        __bf16* Y = yp.p[o];
#pragma unroll
        for (int n = 0; n < 8; ++n) {
            const int col = n * 16 + l15;
            const float bv = (o == 0) ? bias[col] : 0.f;
#pragma unroll
            for (int m = 0; m < 2; ++m)
#pragma unroll
                for (int rr = 0; rr < 4; ++rr) {
                    const int row = rowbase + m * 16 + kg * 4 + rr;
                    if (row < M) Y[(size_t)row * 128 + col] = (__bf16)(acc[m][n][rr] + bv);
                }
        }
    }
}

struct B3 { const __bf16* p[3]; };
struct Y3 { __bf16* p[3]; };

__launch_bounds__(256, 2)
__global__ void gemm_tab3(const float* __restrict__ X, B3 wp, const float* __restrict__ bias,
                          Y3 yp, const float* __restrict__ q, const float* __restrict__ sc,
                          float* __restrict__ wgt, int M) {
    __shared__ __bf16 Bs[128 * 256];   // 64 KB (half-K chunk)
    const int t = threadIdx.x;
    const int lane = t & 63;
    const int wave = t >> 6;
    const int l15 = lane & 15;
    const int kg = lane >> 4;
    const int rowbase = blockIdx.x * 64 + wave * 16;
    const int r0 = rowbase + l15;
    const bool rv = r0 < M;
    const int rc = rv ? r0 : (M - 1);
    const float* baseA = X + (size_t)rc * 512 + kg * 8;

    bf16x8 af[16];
    float dot = 0.f, ss = 0.f;
#pragma unroll
    for (int ks = 0; ks < 16; ++ks) {
        const float4 x0 = *reinterpret_cast<const float4*>(baseA + ks * 32);
        const float4 x1 = *reinterpret_cast<const float4*>(baseA + ks * 32 + 4);
        const float4 q0 = *reinterpret_cast<const float4*>(q + kg * 8 + ks * 32);
        const float4 q1 = *reinterpret_cast<const float4*>(q + kg * 8 + ks * 32 + 4);
        dot += x0.x * q0.x + x0.y * q0.y + x0.z * q0.z + x0.w * q0.w
             + x1.x * q1.x + x1.y * q1.y + x1.z * q1.z + x1.w * q1.w;
        ss += x0.x * x0.x + x0.y * x0.y + x0.z * x0.z + x0.w * x0.w
            + x1.x * x1.x + x1.y * x1.y + x1.z * x1.z + x1.w * x1.w;
        bf16x8 tt;
        tt[0] = (__bf16)x0.x; tt[1] = (__bf16)x0.y; tt[2] = (__bf16)x0.z; tt[3] = (__bf16)x0.w;
        tt[4] = (__bf16)x1.x; tt[5] = (__bf16)x1.y; tt[6] = (__bf16)x1.z; tt[7] = (__bf16)x1.w;
        af[ks] = tt;
    }
    dot += __shfl_xor(dot, 16); dot += __shfl_xor(dot, 32);
    ss  += __shfl_xor(ss, 16);  ss  += __shfl_xor(ss, 32);
    if (lane < 16 && rv) {
        const float nx = fmaxf(sqrtf(ss), 1e-12f);
        wgt[r0] = fmaxf(dot, 0.f) / (nx * sc[2]);
    }

#pragma unroll
    for (int o = 0; o < 3; ++o) {
        f32x4 acc[8];
#pragma unroll
        for (int n = 0; n < 8; ++n) acc[n] = (f32x4)0.f;
        const __bf16* Wt = wp.p[o];
#pragma unroll
        for (int c = 0; c < 2; ++c) {
            __syncthreads();
#pragma unroll
            for (int i = 0; i < 16; ++i) {
                const int u = t + i * 256;
                const int row = u >> 5;
                const int ku = u & 31;
                const bf16x8 v = *reinterpret_cast<const bf16x8*>(Wt + (size_t)row * 512 + c * 256 + ku * 8);
                *reinterpret_cast<bf16x8*>(&Bs[row * 256 + ((ku ^ (row & 7)) << 3)]) = v;
            }
            __syncthreads();
#pragma unroll
            for (int ks = 0; ks < 8; ++ks) {
                const int ku = ks * 4 + kg;
#pragma unroll
                for (int n = 0; n < 8; ++n) {
                    const int r = n * 16 + l15;
                    const bf16x8 bf = *reinterpret_cast<const bf16x8*>(&Bs[r * 256 + ((ku ^ (r & 7)) << 3)]);
                    acc[n] = __builtin_amdgcn_mfma_f32_16x16x32_bf16(af[c * 8 + ks], bf, acc[n], 0, 0, 0);
                }
            }
        }
        __bf16* Y = yp.p[o];
#pragma unroll
        for (int n = 0; n < 8; ++n) {
            const int col = n * 16 + l15;
            const float bv = (o == 0) ? bias[col] : 0.f;
#pragma unroll
            for (int rr = 0; rr < 4; ++rr) {
                const int row = rowbase + kg * 4 + rr;
                if (row < M) Y[(size_t)row * 128 + col] = (__bf16)(acc[n][rr] + bv);
            }
        }
    }
}

// ---------------- single-arena CSR build ----------------

struct ED { const int* dst; const int* src; int E; int ebase; int ng; int g;
            int keybase; int srcoff; int ts; };
struct ED6 { ED d[6]; };

__global__ void count_all(ED6 ds, int* __restrict__ cnt, int total) {
    int e = blockIdx.x * blockDim.x + threadIdx.x;
    if (e >= total) return;
#pragma unroll
    for (int i = 5; i >= 0; --i) {
        if (e >= ds.d[i].ebase) {
            const ED d = ds.d[i];
            const int le = e - d.ebase;
            atomicAdd(&cnt[d.keybase + d.dst[le] * d.ng + d.g], 1);
            return;
        }
    }
}

// region C (ts-by-dst) counts equal region B g=1 counts
__global__ void copy_cnt(int* __restrict__ cnt) {
    int d = blockIdx.x * blockDim.x + threadIdx.x;
    if (d < NT) cnt[KB_TS + d] = cnt[KB_TAB + 2 * d + 1];
}

// fill: idx scatter (4B) for all regions; ts edges additionally write {src,norm} int2
// at the region-C-relative position (same intra-segment order as region B).
__global__ void fill_all(ED6 ds, const int* __restrict__ rs, int* __restrict__ work,
                         int* __restrict__ idx, int2* __restrict__ ed2,
                         const float* __restrict__ ew, const float* __restrict__ dis,
                         int total) {
    int e = blockIdx.x * blockDim.x + threadIdx.x;
    if (e >= total) return;
#pragma unroll
    for (int i = 5; i >= 0; --i) {
        if (e >= ds.d[i].ebase) {
            const ED d = ds.d[i];
            const int le = e - d.ebase;
            const int dstv = d.dst[le];
            const int srcv = d.src[le];
            const int key = d.keybase + dstv * d.ng + d.g;
            const int pos = atomicAdd(&work[key], 1);
            idx[pos] = d.srcoff + srcv;
            if (d.ts) {
                const int rel = pos - rs[key];
                const int posC = rs[KB_TS + dstv] + rel - NED_AB;
                const float nv = dis[srcv] * ew[le] * dis[dstv];
                ed2[posC] = make_int2(srcv, __float_as_int(nv));
            }
            return;
        }
    }
}

__launch_bounds__(256)
__global__ void scan_phase1(const int* __restrict__ cnt, int* __restrict__ rs,
                            int* __restrict__ bsum, int N) {
    __shared__ int sh[256];
    const int t = threadIdx.x;
    const int base = blockIdx.x * 1024 + t * 4;
    int v0 = 0, v1 = 0, v2 = 0, v3 = 0;
    if (base + 0 < N) v0 = cnt[base + 0];
    if (base + 1 < N) v1 = cnt[base + 1];
    if (base + 2 < N) v2 = cnt[base + 2];
    if (base + 3 < N) v3 = cnt[base + 3];
    const int tot = v0 + v1 + v2 + v3;
    sh[t] = tot;
    __syncthreads();
#pragma unroll
    for (int off = 1; off < 256; off <<= 1) {
        int y = (t >= off) ? sh[t - off] : 0;
        __syncthreads();
        sh[t] += y;
        __syncthreads();
    }
    const int incl = sh[t];
    const int excl = incl - tot;
    if (base + 0 < N) rs[base + 0] = excl;
    if (base + 1 < N) rs[base + 1] = excl + v0;
    if (base + 2 < N) rs[base + 2] = excl + v0 + v1;
    if (base + 3 < N) rs[base + 3] = excl + v0 + v1 + v2;
    if (t == 255) bsum[blockIdx.x] = incl;
}

__global__ void scan_phase2(const int* __restrict__ bsum, int* __restrict__ boff, int nblk) {
    const int l = threadIdx.x;  // 64 threads
    int carry = 0;
    for (int base = 0; base < nblk; base += 64) {
        const int v = (base + l < nblk) ? bsum[base + l] : 0;
        int inc = v;
#pragma unroll
        for (int off = 1; off < 64; off <<= 1) {
            const int y = __shfl_up(inc, off);
            if (l >= off) inc += y;
        }
        if (base + l < nblk) boff[base + l] = carry + inc - v;
        carry += __shfl(inc, 63);
    }
    if (l == 0) boff[nblk] = carry;
}

__global__ void scan_phase3(int* __restrict__ rs, int* __restrict__ work,
                            const int* __restrict__ boff, int N, int nblk) {
    int i = blockIdx.x * blockDim.x + threadIdx.x;
    if (i < N) {
        const int v = rs[i] + boff[i >> 10];
        rs[i] = v;
        work[i] = v;
    }
    if (i == 0) rs[N] = boff[nblk];
}

__global__ void deg_accum(const int* __restrict__ dst, const float* __restrict__ ew,
                          float* __restrict__ deg, int E) {
    int e = blockIdx.x * blockDim.x + threadIdx.x;
    if (e < E) atomicAdd(&deg[dst[e]], ew[e]);
}

__global__ void deg_to_dis(float* __restrict__ deg, int n) {
    int i = blockIdx.x * blockDim.x + threadIdx.x;
    if (i < n) {
        float d = deg[i];
        deg[i] = (d > 0.f) ? (1.0f / sqrtf(d)) : 0.f;
    }
}

__global__ void fill_f32(float* __restrict__ p, float v, int n) {
    int i = blockIdx.x * blockDim.x + threadIdx.x;
    if (i < n) p[i] = v;
}

// ---------------- fused row kernels ----------------
// One wave per dst row; 4 edge-slots x 16 lanes (16B/lane); per-edge mean scale
// derived from segment boundaries (monotone g-tracker).

__launch_bounds__(256)
__global__ void col_fused(const __bf16* __restrict__ selfRow, const __bf16* __restrict__ featCat,
                          const int* __restrict__ rs, const int* __restrict__ srt,
                          const float* __restrict__ wvec, float* __restrict__ outv, int n) {
    const int wave = threadIdx.x >> 6;
    const int lane = threadIdx.x & 63;
    const int sg = lane >> 4;
    const int sl = lane & 15;
    const int row = blockIdx.x * 4 + wave;
    if (row >= n) return;
    const int4 r4 = *reinterpret_cast<const int4*>(&rs[row * 4]);
    const int bnd[5] = {r4.x, r4.y, r4.z, r4.w, rs[row * 4 + 4]};
    float wseg[4];
#pragma unroll
    for (int t = 0; t < 4; ++t) {
        const int len = bnd[t + 1] - bnd[t];
        wseg[t] = (len > 0) ? (1.0f / (float)len) : 0.f;
    }
    const int e = bnd[4];
    float s8[8] = {0.f, 0.f, 0.f, 0.f, 0.f, 0.f, 0.f, 0.f};
    int j = bnd[0] + sg;
    int g = 0;
    for (; j + 4 < e; j += 8) {
        while (j >= bnd[g + 1]) ++g;
        int g1 = g;
        const int j1 = j + 4;
        while (j1 >= bnd[g1 + 1]) ++g1;
        const float w0 = wseg[g], w1 = wseg[g1];
        const int s0 = srt[j], s1 = srt[j1];
        const bf16x8 v0 = *reinterpret_cast<const bf16x8*>(&featCat[(size_t)s0 * 128 + sl * 8]);
        const bf16x8 v1 = *reinterpret_cast<const bf16x8*>(&featCat[(size_t)s1 * 128 + sl * 8]);
#pragma unroll
        for (int t = 0; t < 8; ++t) {
            s8[t] = fmaf(w0, (float)v0[t], s8[t]);
            s8[t] = fmaf(w1, (float)v1[t], s8[t]);
        }
        g = g1;
    }
    if (j < e) {
        while (j >= bnd[g + 1]) ++g;
        const float w0 = wseg[g];
        const int s0 = srt[j];
        const bf16x8 v0 = *reinterpret_cast<const bf16x8*>(&featCat[(size_t)s0 * 128 + sl * 8]);
#pragma unroll
        for (int t = 0; t < 8; ++t) s8[t] = fmaf(w0, (float)v0[t], s8[t]);
    }
#pragma unroll
    for (int t = 0; t < 8; ++t) {
        s8[t] += __shfl_xor(s8[t], 16);
        s8[t] += __shfl_xor(s8[t], 32);
    }
    const bf16x8 gv = *reinterpret_cast<const bf16x8*>(&selfRow[(size_t)row * 128 + sl * 8]);
    const float4 w0 = *reinterpret_cast<const float4*>(&wvec[sl * 8]);
    const float4 w1 = *reinterpret_cast<const float4*>(&wvec[sl * 8 + 4]);
    const float ww[8] = {w0.x, w0.y, w0.z, w0.w, w1.x, w1.y, w1.z, w1.w};
    float d = 0.f;
#pragma unroll
    for (int t = 0; t < 8; ++t) d = fmaf(fmaxf(s8[t] + (float)gv[t], 0.f), ww[t], d);
#pragma unroll
    for (int off = 8; off; off >>= 1) d += __shfl_xor(d, off);
    if (lane == 0) outv[row] = d;
}

__launch_bounds__(256)
__global__ void tab_fused(const __bf16* __restrict__ selfRow, const __bf16* __restrict__ featCat,
                          const int* __restrict__ rs, const int* __restrict__ srt,
                          const float* __restrict__ wa, const float* __restrict__ wb,
                          float* __restrict__ ya, float* __restrict__ yb, int n) {
    const int wave = threadIdx.x >> 6;
    const int lane = threadIdx.x & 63;
    const int sg = lane >> 4;
    const int sl = lane & 15;
    const int row = blockIdx.x * 4 + wave;
    if (row >= n) return;
    const int bnd[3] = {rs[row * 2], rs[row * 2 + 1], rs[row * 2 + 2]};
    float wseg[2];
#pragma unroll
    for (int t = 0; t < 2; ++t) {
        const int len = bnd[t + 1] - bnd[t];
        wseg[t] = (len > 0) ? (1.0f / (float)len) : 0.f;
    }
    const int e = bnd[2];
    float s8[8] = {0.f, 0.f, 0.f, 0.f, 0.f, 0.f, 0.f, 0.f};
    int j = bnd[0] + sg;
    int g = 0;
    for (; j + 4 < e; j += 8) {
        while (j >= bnd[g + 1]) ++g;
        int g1 = g;
        const int j1 = j + 4;
        while (j1 >= bnd[g1 + 1]) ++g1;
        const float w0 = wseg[g], w1 = wseg[g1];
        const int s0 = srt[j], s1 = srt[j1];
        const bf16x8 v0 = *reinterpret_cast<const bf16x8*>(&featCat[(size_t)s0 * 128 + sl * 8]);
        const bf16x8 v1 = *reinterpret_cast<const bf16x8*>(&featCat[(size_t)s1 * 128 + sl * 8]);
#pragma unroll
        for (int t = 0; t < 8; ++t) {
            s8[t] = fmaf(w0, (float)v0[t], s8[t]);
            s8[t] = fmaf(w1, (float)v1[t], s8[t]);
        }
        g = g1;
    }
    if (j < e) {
        while (j >= bnd[g + 1]) ++g;
        const float w0 = wseg[g];
        const int s0 = srt[j];
        const bf16x8 v0 = *reinterpret_cast<const bf16x8*>(&featCat[(size_t)s0 * 128 + sl * 8]);
#pragma unroll
        for (int t = 0; t < 8; ++t) s8[t] = fmaf(w0, (float)v0[t], s8[t]);
    }
#pragma unroll
    for (int t = 0; t < 8; ++t) {
        s8[t] += __shfl_xor(s8[t], 16);
        s8[t] += __shfl_xor(s8[t], 32);
    }
    const bf16x8 gv = *reinterpret_cast<const bf16x8*>(&selfRow[(size_t)row * 128 + sl * 8]);
    const float4 a0 = *reinterpret_cast<const float4*>(&wa[sl * 8]);
    const float4 a1 = *reinterpret_cast<const float4*>(&wa[sl * 8 + 4]);
    const float4 b0 = *reinterpret_cast<const float4*>(&wb[sl * 8]);
    const float4 b1 = *reinterpret_cast<const float4*>(&wb[sl * 8 + 4]);
    const float wwa[8] = {a0.x, a0.y, a0.z, a0.w, a1.x, a1.y, a1.z, a1.w};
    const float wwb[8] = {b0.x, b0.y, b0.z, b0.w, b1.x, b1.y, b1.z, b1.w};
    float da = 0.f, db = 0.f;
#pragma unroll
    for (int t = 0; t < 8; ++t) {
        const float rv = fmaxf(s8[t] + (float)gv[t], 0.f);
        da = fmaf(rv, wwa[t], da);
        db = fmaf(rv, wwb[t], db);
    }
#pragma unroll
    for (int off = 8; off; off >>= 1) { da += __shfl_xor(da, off); db += __shfl_xor(db, off); }
    if (lane == 0) { ya[row] = da; yb[row] = db; }
}

// ---------------- tail ----------------

// y0[i] = tvs[i] + mean_rev(colv) + mean_ts(tvt) + c0 + wgt[i]*qdot ; 16 lanes/row
__launch_bounds__(256)
__global__ void y0_joint(const float* __restrict__ tvs, const float* __restrict__ val2,
                         const int* __restrict__ rs2, const int* __restrict__ srt2,
                         const float* __restrict__ wgt, const float* __restrict__ sc,
                         float* __restrict__ y0, int n) {
    const int row = blockIdx.x * 16 + (threadIdx.x >> 4);
    const int l = threadIdx.x & 15;
    if (row >= n) return;
    const int bnd[3] = {rs2[row * 2], rs2[row * 2 + 1], rs2[row * 2 + 2]};
    float wseg[2];
#pragma unroll
    for (int t = 0; t < 2; ++t) {
        const int len = bnd[t + 1] - bnd[t];
        wseg[t] = (len > 0) ? (1.0f / (float)len) : 0.f;
    }
    float s = 0.f;
    int g = 0;
    for (int j = bnd[0] + l; j < bnd[2]; j += 16) {
        while (j >= bnd[g + 1]) ++g;
        s = fmaf(wseg[g], val2[srt2[j]], s);
    }
#pragma unroll
    for (int off = 8; off; off >>= 1) s += __shfl_xor(s, off);
    if (l == 0) y0[row] = tvs[row] + sc[1] + wgt[row] * sc[0] + s;
}

// scalar APPNP step; 16 lanes/row; int2 {src, norm} arena; fused final output
__launch_bounds__(256)
__global__ void appnp_s(const float* __restrict__ z, const float* __restrict__ y0,
                        const int* __restrict__ rsT, const int2* __restrict__ ed2,
                        const float* __restrict__ dis, float* __restrict__ zo,
                        const float* __restrict__ blin, float* __restrict__ out,
                        int n, int last) {
    const int row = blockIdx.x * 16 + (threadIdx.x >> 4);
    const int l = threadIdx.x & 15;
    if (row >= n) return;
    const int b = rsT[row] - NED_AB, e = rsT[row + 1] - NED_AB;
    float s = 0.f;
    int j = b + l;
    for (; j + 16 < e; j += 32) {
        const int2 p0 = ed2[j];
        const int2 p1 = ed2[j + 16];
        s = fmaf(__int_as_float(p0.y), z[p0.x], s);
        s = fmaf(__int_as_float(p1.y), z[p1.x], s);
    }
    if (j < e) {
        const int2 p0 = ed2[j];
        s = fmaf(__int_as_float(p0.y), z[p0.x], s);
    }
#pragma unroll
    for (int off = 8; off; off >>= 1) s += __shfl_xor(s, off);
    if (l == 0) {
        const float d = dis[row];
        const float v = 0.8f * (s + d * d * z[row]) + 0.2f * y0[row];
        if (last) out[row] = v + blin[0];
        else zo[row] = v;
    }
}

// ---------------- host ----------------

extern "C" void kernel_launch(void* const* d_in, const int* in_sizes, int n_in,
                              void* d_out, int out_size, void* d_ws, size_t ws_size,
                              hipStream_t stream) {
    const float* table_x  = (const float*)d_in[0];
    const float* column_x = (const float*)d_in[1];
    const float* q        = (const float*)d_in[2];
    const float* Wl1_tc  = (const float*)d_in[3];  const float* bl1_tc  = (const float*)d_in[4];  const float* Wr1_tc  = (const float*)d_in[5];
    const float* Wl1_rev = (const float*)d_in[6];  const float* bl1_rev = (const float*)d_in[7];  const float* Wr1_rev = (const float*)d_in[8];
    const float* Wl1_cs  = (const float*)d_in[9];  const float* bl1_cs  = (const float*)d_in[10]; const float* Wr1_cs  = (const float*)d_in[11];
    const float* Wl1_ns  = (const float*)d_in[12]; const float* bl1_ns  = (const float*)d_in[13]; const float* Wr1_ns  = (const float*)d_in[14];
    const float* Wl1_ds  = (const float*)d_in[15]; const float* bl1_ds  = (const float*)d_in[16]; const float* Wr1_ds  = (const float*)d_in[17];
    const float* Wl1_ts  = (const float*)d_in[18]; const float* bl1_ts  = (const float*)d_in[19]; const float* Wr1_ts  = (const float*)d_in[20];
    const float* Wl2_rev = (const float*)d_in[21]; const float* bl2_rev = (const float*)d_in[22]; const float* Wr2_rev = (const float*)d_in[23];
    const float* Wl2_ts  = (const float*)d_in[24]; const float* bl2_ts  = (const float*)d_in[25]; const float* Wr2_ts  = (const float*)d_in[26];
    const float* Wq   = (const float*)d_in[27]; const float* bq   = (const float*)d_in[28];
    const float* Wlin = (const float*)d_in[29]; const float* blin = (const float*)d_in[30];
    const float* ts_ew = (const float*)d_in[31];
    const int* tc_src = (const int*)d_in[32];
    const int* tc_dst = (const int*)d_in[33];
    const int* cs_ei  = (const int*)d_in[34];
    const int* ns_ei  = (const int*)d_in[35];
    const int* ds_ei  = (const int*)d_in[36];
    const int* ts_ei  = (const int*)d_in[37];

    // ---- workspace carve ----
    char* w = (char*)d_ws;
    size_t off = 0;
    auto alloc = [&](size_t bytes) -> void* {
        void* p = w + off;
        off += (bytes + 255) & ~(size_t)255;
        return p;
    };
    __bf16* featC = (__bf16*)alloc(((size_t)3 * NC + NT) * 128 * 2);  // cs | ns | ds | tc
    __bf16* featT = (__bf16*)alloc(((size_t)NC + NT) * 128 * 2);      // rev | ts
    __bf16* projC_cs  = featC;
    __bf16* projC_ns  = featC + (size_t)NC * 128;
    __bf16* projC_ds  = featC + (size_t)2 * NC * 128;
    __bf16* projT_tc  = featC + (size_t)3 * NC * 128;
    __bf16* projC_rev = featT;
    __bf16* projT_ts  = featT + (size_t)NC * 128;
    __bf16* gemmC = (__bf16*)alloc((size_t)NC * 128 * 2);
    __bf16* gemmT = (__bf16*)alloc((size_t)NT * 128 * 2);
    float* val2  = (float*)alloc((size_t)(NC + NT) * 4);   // colv | tvt
    float* f_colv = val2;
    float* f_tvt  = val2 + NC;
    float* f_tvs = (float*)alloc((size_t)NT * 4);
    float* f_wgt = (float*)alloc((size_t)NT * 4);
    float* f_dis = (float*)alloc((size_t)NT * 4);
    float* f_y0  = (float*)alloc((size_t)NT * 4);
    float* f_za  = (float*)alloc((size_t)NT * 4);
    float* f_zb  = (float*)alloc((size_t)NT * 4);
    __bf16* WtS1c  = (__bf16*)alloc((size_t)128 * 256 * 2);
    __bf16* Wt_cs  = (__bf16*)alloc((size_t)128 * 256 * 2);
    __bf16* Wt_ns  = (__bf16*)alloc((size_t)128 * 256 * 2);
    __bf16* Wt_ds  = (__bf16*)alloc((size_t)128 * 256 * 2);
    __bf16* Wt_rev = (__bf16*)alloc((size_t)128 * 256 * 2);
    __bf16* Wt_tc  = (__bf16*)alloc((size_t)128 * 512 * 2);
    __bf16* WtS1t  = (__bf16*)alloc((size_t)128 * 512 * 2);
    __bf16* Wt_ts  = (__bf16*)alloc((size_t)128 * 512 * 2);
    float* f_biasC  = (float*)alloc(128 * 4);
    float* f_biasT1 = (float*)alloc(128 * 4);
    float* f_w2s  = (float*)alloc(128 * 4);
    float* f_wrev = (float*)alloc(128 * 4);
    float* f_wts  = (float*)alloc(128 * 4);
    float* f_sc   = (float*)alloc(16 * 4);
    int* i_cnt  = (int*)alloc((size_t)(NKEY + 1) * 4);
    int* i_rs   = (int*)alloc((size_t)(NKEY + 1) * 4);
    int* i_work = (int*)alloc((size_t)(NKEY + 1) * 4);
    int* ed_idx = (int*)alloc((size_t)NED_AB * 4);
    int2* ed2   = (int2*)alloc((size_t)E_TS * 8);
    int* i_bsum = (int*)alloc(512 * 4);
    int* i_boff = (int*)alloc(513 * 4);
    if (off > ws_size) return;

    auto cdiv = [](int a, int b) { return (a + b - 1) / b; };

    // ---- weight/vector prep (2 dispatches) ----
    {
        WD8 ds;
        int eb = 0;
        auto set = [&](int i, const float* a, const float* b2, const float* c, const float* d2,
                       __bf16* o, int K, int ksh) {
            ds.d[i] = {a, b2, c, d2, o, K, ksh, eb};
            eb += 128 * K;
        };
        set(0, Wr1_tc, Wr1_cs, Wr1_ns, Wr1_ds, WtS1c, 256, 8);
        set(1, Wl1_cs, nullptr, nullptr, nullptr, Wt_cs, 256, 8);
        set(2, Wl1_ns, nullptr, nullptr, nullptr, Wt_ns, 256, 8);
        set(3, Wl1_ds, nullptr, nullptr, nullptr, Wt_ds, 256, 8);
        set(4, Wl1_rev, nullptr, nullptr, nullptr, Wt_rev, 256, 8);
        set(5, Wl1_tc, nullptr, nullptr, nullptr, Wt_tc, 512, 9);
        set(6, Wr1_rev, Wr1_ts, nullptr, nullptr, WtS1t, 512, 9);
        set(7, Wl1_ts, nullptr, nullptr, nullptr, Wt_ts, 512, 9);
        wprep_all<<<cdiv(eb, 256), 256, 0, stream>>>(ds, eb);
    }
    vecprep<<<1, 128, 0, stream>>>(q, Wq, bq, Wr2_rev, Wr2_ts, Wl2_rev, Wl2_ts,
                                   bl2_rev, bl2_ts, Wlin, bl1_tc, bl1_cs, bl1_ns, bl1_ds,
                                   bl1_rev, bl1_ts, f_biasC, f_biasT1,
                                   f_w2s, f_wrev, f_wts, f_sc);

    // ---- GEMMs: A-resident, X read once per side ----
    {
        B5 wp; wp.p[0] = WtS1c; wp.p[1] = Wt_cs; wp.p[2] = Wt_ns; wp.p[3] = Wt_ds; wp.p[4] = Wt_rev;
        Y5 yp; yp.p[0] = gemmC; yp.p[1] = projC_cs; yp.p[2] = projC_ns; yp.p[3] = projC_ds; yp.p[4] = projC_rev;
        gemm_col5<<<cdiv(NC, 128), 256, 0, stream>>>(column_x, wp, f_biasC, yp, NC);
    }
    {
        B3 wp; wp.p[0] = WtS1t; wp.p[1] = Wt_tc; wp.p[2] = Wt_ts;
        Y3 yp; yp.p[0] = gemmT; yp.p[1] = projT_tc; yp.p[2] = projT_ts;
        gemm_tab3<<<cdiv(NT, 64), 256, 0, stream>>>(table_x, wp, f_biasT1, yp, q, f_sc, f_wgt, NT);
    }

    // ---- single-arena CSR build ----
    ED6 cds;
    cds.d[0] = {cs_ei + E_SIM, cs_ei, E_SIM, 0,                  4, 0, KB_COL, 0,      0};
    cds.d[1] = {ns_ei + E_SIM, ns_ei, E_SIM, E_SIM,              4, 1, KB_COL, NC,     0};
    cds.d[2] = {ds_ei + E_SIM, ds_ei, E_SIM, 2 * E_SIM,          4, 2, KB_COL, 2 * NC, 0};
    cds.d[3] = {tc_dst, tc_src, E_TC, 3 * E_SIM,                 4, 3, KB_COL, 3 * NC, 0};
    cds.d[4] = {tc_src, tc_dst, E_TC, 3 * E_SIM + E_TC,          2, 0, KB_TAB, 0,      0};
    cds.d[5] = {ts_ei + E_TS, ts_ei, E_TS, 3 * E_SIM + 2 * E_TC, 2, 1, KB_TAB, NC,     1};

    hipMemsetAsync(i_cnt, 0, (size_t)NKEY * 4, stream);
    count_all<<<cdiv(NED_AB, 256), 256, 0, stream>>>(cds, i_cnt, NED_AB);
    copy_cnt<<<cdiv(NT, 256), 256, 0, stream>>>(i_cnt);
    {
        const int nblk = cdiv(NKEY, 1024);
        scan_phase1<<<nblk, 256, 0, stream>>>(i_cnt, i_rs, i_bsum, NKEY);
        scan_phase2<<<1, 64, 0, stream>>>(i_bsum, i_boff, nblk);
        scan_phase3<<<cdiv(NKEY, 256), 256, 0, stream>>>(i_rs, i_work, i_boff, NKEY, nblk);
    }
    // dis must be ready before fill_all (norm written there)
    fill_f32<<<cdiv(NT, 256), 256, 0, stream>>>(f_dis, 1.0f, NT);
    deg_accum<<<cdiv(E_TS, 256), 256, 0, stream>>>(ts_ei + E_TS, ts_ew, f_dis, E_TS);
    deg_to_dis<<<cdiv(NT, 256), 256, 0, stream>>>(f_dis, NT);
    fill_all<<<cdiv(NED_AB, 256), 256, 0, stream>>>(cds, i_rs, i_work, ed_idx, ed2,
                                                    ts_ew, f_dis, NED_AB);

    // ---- fused aggregation + relu + dot ----
    col_fused<<<cdiv(NC, 4), 256, 0, stream>>>(gemmC, featC, i_rs + KB_COL, ed_idx,
                                               f_wrev, f_colv, NC);
    tab_fused<<<cdiv(NT, 4), 256, 0, stream>>>(gemmT, featT, i_rs + KB_TAB, ed_idx,
                                               f_w2s, f_wts, f_tvs, f_tvt, NT);

    // ---- tail ----
    y0_joint<<<cdiv(NT, 16), 256, 0, stream>>>(f_tvs, val2, i_rs + KB_TAB, ed_idx,
                                               f_wgt, f_sc, f_y0, NT);

    const float* zin = f_y0;
    float* zout = f_za;
    for (int it = 0; it < 10; ++it) {
        const int last = (it == 9);
        appnp_s<<<cdiv(NT, 16), 256, 0, stream>>>(zin, f_y0, i_rs + KB_TS, ed2,
                                                  f_dis, zout, blin, (float*)d_out, NT, last);
        zin = zout;
        zout = (zout == f_za) ? f_zb : f_za;
    }
}